// Round 1
// baseline (965.930 us; speedup 1.0000x reference)
//
#include <hip/hip_runtime.h>
#include <math.h>

// ---------------------------------------------------------------------------
// PNA (2 conv layers) on MI355X.
// Key algebra:
//   h_e = Wpre @ [x_dst; x_src] + b  =  A[dst] + B[src],  A = x@Wl^T, B = x@Wr^T + b
//   mean(h) = A + mean(B); max(h) = A + max(B); min(h) = A + min(B); std(h) = std(B)
//   lin(post(cat)) = cat @ W_eff^T + b_eff,  W_eff = W_lin@W_post
//   cat = [x, aggr, aggr*amp, aggr/amp]  =>  out = Wx@x + (WA + amp*WB + inv*WC)@aggr
// avg_log recomputed on-device from the degree histogram (dtype-safe).
// ---------------------------------------------------------------------------

__global__ void make_eff_kernel(const float* __restrict__ W1_post, const float* __restrict__ b1_post,
                                const float* __restrict__ W1_lin, const float* __restrict__ b1_lin,
                                const float* __restrict__ W2_post, const float* __restrict__ b2_post,
                                const float* __restrict__ W2_lin, const float* __restrict__ b2_lin,
                                float* __restrict__ W1eff, float* __restrict__ b1eff,
                                float* __restrict__ W2eff, float* __restrict__ b2eff) {
  int id = blockIdx.x * blockDim.x + threadIdx.x;
  const int n1 = 64 * 832;
  if (id < n1) {
    int o = id / 832, k = id - o * 832;
    float s = 0.f;
#pragma unroll 8
    for (int j = 0; j < 64; ++j) s = fmaf(W1_lin[o * 64 + j], W1_post[j * 832 + k], s);
    W1eff[id] = s;
  } else if (id < n1 + 64) {
    int o = id - n1;
    float s = b1_lin[o];
    for (int j = 0; j < 64; ++j) s = fmaf(W1_lin[o * 64 + j], b1_post[j], s);
    b1eff[o] = s;
  } else if (id < n1 + 64 + 2 * 832) {
    int t = id - (n1 + 64);
    int o = t / 832, k = t - o * 832;
    W2eff[t] = fmaf(W2_lin[o * 2 + 0], W2_post[k],
                    W2_lin[o * 2 + 1] * W2_post[832 + k]);
  } else if (id < n1 + 64 + 2 * 832 + 2) {
    int o = id - (n1 + 64 + 2 * 832);
    b2eff[o] = b2_lin[o] + W2_lin[o * 2 + 0] * b2_post[0] + W2_lin[o * 2 + 1] * b2_post[1];
  }
}

__global__ void hist_kernel(const int* __restrict__ dst, int* __restrict__ deg, int E) {
  int i = blockIdx.x * blockDim.x + threadIdx.x;
  if (i < E) atomicAdd(&deg[dst[i]], 1);
}

__global__ void avglog_kernel(const int* __restrict__ deg, float* __restrict__ out_sum, int n) {
  int i = blockIdx.x * blockDim.x + threadIdx.x;
  float v = (i < n) ? logf((float)deg[i] + 1.0f) : 0.0f;
  __shared__ float red[4];
  int lane = threadIdx.x & 63, wid = threadIdx.x >> 6;
  for (int off = 32; off; off >>= 1) v += __shfl_down(v, off);
  if (lane == 0) red[wid] = v;
  __syncthreads();
  if (threadIdx.x == 0) atomicAdd(out_sum, red[0] + red[1] + red[2] + red[3]);
}

// single-block exclusive scan of deg -> rowptr (+cursor copy); also amp/inv per node
__global__ void scan_kernel(const int* __restrict__ deg, int* __restrict__ rowptr,
                            int* __restrict__ cursor, float* __restrict__ amp,
                            float* __restrict__ inv, const float* __restrict__ avg_sum, int n) {
  __shared__ int warp_sums[16];
  __shared__ int carry_s;
  int tid = threadIdx.x;
  int lane = tid & 63, wid = tid >> 6;
  if (tid == 0) carry_s = 0;
  __syncthreads();
  float inv_avg = (float)n / avg_sum[0];  // 1 / avg_log
  for (int base = 0; base < n; base += 1024) {
    int i = base + tid;
    int v = (i < n) ? deg[i] : 0;
    int x = v;
    for (int off = 1; off < 64; off <<= 1) {
      int t = __shfl_up(x, off);
      if (lane >= off) x += t;
    }
    if (lane == 63) warp_sums[wid] = x;
    __syncthreads();  // B1
    if (wid == 0) {
      int ws = (lane < 16) ? warp_sums[lane] : 0;
      for (int off = 1; off < 16; off <<= 1) {
        int t = __shfl_up(ws, off);
        if (lane >= off) ws += t;
      }
      if (lane < 16) warp_sums[lane] = ws;
    }
    __syncthreads();  // B2
    int wave_off = (wid > 0) ? warp_sums[wid - 1] : 0;
    int incl = x + wave_off;
    int carry = carry_s;
    if (i < n) {
      int excl = carry + incl - v;
      rowptr[i] = excl;
      cursor[i] = excl;
      float dnm = (float)(v > 0 ? v : 1);
      float a = logf(dnm + 1.0f) * inv_avg;
      amp[i] = a;
      inv[i] = 1.0f / a;
    }
    __syncthreads();  // B3
    if (tid == 1023) carry_s = carry + incl;
    __syncthreads();  // B4
  }
  if (tid == 0) rowptr[n] = carry_s;
}

__global__ void fill_kernel(const int* __restrict__ src, const int* __restrict__ dst,
                            int* __restrict__ cursor, int* __restrict__ col, int E) {
  int i = blockIdx.x * blockDim.x + threadIdx.x;
  if (i < E) {
    int d = dst[i];
    int pos = atomicAdd(&cursor[d], 1);
    col[pos] = src[i];
  }
}

// A = x @ Wl^T ; B = x @ Wr^T + b   (Wpre is [64,128] row-major; Wl=cols 0..63, Wr=64..127)
__global__ void pre_kernel(const float* __restrict__ xin, const float* __restrict__ Wpre,
                           const float* __restrict__ bpre,
                           float* __restrict__ A, float* __restrict__ Bo, int n) {
  __shared__ float w[64 * 129];  // +1 pad: (lane+k)%32 banks, 2-way max (free)
  int tid = threadIdx.x;
  for (int i = tid; i < 64 * 128; i += 256) {
    int r = i >> 7, c = i & 127;
    w[r * 129 + c] = Wpre[i];
  }
  __syncthreads();
  int lane = tid & 63, wid = tid >> 6;
  float bias = bpre[lane];
  int stride = gridDim.x * 4;
  for (int node = blockIdx.x * 4 + wid; node < n; node += stride) {
    float xr = xin[(size_t)node * 64 + lane];
    float accA = 0.f, accB = 0.f;
#pragma unroll 8
    for (int k = 0; k < 64; ++k) {
      float xv = __shfl(xr, k);
      accA = fmaf(xv, w[lane * 129 + k], accA);
      accB = fmaf(xv, w[lane * 129 + 64 + k], accB);
    }
    A[(size_t)node * 64 + lane] = accA;
    Bo[(size_t)node * 64 + lane] = accB + bias;
  }
}

// wave per node: stats of B over in-neighbors; writes aggr[n][256] = [mean,mn,mx,std]
__global__ void aggr_kernel(const float* __restrict__ A, const float* __restrict__ B,
                            const int* __restrict__ rowptr, const int* __restrict__ col,
                            float* __restrict__ aggr, int n) {
  int tid = threadIdx.x;
  int lane = tid & 63, wid = tid >> 6;
  int stride = gridDim.x * 4;
  for (int node = blockIdx.x * 4 + wid; node < n; node += stride) {
    int s0 = rowptr[node], s1 = rowptr[node + 1];
    float sum = 0.f, sq = 0.f, mx = -3.4e38f, mn = 3.4e38f;
    int e = s0;
    for (; e + 4 <= s1; e += 4) {
      int i0 = col[e], i1 = col[e + 1], i2 = col[e + 2], i3 = col[e + 3];
      float b0 = B[(size_t)i0 * 64 + lane];
      float b1 = B[(size_t)i1 * 64 + lane];
      float b2 = B[(size_t)i2 * 64 + lane];
      float b3 = B[(size_t)i3 * 64 + lane];
      sum += b0 + b1 + b2 + b3;
      sq = fmaf(b0, b0, sq); sq = fmaf(b1, b1, sq);
      sq = fmaf(b2, b2, sq); sq = fmaf(b3, b3, sq);
      mx = fmaxf(mx, fmaxf(fmaxf(b0, b1), fmaxf(b2, b3)));
      mn = fminf(mn, fminf(fminf(b0, b1), fminf(b2, b3)));
    }
    for (; e < s1; ++e) {
      int s = col[e];
      float b = B[(size_t)s * 64 + lane];
      sum += b; sq = fmaf(b, b, sq);
      mx = fmaxf(mx, b); mn = fminf(mn, b);
    }
    int d = s1 - s0;
    float mean, mnv, mxv, sd;
    if (d > 0) {
      float idn = 1.0f / (float)d;
      float mB = sum * idn;
      float a = A[(size_t)node * 64 + lane];
      mean = a + mB;
      mnv = a + mn;
      mxv = a + mx;
      float var = fmaf(-mB, mB, sq * idn);
      sd = sqrtf(fmaxf(var, 0.0f) + 1e-5f);
    } else {
      mean = 0.f; mnv = 0.f; mxv = 0.f; sd = sqrtf(1e-5f);
    }
    size_t o = (size_t)node * 256 + lane;
    aggr[o] = mean; aggr[o + 64] = mnv; aggr[o + 128] = mxv; aggr[o + 192] = sd;
  }
}

// h1 = relu( Wx@x + (WA + amp*WB + inv*WC)@aggr + beff )  -- 64-row tile GEMM
#define ZS 68
__global__ __launch_bounds__(256) void post1_kernel(
    const float* __restrict__ x, const float* __restrict__ aggr,
    const float* __restrict__ amp, const float* __restrict__ inv,
    const float* __restrict__ Weff, const float* __restrict__ beff,
    float* __restrict__ h1, int n) {
  __shared__ __attribute__((aligned(16))) float zt[64 * ZS];
  __shared__ __attribute__((aligned(16))) float wA[64 * ZS];
  __shared__ __attribute__((aligned(16))) float wB[64 * ZS];
  __shared__ __attribute__((aligned(16))) float wC[64 * ZS];
  int tid = threadIdx.x;
  int ty = tid >> 4, tx = tid & 15;
  int row0 = blockIdx.x * 64;
  float accP[4][4] = {};
  float accQ[4][4] = {};
  float accR[4][4] = {};

  // ---- x tile (cat k 0..63, weights Wx) ----
  for (int i = tid; i < 64 * 64; i += 256) {
    int r = i >> 6, c = i & 63;
    int gr = row0 + r;
    zt[r * ZS + c] = (gr < n) ? x[(size_t)gr * 64 + c] : 0.f;
    wA[r * ZS + c] = Weff[r * 832 + c];
  }
  __syncthreads();
#pragma unroll 4
  for (int k = 0; k < 64; k += 4) {
    float4 zv[4], av[4];
#pragma unroll
    for (int m = 0; m < 4; ++m) zv[m] = *(const float4*)&zt[(ty + 16 * m) * ZS + k];
#pragma unroll
    for (int u = 0; u < 4; ++u) av[u] = *(const float4*)&wA[(tx + 16 * u) * ZS + k];
#pragma unroll
    for (int m = 0; m < 4; ++m)
#pragma unroll
      for (int u = 0; u < 4; ++u) {
        accP[m][u] = fmaf(zv[m].x, av[u].x, accP[m][u]);
        accP[m][u] = fmaf(zv[m].y, av[u].y, accP[m][u]);
        accP[m][u] = fmaf(zv[m].z, av[u].z, accP[m][u]);
        accP[m][u] = fmaf(zv[m].w, av[u].w, accP[m][u]);
      }
  }
  // ---- 4 aggr tiles ----
  for (int t = 0; t < 4; ++t) {
    __syncthreads();
    for (int i = tid; i < 64 * 64; i += 256) {
      int r = i >> 6, c = i & 63;
      int gr = row0 + r;
      zt[r * ZS + c] = (gr < n) ? aggr[(size_t)gr * 256 + t * 64 + c] : 0.f;
      wA[r * ZS + c] = Weff[r * 832 + 64 + t * 64 + c];
      wB[r * ZS + c] = Weff[r * 832 + 320 + t * 64 + c];
      wC[r * ZS + c] = Weff[r * 832 + 576 + t * 64 + c];
    }
    __syncthreads();
#pragma unroll 2
    for (int k = 0; k < 64; k += 4) {
      float4 zv[4], av[4], bv[4], cv[4];
#pragma unroll
      for (int m = 0; m < 4; ++m) zv[m] = *(const float4*)&zt[(ty + 16 * m) * ZS + k];
#pragma unroll
      for (int u = 0; u < 4; ++u) {
        av[u] = *(const float4*)&wA[(tx + 16 * u) * ZS + k];
        bv[u] = *(const float4*)&wB[(tx + 16 * u) * ZS + k];
        cv[u] = *(const float4*)&wC[(tx + 16 * u) * ZS + k];
      }
#pragma unroll
      for (int m = 0; m < 4; ++m)
#pragma unroll
        for (int u = 0; u < 4; ++u) {
          accP[m][u] = fmaf(zv[m].x, av[u].x, accP[m][u]);
          accP[m][u] = fmaf(zv[m].y, av[u].y, accP[m][u]);
          accP[m][u] = fmaf(zv[m].z, av[u].z, accP[m][u]);
          accP[m][u] = fmaf(zv[m].w, av[u].w, accP[m][u]);
          accQ[m][u] = fmaf(zv[m].x, bv[u].x, accQ[m][u]);
          accQ[m][u] = fmaf(zv[m].y, bv[u].y, accQ[m][u]);
          accQ[m][u] = fmaf(zv[m].z, bv[u].z, accQ[m][u]);
          accQ[m][u] = fmaf(zv[m].w, bv[u].w, accQ[m][u]);
          accR[m][u] = fmaf(zv[m].x, cv[u].x, accR[m][u]);
          accR[m][u] = fmaf(zv[m].y, cv[u].y, accR[m][u]);
          accR[m][u] = fmaf(zv[m].z, cv[u].z, accR[m][u]);
          accR[m][u] = fmaf(zv[m].w, cv[u].w, accR[m][u]);
        }
    }
  }
  // epilogue
#pragma unroll
  for (int m = 0; m < 4; ++m) {
    int r = row0 + ty + 16 * m;
    if (r < n) {
      float av = amp[r], iv = inv[r];
#pragma unroll
      for (int u = 0; u < 4; ++u) {
        int o = tx + 16 * u;
        float vv = accP[m][u] + av * accQ[m][u] + iv * accR[m][u] + beff[o];
        h1[(size_t)r * 64 + o] = fmaxf(vv, 0.f);
      }
    }
  }
}

// conv2 post: out[n][2], wave per node, shuffle reduce
__global__ void post2_kernel(const float* __restrict__ h1, const float* __restrict__ aggr,
                             const float* __restrict__ amp, const float* __restrict__ inv,
                             const float* __restrict__ W2eff, const float* __restrict__ b2eff,
                             float* __restrict__ out, int n) {
  int tid = threadIdx.x;
  int lane = tid & 63, wid = tid >> 6;
  int stride = gridDim.x * 4;
  for (int node = blockIdx.x * 4 + wid; node < n; node += stride) {
    float av = amp[node], iv = inv[node];
    float xv = h1[(size_t)node * 64 + lane];
    float p0 = W2eff[lane] * xv;
    float p1 = W2eff[832 + lane] * xv;
#pragma unroll
    for (int m = 0; m < 4; ++m) {
      int j = lane + 64 * m;
      float a = aggr[(size_t)node * 256 + j];
      float wA0 = W2eff[64 + j], wB0 = W2eff[320 + j], wC0 = W2eff[576 + j];
      float wA1 = W2eff[832 + 64 + j], wB1 = W2eff[832 + 320 + j], wC1 = W2eff[832 + 576 + j];
      p0 = fmaf(a, fmaf(av, wB0, fmaf(iv, wC0, wA0)), p0);
      p1 = fmaf(a, fmaf(av, wB1, fmaf(iv, wC1, wA1)), p1);
    }
    for (int off = 32; off; off >>= 1) {
      p0 += __shfl_down(p0, off);
      p1 += __shfl_down(p1, off);
    }
    if (lane == 0) {
      out[(size_t)node * 2 + 0] = p0 + b2eff[0];
      out[(size_t)node * 2 + 1] = p1 + b2eff[1];
    }
  }
}

extern "C" void kernel_launch(void* const* d_in, const int* in_sizes, int n_in,
                              void* d_out, int out_size, void* d_ws, size_t ws_size,
                              hipStream_t stream) {
  const float* x = (const float*)d_in[0];
  const int* ei = (const int*)d_in[1];
  const float* W1_pre = (const float*)d_in[2];
  const float* b1_pre = (const float*)d_in[3];
  const float* W1_post = (const float*)d_in[4];
  const float* b1_post = (const float*)d_in[5];
  const float* W1_lin = (const float*)d_in[6];
  const float* b1_lin = (const float*)d_in[7];
  const float* W2_pre = (const float*)d_in[8];
  const float* b2_pre = (const float*)d_in[9];
  const float* W2_post = (const float*)d_in[10];
  const float* b2_post = (const float*)d_in[11];
  const float* W2_lin = (const float*)d_in[12];
  const float* b2_lin = (const float*)d_in[13];

  const int N = in_sizes[0] / 64;
  const int E = in_sizes[1] / 2;
  const int* srcp = ei;
  const int* dstp = ei + E;

  char* ws = (char*)d_ws;
  size_t off = 0;
  auto take = [&](size_t bytes) -> void* {
    void* p = ws + off;
    off = (off + bytes + 255) & ~(size_t)255;
    return p;
  };
  int* deg = (int*)take((size_t)N * 4);
  int* rowptr = (int*)take((size_t)(N + 1) * 4);
  int* cursor = (int*)take((size_t)N * 4);
  float* amp = (float*)take((size_t)N * 4);
  float* inv = (float*)take((size_t)N * 4);
  float* avgsum = (float*)take(4);
  float* W1eff = (float*)take((size_t)64 * 832 * 4);
  float* b1eff = (float*)take(64 * 4);
  float* W2eff = (float*)take((size_t)2 * 832 * 4);
  float* b2eff = (float*)take(2 * 4);
  int* col = (int*)take((size_t)E * 4);
  float* Abuf = (float*)take((size_t)N * 64 * 4);
  float* Bbuf = (float*)take((size_t)N * 64 * 4);
  float* aggr = (float*)take((size_t)N * 256 * 4);
  float* h1 = (float*)take((size_t)N * 64 * 4);
  (void)ws_size;
  (void)n_in;
  (void)out_size;

  hipMemsetAsync(deg, 0, (size_t)N * 4, stream);
  hipMemsetAsync(avgsum, 0, 4, stream);

  make_eff_kernel<<<(64 * 832 + 64 + 2 * 832 + 2 + 255) / 256, 256, 0, stream>>>(
      W1_post, b1_post, W1_lin, b1_lin, W2_post, b2_post, W2_lin, b2_lin,
      W1eff, b1eff, W2eff, b2eff);
  hist_kernel<<<(E + 255) / 256, 256, 0, stream>>>(dstp, deg, E);
  avglog_kernel<<<(N + 255) / 256, 256, 0, stream>>>(deg, avgsum, N);
  scan_kernel<<<1, 1024, 0, stream>>>(deg, rowptr, cursor, amp, inv, avgsum, N);
  fill_kernel<<<(E + 255) / 256, 256, 0, stream>>>(srcp, dstp, cursor, col, E);

  // conv1
  pre_kernel<<<1024, 256, 0, stream>>>(x, W1_pre, b1_pre, Abuf, Bbuf, N);
  aggr_kernel<<<4096, 256, 0, stream>>>(Abuf, Bbuf, rowptr, col, aggr, N);
  post1_kernel<<<(N + 63) / 64, 256, 0, stream>>>(x, aggr, amp, inv, W1eff, b1eff, h1, N);

  // conv2
  pre_kernel<<<1024, 256, 0, stream>>>(h1, W2_pre, b2_pre, Abuf, Bbuf, N);
  aggr_kernel<<<4096, 256, 0, stream>>>(Abuf, Bbuf, rowptr, col, aggr, N);
  post2_kernel<<<2048, 256, 0, stream>>>(h1, aggr, amp, inv, W2eff, b2eff, (float*)d_out, N);
}

// Round 2
// 825.297 us; speedup vs baseline: 1.1704x; 1.1704x over previous
//
#include <hip/hip_runtime.h>
#include <math.h>

// ---------------------------------------------------------------------------
// PNA (2 conv layers) on MI355X.
//   h_e = Wpre @ [x_dst; x_src] + b  =  A[dst] + B[src]
//   mean(h)=A+mean(B); max(h)=A+max(B); min(h)=A+min(B); std(h)=std(B)
//   lin(post(cat)) = cat @ W_eff^T + b_eff,  W_eff = W_lin@W_post
//   cat = [x, aggr, amp*aggr, inv*aggr]  (scalers folded into A-tiles)
// post1 runs as bf16-split (hi/lo, 3-product) MFMA GEMM: C = cat @ Weff^T.
// ---------------------------------------------------------------------------

typedef __attribute__((ext_vector_type(4))) float f32x4;
typedef __attribute__((ext_vector_type(8))) short s16x8;

__device__ inline unsigned short f2bf(float f) {
  unsigned int u = __float_as_uint(f);
  unsigned int r = u + 0x7fff + ((u >> 16) & 1);  // RNE
  return (unsigned short)(r >> 16);
}
__device__ inline float bf2f(unsigned short s) {
  return __uint_as_float(((unsigned int)s) << 16);
}

__global__ void make_eff_kernel(const float* __restrict__ W1_post, const float* __restrict__ b1_post,
                                const float* __restrict__ W1_lin, const float* __restrict__ b1_lin,
                                const float* __restrict__ W2_post, const float* __restrict__ b2_post,
                                const float* __restrict__ W2_lin, const float* __restrict__ b2_lin,
                                unsigned short* __restrict__ W1h, unsigned short* __restrict__ W1l,
                                float* __restrict__ b1eff,
                                float* __restrict__ W2eff, float* __restrict__ b2eff) {
  int id = blockIdx.x * blockDim.x + threadIdx.x;
  const int n1 = 64 * 832;
  if (id < n1) {
    int o = id / 832, k = id - o * 832;
    float s = 0.f;
#pragma unroll 8
    for (int j = 0; j < 64; ++j) s = fmaf(W1_lin[o * 64 + j], W1_post[j * 832 + k], s);
    unsigned short h = f2bf(s);
    W1h[id] = h;
    W1l[id] = f2bf(s - bf2f(h));
  } else if (id < n1 + 64) {
    int o = id - n1;
    float s = b1_lin[o];
    for (int j = 0; j < 64; ++j) s = fmaf(W1_lin[o * 64 + j], b1_post[j], s);
    b1eff[o] = s;
  } else if (id < n1 + 64 + 2 * 832) {
    int t = id - (n1 + 64);
    int o = t / 832, k = t - o * 832;
    W2eff[t] = fmaf(W2_lin[o * 2 + 0], W2_post[k], W2_lin[o * 2 + 1] * W2_post[832 + k]);
  } else if (id < n1 + 64 + 2 * 832 + 2) {
    int o = id - (n1 + 64 + 2 * 832);
    b2eff[o] = b2_lin[o] + W2_lin[o * 2 + 0] * b2_post[0] + W2_lin[o * 2 + 1] * b2_post[1];
  }
}

__global__ void hist_kernel(const int* __restrict__ dst, int* __restrict__ deg, int E) {
  int i = blockIdx.x * blockDim.x + threadIdx.x;
  if (i < E) atomicAdd(&deg[dst[i]], 1);
}

__global__ void avglog_kernel(const int* __restrict__ deg, float* __restrict__ out_sum, int n) {
  int i = blockIdx.x * blockDim.x + threadIdx.x;
  float v = (i < n) ? logf((float)deg[i] + 1.0f) : 0.0f;
  __shared__ float red[4];
  int lane = threadIdx.x & 63, wid = threadIdx.x >> 6;
  for (int off = 32; off; off >>= 1) v += __shfl_down(v, off);
  if (lane == 0) red[wid] = v;
  __syncthreads();
  if (threadIdx.x == 0) atomicAdd(out_sum, red[0] + red[1] + red[2] + red[3]);
}

// hierarchical scan: scan1 (per-block) -> scan2 (block partials) -> scan3 (combine)
__global__ void scan1_kernel(const int* __restrict__ deg, int* __restrict__ excl,
                             int* __restrict__ partial, int n) {
  __shared__ int wsums[4];
  int tid = threadIdx.x, b = blockIdx.x;
  int i = b * 256 + tid;
  int lane = tid & 63, wid = tid >> 6;
  int v = (i < n) ? deg[i] : 0;
  int x = v;
  for (int off = 1; off < 64; off <<= 1) {
    int t = __shfl_up(x, off);
    if (lane >= off) x += t;
  }
  if (lane == 63) wsums[wid] = x;
  __syncthreads();
  int wo = 0;
#pragma unroll
  for (int j = 0; j < 4; ++j) wo += (j < wid) ? wsums[j] : 0;
  if (i < n) excl[i] = wo + x - v;
  if (tid == 255) partial[b] = wo + x;
}

__global__ void scan2_kernel(int* __restrict__ partial, int nb) {
  __shared__ int wsums[16];
  int tid = threadIdx.x;
  int lane = tid & 63, wid = tid >> 6;
  int v = (tid < nb) ? partial[tid] : 0;
  int x = v;
  for (int off = 1; off < 64; off <<= 1) {
    int t = __shfl_up(x, off);
    if (lane >= off) x += t;
  }
  if (lane == 63) wsums[wid] = x;
  __syncthreads();
  if (wid == 0) {
    int w2 = (lane < 16) ? wsums[lane] : 0;
    for (int off = 1; off < 16; off <<= 1) {
      int t = __shfl_up(w2, off);
      if (lane >= off) w2 += t;
    }
    if (lane < 16) wsums[lane] = w2;
  }
  __syncthreads();
  int wo = (wid > 0) ? wsums[wid - 1] : 0;
  if (tid < nb) partial[tid] = wo + x - v;
}

__global__ void scan3_kernel(const int* __restrict__ deg, const int* __restrict__ excl,
                             const int* __restrict__ partial, int* __restrict__ rowptr,
                             int* __restrict__ cursor, float* __restrict__ amp,
                             float* __restrict__ inv, const float* __restrict__ avgsum,
                             int n, int E) {
  int i = blockIdx.x * 256 + threadIdx.x;
  if (i < n) {
    int r = excl[i] + partial[blockIdx.x];
    rowptr[i] = r;
    cursor[i] = r;
    int v = deg[i];
    float dnm = (float)(v > 0 ? v : 1);
    float a = logf(dnm + 1.0f) * ((float)n / avgsum[0]);
    amp[i] = a;
    inv[i] = 1.0f / a;
  }
  if (i == 0) rowptr[n] = E;
}

__global__ void fill_kernel(const int* __restrict__ src, const int* __restrict__ dst,
                            int* __restrict__ cursor, int* __restrict__ col, int E) {
  int i = blockIdx.x * blockDim.x + threadIdx.x;
  if (i < E) {
    int d = dst[i];
    int pos = atomicAdd(&cursor[d], 1);
    col[pos] = src[i];
  }
}

// A = x @ Wl^T ; B = x @ Wr^T + b
__global__ void pre_kernel(const float* __restrict__ xin, const float* __restrict__ Wpre,
                           const float* __restrict__ bpre,
                           float* __restrict__ A, float* __restrict__ Bo, int n) {
  __shared__ float w[64 * 129];
  int tid = threadIdx.x;
  for (int i = tid; i < 64 * 128; i += 256) {
    int r = i >> 7, c = i & 127;
    w[r * 129 + c] = Wpre[i];
  }
  __syncthreads();
  int lane = tid & 63, wid = tid >> 6;
  float bias = bpre[lane];
  int stride = gridDim.x * 4;
  for (int node = blockIdx.x * 4 + wid; node < n; node += stride) {
    float xr = xin[(size_t)node * 64 + lane];
    float accA = 0.f, accB = 0.f;
#pragma unroll 8
    for (int k = 0; k < 64; ++k) {
      float xv = __shfl(xr, k);
      accA = fmaf(xv, w[lane * 129 + k], accA);
      accB = fmaf(xv, w[lane * 129 + 64 + k], accB);
    }
    A[(size_t)node * 64 + lane] = accA;
    Bo[(size_t)node * 64 + lane] = accB + bias;
  }
}

// wave per node: stats of B over in-neighbors; aggr[n][256] = [mean,mn,mx,std]
__global__ void aggr_kernel(const float* __restrict__ A, const float* __restrict__ B,
                            const int* __restrict__ rowptr, const int* __restrict__ col,
                            float* __restrict__ aggr, int n) {
  int tid = threadIdx.x;
  int lane = tid & 63, wid = tid >> 6;
  int stride = gridDim.x * 4;
  for (int node = blockIdx.x * 4 + wid; node < n; node += stride) {
    int s0 = rowptr[node], s1 = rowptr[node + 1];
    float sum = 0.f, sq = 0.f, mx = -3.4e38f, mn = 3.4e38f;
    int e = s0;
    for (; e + 4 <= s1; e += 4) {
      int i0 = col[e], i1 = col[e + 1], i2 = col[e + 2], i3 = col[e + 3];
      float b0 = B[(size_t)i0 * 64 + lane];
      float b1 = B[(size_t)i1 * 64 + lane];
      float b2 = B[(size_t)i2 * 64 + lane];
      float b3 = B[(size_t)i3 * 64 + lane];
      sum += b0 + b1 + b2 + b3;
      sq = fmaf(b0, b0, sq); sq = fmaf(b1, b1, sq);
      sq = fmaf(b2, b2, sq); sq = fmaf(b3, b3, sq);
      mx = fmaxf(mx, fmaxf(fmaxf(b0, b1), fmaxf(b2, b3)));
      mn = fminf(mn, fminf(fminf(b0, b1), fminf(b2, b3)));
    }
    for (; e < s1; ++e) {
      int s = col[e];
      float b = B[(size_t)s * 64 + lane];
      sum += b; sq = fmaf(b, b, sq);
      mx = fmaxf(mx, b); mn = fminf(mn, b);
    }
    int d = s1 - s0;
    float mean, mnv, mxv, sd;
    if (d > 0) {
      float idn = 1.0f / (float)d;
      float mB = sum * idn;
      float a = A[(size_t)node * 64 + lane];
      mean = a + mB;
      mnv = a + mn;
      mxv = a + mx;
      float var = fmaf(-mB, mB, sq * idn);
      sd = sqrtf(fmaxf(var, 0.0f) + 1e-5f);
    } else {
      mean = 0.f; mnv = 0.f; mxv = 0.f; sd = sqrtf(1e-5f);
    }
    size_t o = (size_t)node * 256 + lane;
    aggr[o] = mean; aggr[o + 64] = mnv; aggr[o + 128] = mxv; aggr[o + 192] = sd;
  }
}

// post1: h1 = relu( [x, aggr, amp*aggr, inv*aggr] @ Weff^T + beff )
// bf16-split MFMA (3 products), 64 rows x 64 cols per block, K=832.
// LDS A-tiles [64][64] bf16 hi/lo x 3 scalings, XOR-swizzled at 16B granules.
__global__ __launch_bounds__(256) void post1_kernel(
    const float* __restrict__ x, const float* __restrict__ aggr,
    const float* __restrict__ amp, const float* __restrict__ inv,
    const unsigned short* __restrict__ Wh, const unsigned short* __restrict__ Wl,
    const float* __restrict__ beff, float* __restrict__ h1, int n) {
  __shared__ unsigned short Ah[3][64 * 64];
  __shared__ unsigned short Al[3][64 * 64];
  int tid = threadIdx.x;
  int lane = tid & 63, w = tid >> 6;
  int row0 = blockIdx.x * 64;
  // staging ids: thread owns row sr, 16 cols starting at cg*16
  int sr = tid >> 2;
  int cg = tid & 3;
  int grow = row0 + sr;
  bool rok = grow < n;
  float ampr = rok ? amp[grow] : 1.0f;
  float invr = rok ? inv[grow] : 1.0f;
  // mfma lane ids
  int ar = lane & 15;            // A row within 16 / B col within 16
  int kl = (lane >> 4) * 8;      // lane k offset
  int lrow = w * 16 + ar;        // LDS A row (wave w owns rows 16w..16w+15)
  int rsw = lrow & 7;

  f32x4 acc[4];
#pragma unroll
  for (int ct = 0; ct < 4; ++ct) acc[ct] = (f32x4){0.f, 0.f, 0.f, 0.f};

  float v[16];
  // ---- stage one chunk (64 rows x 64 cols f32) into scaled bf16 hi/lo tiles ----
  auto stage = [&](const float* src, int ld, int nscal) {
    if (rok) {
      const float* base = src + (size_t)grow * ld + cg * 16;
      float4 a0 = *(const float4*)(base + 0);
      float4 a1 = *(const float4*)(base + 4);
      float4 a2 = *(const float4*)(base + 8);
      float4 a3 = *(const float4*)(base + 12);
      v[0] = a0.x; v[1] = a0.y; v[2] = a0.z; v[3] = a0.w;
      v[4] = a1.x; v[5] = a1.y; v[6] = a1.z; v[7] = a1.w;
      v[8] = a2.x; v[9] = a2.y; v[10] = a2.z; v[11] = a2.w;
      v[12] = a3.x; v[13] = a3.y; v[14] = a3.z; v[15] = a3.w;
    } else {
#pragma unroll
      for (int j = 0; j < 16; ++j) v[j] = 0.f;
    }
    int g0 = cg * 2;
    int o0 = sr * 64 + (((g0 + 0) ^ (sr & 7)) << 3);
    int o1 = sr * 64 + (((g0 + 1) ^ (sr & 7)) << 3);
#pragma unroll
    for (int s = 0; s < 3; ++s) {
      if (s >= nscal) break;
      float sc = (s == 0) ? 1.0f : ((s == 1) ? ampr : invr);
      unsigned short hs[16], ls[16];
#pragma unroll
      for (int j = 0; j < 16; ++j) {
        float t = v[j] * sc;
        unsigned short h = f2bf(t);
        hs[j] = h;
        ls[j] = f2bf(t - bf2f(h));
      }
      *(s16x8*)&Ah[s][o0] = *(s16x8*)&hs[0];
      *(s16x8*)&Ah[s][o1] = *(s16x8*)&hs[8];
      *(s16x8*)&Al[s][o0] = *(s16x8*)&ls[0];
      *(s16x8*)&Al[s][o1] = *(s16x8*)&ls[8];
    }
  };
  // ---- one 64-wide k-tile of MFMAs from staged scaling s, weight col base kc ----
  auto do_ktile = [&](int s, int kc) {
#pragma unroll
    for (int kk = 0; kk < 64; kk += 32) {
      int g = (kk + kl) >> 3;
      int off = lrow * 64 + ((g ^ rsw) << 3);
      s16x8 ahf = *(const s16x8*)&Ah[s][off];
      s16x8 alf = *(const s16x8*)&Al[s][off];
      int ko = kc + kk + kl;
#pragma unroll
      for (int ct = 0; ct < 4; ++ct) {
        size_t br = (size_t)(ct * 16 + ar) * 832 + ko;
        s16x8 bhf = *(const s16x8*)&Wh[br];
        s16x8 blf = *(const s16x8*)&Wl[br];
        acc[ct] = __builtin_amdgcn_mfma_f32_16x16x32_bf16(ahf, bhf, acc[ct], 0, 0, 0);
        acc[ct] = __builtin_amdgcn_mfma_f32_16x16x32_bf16(ahf, blf, acc[ct], 0, 0, 0);
        acc[ct] = __builtin_amdgcn_mfma_f32_16x16x32_bf16(alf, bhf, acc[ct], 0, 0, 0);
      }
    }
  };

  // x tile (k 0..63)
  stage(x, 64, 1);
  __syncthreads();
  do_ktile(0, 0);
  // 4 aggr chunks x 3 scalings
  for (int c = 0; c < 4; ++c) {
    __syncthreads();
    stage(aggr + c * 64, 256, 3);
    __syncthreads();
#pragma unroll
    for (int s = 0; s < 3; ++s) do_ktile(s, 64 + s * 256 + c * 64);
  }
  // epilogue: D[(lane>>4)*4+i][ct*16 + ar]
#pragma unroll
  for (int ct = 0; ct < 4; ++ct) {
    int colo = ct * 16 + ar;
    float b = beff[colo];
#pragma unroll
    for (int i = 0; i < 4; ++i) {
      int r = row0 + w * 16 + (lane >> 4) * 4 + i;
      if (r < n) h1[(size_t)r * 64 + colo] = fmaxf(acc[ct][i] + b, 0.f);
    }
  }
}

// conv2 post: out[n][2], wave per node, shuffle reduce
__global__ void post2_kernel(const float* __restrict__ h1, const float* __restrict__ aggr,
                             const float* __restrict__ amp, const float* __restrict__ inv,
                             const float* __restrict__ W2eff, const float* __restrict__ b2eff,
                             float* __restrict__ out, int n) {
  int tid = threadIdx.x;
  int lane = tid & 63, wid = tid >> 6;
  int stride = gridDim.x * 4;
  for (int node = blockIdx.x * 4 + wid; node < n; node += stride) {
    float av = amp[node], iv = inv[node];
    float xv = h1[(size_t)node * 64 + lane];
    float p0 = W2eff[lane] * xv;
    float p1 = W2eff[832 + lane] * xv;
#pragma unroll
    for (int m = 0; m < 4; ++m) {
      int j = lane + 64 * m;
      float a = aggr[(size_t)node * 256 + j];
      float wA0 = W2eff[64 + j], wB0 = W2eff[320 + j], wC0 = W2eff[576 + j];
      float wA1 = W2eff[832 + 64 + j], wB1 = W2eff[832 + 320 + j], wC1 = W2eff[832 + 576 + j];
      p0 = fmaf(a, fmaf(av, wB0, fmaf(iv, wC0, wA0)), p0);
      p1 = fmaf(a, fmaf(av, wB1, fmaf(iv, wC1, wA1)), p1);
    }
    for (int off = 32; off; off >>= 1) {
      p0 += __shfl_down(p0, off);
      p1 += __shfl_down(p1, off);
    }
    if (lane == 0) {
      out[(size_t)node * 2 + 0] = p0 + b2eff[0];
      out[(size_t)node * 2 + 1] = p1 + b2eff[1];
    }
  }
}

extern "C" void kernel_launch(void* const* d_in, const int* in_sizes, int n_in,
                              void* d_out, int out_size, void* d_ws, size_t ws_size,
                              hipStream_t stream) {
  const float* x = (const float*)d_in[0];
  const int* ei = (const int*)d_in[1];
  const float* W1_pre = (const float*)d_in[2];
  const float* b1_pre = (const float*)d_in[3];
  const float* W1_post = (const float*)d_in[4];
  const float* b1_post = (const float*)d_in[5];
  const float* W1_lin = (const float*)d_in[6];
  const float* b1_lin = (const float*)d_in[7];
  const float* W2_pre = (const float*)d_in[8];
  const float* b2_pre = (const float*)d_in[9];
  const float* W2_post = (const float*)d_in[10];
  const float* b2_post = (const float*)d_in[11];
  const float* W2_lin = (const float*)d_in[12];
  const float* b2_lin = (const float*)d_in[13];

  const int N = in_sizes[0] / 64;
  const int E = in_sizes[1] / 2;
  const int* srcp = ei;
  const int* dstp = ei + E;
  const int nb = (N + 255) / 256;

  char* ws = (char*)d_ws;
  size_t off = 0;
  auto take = [&](size_t bytes) -> void* {
    void* p = ws + off;
    off = (off + bytes + 255) & ~(size_t)255;
    return p;
  };
  int* deg = (int*)take((size_t)N * 4);
  int* rowptr = (int*)take((size_t)(N + 1) * 4);
  int* cursor = (int*)take((size_t)N * 4);
  int* tmp = (int*)take((size_t)N * 4);
  int* partial = (int*)take(4096);
  float* amp = (float*)take((size_t)N * 4);
  float* inv = (float*)take((size_t)N * 4);
  float* avgsum = (float*)take(4);
  unsigned short* W1h = (unsigned short*)take((size_t)64 * 832 * 2);
  unsigned short* W1l = (unsigned short*)take((size_t)64 * 832 * 2);
  float* b1eff = (float*)take(64 * 4);
  float* W2eff = (float*)take((size_t)2 * 832 * 4);
  float* b2eff = (float*)take(2 * 4);
  int* col = (int*)take((size_t)E * 4);
  float* Abuf = (float*)take((size_t)N * 64 * 4);
  float* Bbuf = (float*)take((size_t)N * 64 * 4);
  float* aggr = (float*)take((size_t)N * 256 * 4);
  float* h1 = (float*)take((size_t)N * 64 * 4);
  (void)ws_size; (void)n_in; (void)out_size;

  hipMemsetAsync(deg, 0, (size_t)N * 4, stream);
  hipMemsetAsync(avgsum, 0, 4, stream);

  make_eff_kernel<<<(64 * 832 + 64 + 2 * 832 + 2 + 255) / 256, 256, 0, stream>>>(
      W1_post, b1_post, W1_lin, b1_lin, W2_post, b2_post, W2_lin, b2_lin,
      W1h, W1l, b1eff, W2eff, b2eff);
  hist_kernel<<<(E + 255) / 256, 256, 0, stream>>>(dstp, deg, E);
  avglog_kernel<<<(N + 255) / 256, 256, 0, stream>>>(deg, avgsum, N);
  scan1_kernel<<<nb, 256, 0, stream>>>(deg, tmp, partial, N);
  scan2_kernel<<<1, 1024, 0, stream>>>(partial, nb);
  scan3_kernel<<<nb, 256, 0, stream>>>(deg, tmp, partial, rowptr, cursor, amp, inv,
                                       avgsum, N, E);
  fill_kernel<<<(E + 255) / 256, 256, 0, stream>>>(srcp, dstp, cursor, col, E);

  // conv1
  pre_kernel<<<1024, 256, 0, stream>>>(x, W1_pre, b1_pre, Abuf, Bbuf, N);
  aggr_kernel<<<4096, 256, 0, stream>>>(Abuf, Bbuf, rowptr, col, aggr, N);
  post1_kernel<<<(N + 63) / 64, 256, 0, stream>>>(x, aggr, amp, inv, W1h, W1l, b1eff, h1, N);

  // conv2
  pre_kernel<<<1024, 256, 0, stream>>>(h1, W2_pre, b2_pre, Abuf, Bbuf, N);
  aggr_kernel<<<4096, 256, 0, stream>>>(Abuf, Bbuf, rowptr, col, aggr, N);
  post2_kernel<<<2048, 256, 0, stream>>>(h1, aggr, amp, inv, W2eff, b2eff, (float*)d_out, N);
}

// Round 3
// 783.815 us; speedup vs baseline: 1.2323x; 1.0529x over previous
//
#include <hip/hip_runtime.h>
#include <math.h>

// ---------------------------------------------------------------------------
// PNA (2 conv layers) on MI355X.
//   h_e = Wpre @ [x_dst; x_src] + b  =  A[dst] + B[src]
//   mean(h)=A+mean(B); max(h)=A+max(B); min(h)=A+min(B); std(h)=std(B)
//   lin(post(cat)) = cat @ W_eff^T + b_eff,  W_eff = W_lin@W_post
//   out = Wx@x + WA@aggr + amp*(WB@aggr) + inv*(WC@aggr)   (epilogue scaling)
// post1: bf16-split (hi/lo, 3-product) MFMA GEMM, 128-row tiles, P/Q/R accs.
// ---------------------------------------------------------------------------

typedef __attribute__((ext_vector_type(4))) float f32x4;
typedef __attribute__((ext_vector_type(8))) short s16x8;

__device__ inline unsigned short f2bf(float f) {
  unsigned int u = __float_as_uint(f);
  unsigned int r = u + 0x7fff + ((u >> 16) & 1);  // RNE
  return (unsigned short)(r >> 16);
}
__device__ inline float bf2f(unsigned short s) {
  return __uint_as_float(((unsigned int)s) << 16);
}

__global__ void make_eff_kernel(const float* __restrict__ W1_post, const float* __restrict__ b1_post,
                                const float* __restrict__ W1_lin, const float* __restrict__ b1_lin,
                                const float* __restrict__ W2_post, const float* __restrict__ b2_post,
                                const float* __restrict__ W2_lin, const float* __restrict__ b2_lin,
                                unsigned short* __restrict__ W1h, unsigned short* __restrict__ W1l,
                                float* __restrict__ b1eff,
                                float* __restrict__ W2eff, float* __restrict__ b2eff) {
  int id = blockIdx.x * blockDim.x + threadIdx.x;
  const int n1 = 64 * 832;
  if (id < n1) {
    int o = id / 832, k = id - o * 832;
    float s = 0.f;
#pragma unroll 8
    for (int j = 0; j < 64; ++j) s = fmaf(W1_lin[o * 64 + j], W1_post[j * 832 + k], s);
    unsigned short h = f2bf(s);
    W1h[id] = h;
    W1l[id] = f2bf(s - bf2f(h));
  } else if (id < n1 + 64) {
    int o = id - n1;
    float s = b1_lin[o];
    for (int j = 0; j < 64; ++j) s = fmaf(W1_lin[o * 64 + j], b1_post[j], s);
    b1eff[o] = s;
  } else if (id < n1 + 64 + 2 * 832) {
    int t = id - (n1 + 64);
    int o = t / 832, k = t - o * 832;
    W2eff[t] = fmaf(W2_lin[o * 2 + 0], W2_post[k], W2_lin[o * 2 + 1] * W2_post[832 + k]);
  } else if (id < n1 + 64 + 2 * 832 + 2) {
    int o = id - (n1 + 64 + 2 * 832);
    b2eff[o] = b2_lin[o] + W2_lin[o * 2 + 0] * b2_post[0] + W2_lin[o * 2 + 1] * b2_post[1];
  }
}

__global__ void hist_kernel(const int* __restrict__ dst, int* __restrict__ deg, int E) {
  int i = blockIdx.x * blockDim.x + threadIdx.x;
  if (i < E) atomicAdd(&deg[dst[i]], 1);
}

__global__ void avglog_kernel(const int* __restrict__ deg, float* __restrict__ out_sum, int n) {
  int i = blockIdx.x * blockDim.x + threadIdx.x;
  float v = (i < n) ? logf((float)deg[i] + 1.0f) : 0.0f;
  __shared__ float red[4];
  int lane = threadIdx.x & 63, wid = threadIdx.x >> 6;
  for (int off = 32; off; off >>= 1) v += __shfl_down(v, off);
  if (lane == 0) red[wid] = v;
  __syncthreads();
  if (threadIdx.x == 0) atomicAdd(out_sum, red[0] + red[1] + red[2] + red[3]);
}

// hierarchical scan
__global__ void scan1_kernel(const int* __restrict__ deg, int* __restrict__ excl,
                             int* __restrict__ partial, int n) {
  __shared__ int wsums[4];
  int tid = threadIdx.x, b = blockIdx.x;
  int i = b * 256 + tid;
  int lane = tid & 63, wid = tid >> 6;
  int v = (i < n) ? deg[i] : 0;
  int x = v;
  for (int off = 1; off < 64; off <<= 1) {
    int t = __shfl_up(x, off);
    if (lane >= off) x += t;
  }
  if (lane == 63) wsums[wid] = x;
  __syncthreads();
  int wo = 0;
#pragma unroll
  for (int j = 0; j < 4; ++j) wo += (j < wid) ? wsums[j] : 0;
  if (i < n) excl[i] = wo + x - v;
  if (tid == 255) partial[b] = wo + x;
}

__global__ void scan2_kernel(int* __restrict__ partial, int nb) {
  __shared__ int wsums[16];
  int tid = threadIdx.x;
  int lane = tid & 63, wid = tid >> 6;
  int v = (tid < nb) ? partial[tid] : 0;
  int x = v;
  for (int off = 1; off < 64; off <<= 1) {
    int t = __shfl_up(x, off);
    if (lane >= off) x += t;
  }
  if (lane == 63) wsums[wid] = x;
  __syncthreads();
  if (wid == 0) {
    int w2 = (lane < 16) ? wsums[lane] : 0;
    for (int off = 1; off < 16; off <<= 1) {
      int t = __shfl_up(w2, off);
      if (lane >= off) w2 += t;
    }
    if (lane < 16) wsums[lane] = w2;
  }
  __syncthreads();
  int wo = (wid > 0) ? wsums[wid - 1] : 0;
  if (tid < nb) partial[tid] = wo + x - v;
}

__global__ void scan3_kernel(const int* __restrict__ deg, const int* __restrict__ excl,
                             const int* __restrict__ partial, int* __restrict__ rowptr,
                             int* __restrict__ cursor, float* __restrict__ amp,
                             float* __restrict__ inv, const float* __restrict__ avgsum,
                             int n, int E) {
  int i = blockIdx.x * 256 + threadIdx.x;
  if (i < n) {
    int r = excl[i] + partial[blockIdx.x];
    rowptr[i] = r;
    cursor[i] = r;
    int v = deg[i];
    float dnm = (float)(v > 0 ? v : 1);
    float a = logf(dnm + 1.0f) * ((float)n / avgsum[0]);
    amp[i] = a;
    inv[i] = 1.0f / a;
  }
  if (i == 0) rowptr[n] = E;
}

__global__ void fill_kernel(const int* __restrict__ src, const int* __restrict__ dst,
                            int* __restrict__ cursor, int* __restrict__ col, int E) {
  int i = blockIdx.x * blockDim.x + threadIdx.x;
  if (i < E) {
    int d = dst[i];
    int pos = atomicAdd(&cursor[d], 1);
    col[pos] = src[i];
  }
}

// A = x @ Wl^T ; B = x @ Wr^T + b
__global__ void pre_kernel(const float* __restrict__ xin, const float* __restrict__ Wpre,
                           const float* __restrict__ bpre,
                           float* __restrict__ A, float* __restrict__ Bo, int n) {
  __shared__ float w[64 * 129];
  int tid = threadIdx.x;
  for (int i = tid; i < 64 * 128; i += 256) {
    int r = i >> 7, c = i & 127;
    w[r * 129 + c] = Wpre[i];
  }
  __syncthreads();
  int lane = tid & 63, wid = tid >> 6;
  float bias = bpre[lane];
  int stride = gridDim.x * 4;
  for (int node = blockIdx.x * 4 + wid; node < n; node += stride) {
    float xr = xin[(size_t)node * 64 + lane];
    float accA = 0.f, accB = 0.f;
#pragma unroll 8
    for (int k = 0; k < 64; ++k) {
      float xv = __shfl(xr, k);
      accA = fmaf(xv, w[lane * 129 + k], accA);
      accB = fmaf(xv, w[lane * 129 + 64 + k], accB);
    }
    A[(size_t)node * 64 + lane] = accA;
    Bo[(size_t)node * 64 + lane] = accB + bias;
  }
}

// wave per node: stats of B over in-neighbors; aggr[n][256] = [mean,mn,mx,std]
__global__ void aggr_kernel(const float* __restrict__ A, const float* __restrict__ B,
                            const int* __restrict__ rowptr, const int* __restrict__ col,
                            float* __restrict__ aggr, int n) {
  int tid = threadIdx.x;
  int lane = tid & 63, wid = tid >> 6;
  int stride = gridDim.x * 4;
  for (int node = blockIdx.x * 4 + wid; node < n; node += stride) {
    int s0 = rowptr[node], s1 = rowptr[node + 1];
    float sum = 0.f, sq = 0.f, mx = -3.4e38f, mn = 3.4e38f;
    int e = s0;
    for (; e + 4 <= s1; e += 4) {
      int i0 = col[e], i1 = col[e + 1], i2 = col[e + 2], i3 = col[e + 3];
      float b0 = B[(size_t)i0 * 64 + lane];
      float b1 = B[(size_t)i1 * 64 + lane];
      float b2 = B[(size_t)i2 * 64 + lane];
      float b3 = B[(size_t)i3 * 64 + lane];
      sum += b0 + b1 + b2 + b3;
      sq = fmaf(b0, b0, sq); sq = fmaf(b1, b1, sq);
      sq = fmaf(b2, b2, sq); sq = fmaf(b3, b3, sq);
      mx = fmaxf(mx, fmaxf(fmaxf(b0, b1), fmaxf(b2, b3)));
      mn = fminf(mn, fminf(fminf(b0, b1), fminf(b2, b3)));
    }
    for (; e < s1; ++e) {
      int s = col[e];
      float b = B[(size_t)s * 64 + lane];
      sum += b; sq = fmaf(b, b, sq);
      mx = fmaxf(mx, b); mn = fminf(mn, b);
    }
    int d = s1 - s0;
    float mean, mnv, mxv, sd;
    if (d > 0) {
      float idn = 1.0f / (float)d;
      float mB = sum * idn;
      float a = A[(size_t)node * 64 + lane];
      mean = a + mB;
      mnv = a + mn;
      mxv = a + mx;
      float var = fmaf(-mB, mB, sq * idn);
      sd = sqrtf(fmaxf(var, 0.0f) + 1e-5f);
    } else {
      mean = 0.f; mnv = 0.f; mxv = 0.f; sd = sqrtf(1e-5f);
    }
    size_t o = (size_t)node * 256 + lane;
    aggr[o] = mean; aggr[o + 64] = mnv; aggr[o + 128] = mxv; aggr[o + 192] = sd;
  }
}

// post1: h1 = relu( P + amp*Q + inv*R + beff ), P/Q/R = partial GEMMs.
// 128-row blocks, 4 waves (32 rows each), act tile hi/lo bf16 in LDS (XOR-swz),
// weights (bf16 hi/lo) streamed from L2.
__global__ __launch_bounds__(256, 3) void post1_kernel(
    const float* __restrict__ x, const float* __restrict__ aggr,
    const float* __restrict__ amp, const float* __restrict__ inv,
    const unsigned short* __restrict__ Wh, const unsigned short* __restrict__ Wl,
    const float* __restrict__ beff, float* __restrict__ h1, int n) {
  __shared__ unsigned short Ah[128 * 64];
  __shared__ unsigned short Al[128 * 64];
  int tid = threadIdx.x;
  int lane = tid & 63, w = tid >> 6;
  int row0 = blockIdx.x * 128;
  // staging ids: thread owns row sr, 32 cols at hf*32
  int sr = tid >> 1;
  int hf = tid & 1;
  int grow = row0 + sr;
  bool rok = grow < n;
  // mfma lane ids
  int ar = lane & 15;
  int klg = lane >> 4;           // k-group 0..3 (8 elems each)
  f32x4 accP[2][4], accQ[2][4], accR[2][4];
#pragma unroll
  for (int rf = 0; rf < 2; ++rf)
#pragma unroll
    for (int ct = 0; ct < 4; ++ct) {
      accP[rf][ct] = (f32x4){0.f, 0.f, 0.f, 0.f};
      accQ[rf][ct] = (f32x4){0.f, 0.f, 0.f, 0.f};
      accR[rf][ct] = (f32x4){0.f, 0.f, 0.f, 0.f};
    }

  // stage 128x64 f32 chunk -> Ah/Al bf16, truncation split, 16B-granule XOR swizzle
  auto stage = [&](const float* rowbase) {
    float v[32];
    if (rok) {
      const float4* p = (const float4*)(rowbase + hf * 32);
#pragma unroll
      for (int q = 0; q < 8; ++q) {
        float4 t = p[q];
        v[q * 4 + 0] = t.x; v[q * 4 + 1] = t.y; v[q * 4 + 2] = t.z; v[q * 4 + 3] = t.w;
      }
    } else {
#pragma unroll
      for (int j = 0; j < 32; ++j) v[j] = 0.f;
    }
    unsigned short hs[32], ls[32];
#pragma unroll
    for (int j = 0; j < 32; ++j) {
      unsigned int u = __float_as_uint(v[j]);
      unsigned int hu = u & 0xffff0000u;
      hs[j] = (unsigned short)(hu >> 16);
      float lf = v[j] - __uint_as_float(hu);
      ls[j] = (unsigned short)(__float_as_uint(lf) >> 16);
    }
    int rsw = sr & 7;
#pragma unroll
    for (int q = 0; q < 4; ++q) {
      int g = hf * 4 + q;
      int off = sr * 64 + (((g ^ rsw)) << 3);
      *(s16x8*)&Ah[off] = *(const s16x8*)&hs[q * 8];
      *(s16x8*)&Al[off] = *(const s16x8*)&ls[q * 8];
    }
  };

  // one 64-k chunk of MFMAs against weight cols kc..kc+63 into acc
  auto run = [&](f32x4 (&acc)[2][4], int kc) {
#pragma unroll
    for (int kk = 0; kk < 64; kk += 32) {
      s16x8 ah[2], al[2];
#pragma unroll
      for (int rf = 0; rf < 2; ++rf) {
        int lrow = w * 32 + rf * 16 + ar;
        int g = (kk >> 3) + klg;
        int off = lrow * 64 + ((g ^ (lrow & 7)) << 3);
        ah[rf] = *(const s16x8*)&Ah[off];
        al[rf] = *(const s16x8*)&Al[off];
      }
      int ko = kc + kk + klg * 8;
      s16x8 bh[4], bl[4];
#pragma unroll
      for (int ct = 0; ct < 4; ++ct) {
        size_t br = (size_t)(ct * 16 + ar) * 832 + ko;
        bh[ct] = *(const s16x8*)&Wh[br];
        bl[ct] = *(const s16x8*)&Wl[br];
      }
#pragma unroll
      for (int rf = 0; rf < 2; ++rf)
#pragma unroll
        for (int ct = 0; ct < 4; ++ct) {
          acc[rf][ct] = __builtin_amdgcn_mfma_f32_16x16x32_bf16(ah[rf], bh[ct], acc[rf][ct], 0, 0, 0);
          acc[rf][ct] = __builtin_amdgcn_mfma_f32_16x16x32_bf16(ah[rf], bl[ct], acc[rf][ct], 0, 0, 0);
          acc[rf][ct] = __builtin_amdgcn_mfma_f32_16x16x32_bf16(al[rf], bh[ct], acc[rf][ct], 0, 0, 0);
        }
    }
  };

  // x chunk (weight cols 0..63) -> P
  stage(x + (size_t)grow * 64);
  __syncthreads();
  run(accP, 0);
  // 4 aggr chunks; each staged once, run vs WA->P, WB->Q, WC->R
  for (int c = 0; c < 4; ++c) {
    __syncthreads();
    stage(aggr + (size_t)grow * 256 + c * 64);
    __syncthreads();
    run(accP, 64 + c * 64);
    run(accQ, 320 + c * 64);
    run(accR, 576 + c * 64);
  }
  // epilogue
#pragma unroll
  for (int rf = 0; rf < 2; ++rf)
#pragma unroll
    for (int i = 0; i < 4; ++i) {
      int r = row0 + w * 32 + rf * 16 + klg * 4 + i;
      if (r < n) {
        float av = amp[r], iv = inv[r];
#pragma unroll
        for (int ct = 0; ct < 4; ++ct) {
          int colo = ct * 16 + ar;
          float vv = accP[rf][ct][i] + av * accQ[rf][ct][i] + iv * accR[rf][ct][i] + beff[colo];
          h1[(size_t)r * 64 + colo] = fmaxf(vv, 0.f);
        }
      }
    }
}

// conv2 post: out[n][2], wave per node, shuffle reduce
__global__ void post2_kernel(const float* __restrict__ h1, const float* __restrict__ aggr,
                             const float* __restrict__ amp, const float* __restrict__ inv,
                             const float* __restrict__ W2eff, const float* __restrict__ b2eff,
                             float* __restrict__ out, int n) {
  int tid = threadIdx.x;
  int lane = tid & 63, wid = tid >> 6;
  int stride = gridDim.x * 4;
  for (int node = blockIdx.x * 4 + wid; node < n; node += stride) {
    float av = amp[node], iv = inv[node];
    float xv = h1[(size_t)node * 64 + lane];
    float p0 = W2eff[lane] * xv;
    float p1 = W2eff[832 + lane] * xv;
#pragma unroll
    for (int m = 0; m < 4; ++m) {
      int j = lane + 64 * m;
      float a = aggr[(size_t)node * 256 + j];
      float wA0 = W2eff[64 + j], wB0 = W2eff[320 + j], wC0 = W2eff[576 + j];
      float wA1 = W2eff[832 + 64 + j], wB1 = W2eff[832 + 320 + j], wC1 = W2eff[832 + 576 + j];
      p0 = fmaf(a, fmaf(av, wB0, fmaf(iv, wC0, wA0)), p0);
      p1 = fmaf(a, fmaf(av, wB1, fmaf(iv, wC1, wA1)), p1);
    }
    for (int off = 32; off; off >>= 1) {
      p0 += __shfl_down(p0, off);
      p1 += __shfl_down(p1, off);
    }
    if (lane == 0) {
      out[(size_t)node * 2 + 0] = p0 + b2eff[0];
      out[(size_t)node * 2 + 1] = p1 + b2eff[1];
    }
  }
}

extern "C" void kernel_launch(void* const* d_in, const int* in_sizes, int n_in,
                              void* d_out, int out_size, void* d_ws, size_t ws_size,
                              hipStream_t stream) {
  const float* x = (const float*)d_in[0];
  const int* ei = (const int*)d_in[1];
  const float* W1_pre = (const float*)d_in[2];
  const float* b1_pre = (const float*)d_in[3];
  const float* W1_post = (const float*)d_in[4];
  const float* b1_post = (const float*)d_in[5];
  const float* W1_lin = (const float*)d_in[6];
  const float* b1_lin = (const float*)d_in[7];
  const float* W2_pre = (const float*)d_in[8];
  const float* b2_pre = (const float*)d_in[9];
  const float* W2_post = (const float*)d_in[10];
  const float* b2_post = (const float*)d_in[11];
  const float* W2_lin = (const float*)d_in[12];
  const float* b2_lin = (const float*)d_in[13];

  const int N = in_sizes[0] / 64;
  const int E = in_sizes[1] / 2;
  const int* srcp = ei;
  const int* dstp = ei + E;
  const int nb = (N + 255) / 256;

  char* ws = (char*)d_ws;
  size_t off = 0;
  auto take = [&](size_t bytes) -> void* {
    void* p = ws + off;
    off = (off + bytes + 255) & ~(size_t)255;
    return p;
  };
  int* deg = (int*)take((size_t)N * 4);
  int* rowptr = (int*)take((size_t)(N + 1) * 4);
  int* cursor = (int*)take((size_t)N * 4);
  int* tmp = (int*)take((size_t)N * 4);
  int* partial = (int*)take(4096);
  float* amp = (float*)take((size_t)N * 4);
  float* inv = (float*)take((size_t)N * 4);
  float* avgsum = (float*)take(4);
  unsigned short* W1h = (unsigned short*)take((size_t)64 * 832 * 2);
  unsigned short* W1l = (unsigned short*)take((size_t)64 * 832 * 2);
  float* b1eff = (float*)take(64 * 4);
  float* W2eff = (float*)take((size_t)2 * 832 * 4);
  float* b2eff = (float*)take(2 * 4);
  int* col = (int*)take((size_t)E * 4);
  float* Abuf = (float*)take((size_t)N * 64 * 4);
  float* Bbuf = (float*)take((size_t)N * 64 * 4);
  float* aggr = (float*)take((size_t)N * 256 * 4);
  float* h1 = (float*)take((size_t)N * 64 * 4);
  (void)ws_size; (void)n_in; (void)out_size;

  hipMemsetAsync(deg, 0, (size_t)N * 4, stream);
  hipMemsetAsync(avgsum, 0, 4, stream);

  make_eff_kernel<<<(64 * 832 + 64 + 2 * 832 + 2 + 255) / 256, 256, 0, stream>>>(
      W1_post, b1_post, W1_lin, b1_lin, W2_post, b2_post, W2_lin, b2_lin,
      W1h, W1l, b1eff, W2eff, b2eff);
  hist_kernel<<<(E + 255) / 256, 256, 0, stream>>>(dstp, deg, E);
  avglog_kernel<<<(N + 255) / 256, 256, 0, stream>>>(deg, avgsum, N);
  scan1_kernel<<<nb, 256, 0, stream>>>(deg, tmp, partial, N);
  scan2_kernel<<<1, 1024, 0, stream>>>(partial, nb);
  scan3_kernel<<<nb, 256, 0, stream>>>(deg, tmp, partial, rowptr, cursor, amp, inv,
                                       avgsum, N, E);
  fill_kernel<<<(E + 255) / 256, 256, 0, stream>>>(srcp, dstp, cursor, col, E);

  // conv1
  pre_kernel<<<1024, 256, 0, stream>>>(x, W1_pre, b1_pre, Abuf, Bbuf, N);
  aggr_kernel<<<4096, 256, 0, stream>>>(Abuf, Bbuf, rowptr, col, aggr, N);
  post1_kernel<<<(N + 127) / 128, 256, 0, stream>>>(x, aggr, amp, inv, W1h, W1l, b1eff, h1, N);

  // conv2
  pre_kernel<<<1024, 256, 0, stream>>>(h1, W2_pre, b2_pre, Abuf, Bbuf, N);
  aggr_kernel<<<4096, 256, 0, stream>>>(Abuf, Bbuf, rowptr, col, aggr, N);
  post2_kernel<<<2048, 256, 0, stream>>>(h1, aggr, amp, inv, W2eff, b2eff, (float*)d_out, N);
}

// Round 4
// 778.908 us; speedup vs baseline: 1.2401x; 1.0063x over previous
//
#include <hip/hip_runtime.h>
#include <math.h>

// ---------------------------------------------------------------------------
// PNA (2 conv layers) on MI355X — fully fused per conv:
//   pre:  [A|B] = x @ [Wl|Wr]^T (+b on B)        (bf16-split MFMA GEMM)
//   fused_conv1: per-node stats of B over CSR (gather) -> LDS bf16 hi/lo ->
//                3-stream GEMM (P + amp*Q + inv*R) -> relu -> h1
//   fused_conv2: per-node stats + 2-col dot (wave reduce) -> out
// No aggr tensor is ever materialized (kills ~340MB/conv of HBM traffic).
// ---------------------------------------------------------------------------

typedef __attribute__((ext_vector_type(4))) float f32x4;
typedef __attribute__((ext_vector_type(8))) short s16x8;

__device__ inline unsigned short f2bf(float f) {
  unsigned int u = __float_as_uint(f);
  unsigned int r = u + 0x7fff + ((u >> 16) & 1);  // RNE
  return (unsigned short)(r >> 16);
}
__device__ inline float bf2f(unsigned short s) {
  return __uint_as_float(((unsigned int)s) << 16);
}
// truncation split: v = hi + rest, lo = bf16(rest)
__device__ inline void tsplit(float v, unsigned short& h, unsigned short& l) {
  unsigned int u = __float_as_uint(v);
  unsigned int hu = u & 0xffff0000u;
  h = (unsigned short)(hu >> 16);
  float lf = v - __uint_as_float(hu);
  l = (unsigned short)(__float_as_uint(lf) >> 16);
}

// sizes inside make_eff
#define ME_S0 (64 * 832)
#define ME_S1 (ME_S0 + 64)
#define ME_S2 (ME_S1 + 2 * 832)
#define ME_S3 (ME_S2 + 2)
#define ME_S4 (ME_S3 + 128 * 64)
#define ME_S5 (ME_S4 + 128 * 64)

__global__ void make_eff_kernel(const float* __restrict__ W1_post, const float* __restrict__ b1_post,
                                const float* __restrict__ W1_lin, const float* __restrict__ b1_lin,
                                const float* __restrict__ W2_post, const float* __restrict__ b2_post,
                                const float* __restrict__ W2_lin, const float* __restrict__ b2_lin,
                                const float* __restrict__ W1_pre, const float* __restrict__ W2_pre,
                                unsigned short* __restrict__ W1h, unsigned short* __restrict__ W1l,
                                float* __restrict__ b1eff,
                                float* __restrict__ W2eff, float* __restrict__ b2eff,
                                unsigned short* __restrict__ Wp1h, unsigned short* __restrict__ Wp1l,
                                unsigned short* __restrict__ Wp2h, unsigned short* __restrict__ Wp2l) {
  int id = blockIdx.x * blockDim.x + threadIdx.x;
  if (id < ME_S0) {
    int o = id / 832, k = id - o * 832;
    float s = 0.f;
#pragma unroll 8
    for (int j = 0; j < 64; ++j) s = fmaf(W1_lin[o * 64 + j], W1_post[j * 832 + k], s);
    unsigned short h = f2bf(s);
    W1h[id] = h;
    W1l[id] = f2bf(s - bf2f(h));
  } else if (id < ME_S1) {
    int o = id - ME_S0;
    float s = b1_lin[o];
    for (int j = 0; j < 64; ++j) s = fmaf(W1_lin[o * 64 + j], b1_post[j], s);
    b1eff[o] = s;
  } else if (id < ME_S2) {
    int t = id - ME_S1;
    int o = t / 832, k = t - o * 832;
    W2eff[t] = fmaf(W2_lin[o * 2 + 0], W2_post[k], W2_lin[o * 2 + 1] * W2_post[832 + k]);
  } else if (id < ME_S3) {
    int o = id - ME_S2;
    b2eff[o] = b2_lin[o] + W2_lin[o * 2 + 0] * b2_post[0] + W2_lin[o * 2 + 1] * b2_post[1];
  } else if (id < ME_S4) {
    int t = id - ME_S3;
    int c = t >> 6, k = t & 63;
    float v = (c < 64) ? W1_pre[c * 128 + k] : W1_pre[(c - 64) * 128 + 64 + k];
    unsigned short h = f2bf(v);
    Wp1h[t] = h;
    Wp1l[t] = f2bf(v - bf2f(h));
  } else if (id < ME_S5) {
    int t = id - ME_S4;
    int c = t >> 6, k = t & 63;
    float v = (c < 64) ? W2_pre[c * 128 + k] : W2_pre[(c - 64) * 128 + 64 + k];
    unsigned short h = f2bf(v);
    Wp2h[t] = h;
    Wp2l[t] = f2bf(v - bf2f(h));
  }
}

__global__ void hist_kernel(const int* __restrict__ dst, int* __restrict__ deg, int E) {
  int i = blockIdx.x * blockDim.x + threadIdx.x;
  if (i < E) atomicAdd(&deg[dst[i]], 1);
}

__global__ void avglog_kernel(const int* __restrict__ deg, float* __restrict__ out_sum, int n) {
  int i = blockIdx.x * blockDim.x + threadIdx.x;
  float v = (i < n) ? logf((float)deg[i] + 1.0f) : 0.0f;
  __shared__ float red[4];
  int lane = threadIdx.x & 63, wid = threadIdx.x >> 6;
  for (int off = 32; off; off >>= 1) v += __shfl_down(v, off);
  if (lane == 0) red[wid] = v;
  __syncthreads();
  if (threadIdx.x == 0) atomicAdd(out_sum, red[0] + red[1] + red[2] + red[3]);
}

__global__ void scan1_kernel(const int* __restrict__ deg, int* __restrict__ excl,
                             int* __restrict__ partial, int n) {
  __shared__ int wsums[4];
  int tid = threadIdx.x, b = blockIdx.x;
  int i = b * 256 + tid;
  int lane = tid & 63, wid = tid >> 6;
  int v = (i < n) ? deg[i] : 0;
  int x = v;
  for (int off = 1; off < 64; off <<= 1) {
    int t = __shfl_up(x, off);
    if (lane >= off) x += t;
  }
  if (lane == 63) wsums[wid] = x;
  __syncthreads();
  int wo = 0;
#pragma unroll
  for (int j = 0; j < 4; ++j) wo += (j < wid) ? wsums[j] : 0;
  if (i < n) excl[i] = wo + x - v;
  if (tid == 255) partial[b] = wo + x;
}

__global__ void scan2_kernel(int* __restrict__ partial, int nb) {
  __shared__ int wsums[16];
  int tid = threadIdx.x;
  int lane = tid & 63, wid = tid >> 6;
  int v = (tid < nb) ? partial[tid] : 0;
  int x = v;
  for (int off = 1; off < 64; off <<= 1) {
    int t = __shfl_up(x, off);
    if (lane >= off) x += t;
  }
  if (lane == 63) wsums[wid] = x;
  __syncthreads();
  if (wid == 0) {
    int w2 = (lane < 16) ? wsums[lane] : 0;
    for (int off = 1; off < 16; off <<= 1) {
      int t = __shfl_up(w2, off);
      if (lane >= off) w2 += t;
    }
    if (lane < 16) wsums[lane] = w2;
  }
  __syncthreads();
  int wo = (wid > 0) ? wsums[wid - 1] : 0;
  if (tid < nb) partial[tid] = wo + x - v;
}

__global__ void scan3_kernel(const int* __restrict__ deg, const int* __restrict__ excl,
                             const int* __restrict__ partial, int* __restrict__ rowptr,
                             int* __restrict__ cursor, float* __restrict__ amp,
                             float* __restrict__ inv, const float* __restrict__ avgsum,
                             int n, int E) {
  int i = blockIdx.x * 256 + threadIdx.x;
  if (i < n) {
    int r = excl[i] + partial[blockIdx.x];
    rowptr[i] = r;
    cursor[i] = r;
    int v = deg[i];
    float dnm = (float)(v > 0 ? v : 1);
    float a = logf(dnm + 1.0f) * ((float)n / avgsum[0]);
    amp[i] = a;
    inv[i] = 1.0f / a;
  }
  if (i == 0) rowptr[n] = E;
}

__global__ void fill_kernel(const int* __restrict__ src, const int* __restrict__ dst,
                            int* __restrict__ cursor, int* __restrict__ col, int E) {
  int i = blockIdx.x * blockDim.x + threadIdx.x;
  if (i < E) {
    int d = dst[i];
    int pos = atomicAdd(&cursor[d], 1);
    col[pos] = src[i];
  }
}

// [A|B] = x @ [Wl|Wr]^T, bias folded into B. bf16-split MFMA, 128-row blocks.
__global__ __launch_bounds__(256, 2) void pre_mfma(
    const float* __restrict__ xin, const unsigned short* __restrict__ Wh,
    const unsigned short* __restrict__ Wl, const float* __restrict__ bias,
    float* __restrict__ A, float* __restrict__ Bo, int n) {
  __shared__ __attribute__((aligned(16))) unsigned short XH[128 * 64];
  __shared__ __attribute__((aligned(16))) unsigned short XL[128 * 64];
  int tid = threadIdx.x;
  int lane = tid & 63, w = tid >> 6;
  int row0 = blockIdx.x * 128;
  int sr = tid >> 1, hf = tid & 1;
  int grow = row0 + sr;
  {
    float v[32];
    if (grow < n) {
      const float4* p = (const float4*)(xin + (size_t)grow * 64 + hf * 32);
#pragma unroll
      for (int q = 0; q < 8; ++q) {
        float4 t = p[q];
        v[q * 4 + 0] = t.x; v[q * 4 + 1] = t.y; v[q * 4 + 2] = t.z; v[q * 4 + 3] = t.w;
      }
    } else {
#pragma unroll
      for (int j = 0; j < 32; ++j) v[j] = 0.f;
    }
    unsigned short hs[32], ls[32];
#pragma unroll
    for (int j = 0; j < 32; ++j) tsplit(v[j], hs[j], ls[j]);
    int rsw = sr & 7;
#pragma unroll
    for (int q = 0; q < 4; ++q) {
      int g = hf * 4 + q;
      int off = sr * 64 + ((g ^ rsw) << 3);
      *(s16x8*)&XH[off] = *(const s16x8*)&hs[q * 8];
      *(s16x8*)&XL[off] = *(const s16x8*)&ls[q * 8];
    }
  }
  __syncthreads();
  int ar = lane & 15, klg = lane >> 4;
  f32x4 acc[2][8];
#pragma unroll
  for (int rf = 0; rf < 2; ++rf)
#pragma unroll
    for (int ct = 0; ct < 8; ++ct) acc[rf][ct] = (f32x4){0.f, 0.f, 0.f, 0.f};
#pragma unroll
  for (int kk = 0; kk < 64; kk += 32) {
    s16x8 ah[2], al[2];
#pragma unroll
    for (int rf = 0; rf < 2; ++rf) {
      int lrow = w * 32 + rf * 16 + ar;
      int g = (kk >> 3) + klg;
      int off = lrow * 64 + ((g ^ (lrow & 7)) << 3);
      ah[rf] = *(const s16x8*)&XH[off];
      al[rf] = *(const s16x8*)&XL[off];
    }
    int ko = kk + klg * 8;
#pragma unroll
    for (int ct = 0; ct < 8; ++ct) {
      size_t br = (size_t)(ct * 16 + ar) * 64 + ko;
      s16x8 bh = *(const s16x8*)&Wh[br];
      s16x8 bl = *(const s16x8*)&Wl[br];
#pragma unroll
      for (int rf = 0; rf < 2; ++rf) {
        acc[rf][ct] = __builtin_amdgcn_mfma_f32_16x16x32_bf16(ah[rf], bh, acc[rf][ct], 0, 0, 0);
        acc[rf][ct] = __builtin_amdgcn_mfma_f32_16x16x32_bf16(ah[rf], bl, acc[rf][ct], 0, 0, 0);
        acc[rf][ct] = __builtin_amdgcn_mfma_f32_16x16x32_bf16(al[rf], bh, acc[rf][ct], 0, 0, 0);
      }
    }
  }
#pragma unroll
  for (int rf = 0; rf < 2; ++rf)
#pragma unroll
    for (int i = 0; i < 4; ++i) {
      int r = row0 + w * 32 + rf * 16 + klg * 4 + i;
      if (r < n) {
#pragma unroll
        for (int ct = 0; ct < 8; ++ct) {
          int c = ct * 16 + ar;
          float vv = acc[rf][ct][i];
          if (ct < 4) A[(size_t)r * 64 + c] = vv;
          else Bo[(size_t)r * 64 + (c - 64)] = vv + bias[c - 64];
        }
      }
    }
}

// fused conv1: stats (gather) -> LDS bf16 hi/lo -> 3-stream GEMM -> relu -> h1
__global__ __launch_bounds__(512, 1) void fused_conv1(
    const float* __restrict__ x, const float* __restrict__ A,
    const float* __restrict__ B, const int* __restrict__ rowptr,
    const int* __restrict__ col, const float* __restrict__ amp,
    const float* __restrict__ inv, const unsigned short* __restrict__ Wh,
    const unsigned short* __restrict__ Wl, const float* __restrict__ beff,
    float* __restrict__ h1, int n) {
  __shared__ __attribute__((aligned(16))) unsigned short AggH[128 * 256];
  __shared__ __attribute__((aligned(16))) unsigned short AggL[128 * 256];
  int tid = threadIdx.x;
  int lane = tid & 63, w = tid >> 6;  // 8 waves
  int base = blockIdx.x * 128;
  // ---- phase 1: per-wave stats for its own 16 nodes ----
  for (int t = 0; t < 16; ++t) {
    int row = w * 16 + t;
    int node = base + row;
    float st0 = 0.f, st1 = 0.f, st2 = 0.f, st3 = 0.f;
    if (node < n) {
      int s0 = rowptr[node], s1 = rowptr[node + 1];
      float sum = 0.f, sq = 0.f, mx = -3.4e38f, mn = 3.4e38f;
      int e = s0;
      for (; e + 4 <= s1; e += 4) {
        int i0 = col[e], i1 = col[e + 1], i2 = col[e + 2], i3 = col[e + 3];
        float b0 = B[(size_t)i0 * 64 + lane];
        float b1 = B[(size_t)i1 * 64 + lane];
        float b2 = B[(size_t)i2 * 64 + lane];
        float b3 = B[(size_t)i3 * 64 + lane];
        sum += b0 + b1 + b2 + b3;
        sq = fmaf(b0, b0, sq); sq = fmaf(b1, b1, sq);
        sq = fmaf(b2, b2, sq); sq = fmaf(b3, b3, sq);
        mx = fmaxf(mx, fmaxf(fmaxf(b0, b1), fmaxf(b2, b3)));
        mn = fminf(mn, fminf(fminf(b0, b1), fminf(b2, b3)));
      }
      for (; e < s1; ++e) {
        int s = col[e];
        float b = B[(size_t)s * 64 + lane];
        sum += b; sq = fmaf(b, b, sq);
        mx = fmaxf(mx, b); mn = fminf(mn, b);
      }
      int d = s1 - s0;
      if (d > 0) {
        float idn = 1.0f / (float)d;
        float mB = sum * idn;
        float a = A[(size_t)node * 64 + lane];
        st0 = a + mB;
        st1 = a + mn;
        st2 = a + mx;
        float var = fmaf(-mB, mB, sq * idn);
        st3 = sqrtf(fmaxf(var, 0.0f) + 1e-5f);
      } else {
        st3 = sqrtf(1e-5f);
      }
    }
    int bidx = row * 256 + ((lane >> 3) ^ (row & 7)) * 8 + (lane & 7);
    float vals[4] = {st0, st1, st2, st3};
#pragma unroll
    for (int c = 0; c < 4; ++c) {
      unsigned short h, l;
      tsplit(vals[c], h, l);
      AggH[bidx + c * 64] = h;
      AggL[bidx + c * 64] = l;
    }
  }
  // ---- phase 2: per-wave GEMM on its own 16 rows (no barrier needed) ----
  int ar = lane & 15, klg = lane >> 4;
  int lrow = w * 16 + ar;
  int gr = base + lrow;
  f32x4 accP[4], accQ[4], accR[4];
#pragma unroll
  for (int ct = 0; ct < 4; ++ct) {
    accP[ct] = (f32x4){0.f, 0.f, 0.f, 0.f};
    accQ[ct] = (f32x4){0.f, 0.f, 0.f, 0.f};
    accR[ct] = (f32x4){0.f, 0.f, 0.f, 0.f};
  }
  // x stream (weight cols 0..63)
#pragma unroll
  for (int kk = 0; kk < 64; kk += 32) {
    unsigned short hs[8], ls[8];
    if (gr < n) {
      const float* p = x + (size_t)gr * 64 + kk + klg * 8;
      float4 v0 = *(const float4*)p;
      float4 v1 = *(const float4*)(p + 4);
      float vv[8] = {v0.x, v0.y, v0.z, v0.w, v1.x, v1.y, v1.z, v1.w};
#pragma unroll
      for (int j = 0; j < 8; ++j) tsplit(vv[j], hs[j], ls[j]);
    } else {
#pragma unroll
      for (int j = 0; j < 8; ++j) { hs[j] = 0; ls[j] = 0; }
    }
    s16x8 ah = *(const s16x8*)hs;
    s16x8 al = *(const s16x8*)ls;
    int ko = kk + klg * 8;
#pragma unroll
    for (int ct = 0; ct < 4; ++ct) {
      size_t br = (size_t)(ct * 16 + ar) * 832 + ko;
      s16x8 bh = *(const s16x8*)&Wh[br];
      s16x8 bl = *(const s16x8*)&Wl[br];
      accP[ct] = __builtin_amdgcn_mfma_f32_16x16x32_bf16(ah, bh, accP[ct], 0, 0, 0);
      accP[ct] = __builtin_amdgcn_mfma_f32_16x16x32_bf16(ah, bl, accP[ct], 0, 0, 0);
      accP[ct] = __builtin_amdgcn_mfma_f32_16x16x32_bf16(al, bh, accP[ct], 0, 0, 0);
    }
  }
  // aggr streams (P: cols 64.., Q: 320.., R: 576..)
#pragma unroll
  for (int c = 0; c < 4; ++c) {
#pragma unroll
    for (int kk = 0; kk < 64; kk += 32) {
      int g = ((kk >> 3) + klg) ^ (lrow & 7);
      int off = lrow * 256 + c * 64 + g * 8;
      s16x8 ah = *(const s16x8*)&AggH[off];
      s16x8 al = *(const s16x8*)&AggL[off];
      int ko = kk + klg * 8;
#pragma unroll
      for (int ct = 0; ct < 4; ++ct) {
        size_t rb = (size_t)(ct * 16 + ar) * 832 + c * 64 + ko;
        s16x8 bh = *(const s16x8*)&Wh[rb + 64];
        s16x8 bl = *(const s16x8*)&Wl[rb + 64];
        accP[ct] = __builtin_amdgcn_mfma_f32_16x16x32_bf16(ah, bh, accP[ct], 0, 0, 0);
        accP[ct] = __builtin_amdgcn_mfma_f32_16x16x32_bf16(ah, bl, accP[ct], 0, 0, 0);
        accP[ct] = __builtin_amdgcn_mfma_f32_16x16x32_bf16(al, bh, accP[ct], 0, 0, 0);
        bh = *(const s16x8*)&Wh[rb + 320];
        bl = *(const s16x8*)&Wl[rb + 320];
        accQ[ct] = __builtin_amdgcn_mfma_f32_16x16x32_bf16(ah, bh, accQ[ct], 0, 0, 0);
        accQ[ct] = __builtin_amdgcn_mfma_f32_16x16x32_bf16(ah, bl, accQ[ct], 0, 0, 0);
        accQ[ct] = __builtin_amdgcn_mfma_f32_16x16x32_bf16(al, bh, accQ[ct], 0, 0, 0);
        bh = *(const s16x8*)&Wh[rb + 576];
        bl = *(const s16x8*)&Wl[rb + 576];
        accR[ct] = __builtin_amdgcn_mfma_f32_16x16x32_bf16(ah, bh, accR[ct], 0, 0, 0);
        accR[ct] = __builtin_amdgcn_mfma_f32_16x16x32_bf16(ah, bl, accR[ct], 0, 0, 0);
        accR[ct] = __builtin_amdgcn_mfma_f32_16x16x32_bf16(al, bh, accR[ct], 0, 0, 0);
      }
    }
  }
  // epilogue
#pragma unroll
  for (int i = 0; i < 4; ++i) {
    int r = base + w * 16 + klg * 4 + i;
    if (r < n) {
      float av = amp[r], iv = inv[r];
#pragma unroll
      for (int ct = 0; ct < 4; ++ct) {
        int colo = ct * 16 + ar;
        float vv = accP[ct][i] + av * accQ[ct][i] + iv * accR[ct][i] + beff[colo];
        h1[(size_t)r * 64 + colo] = fmaxf(vv, 0.f);
      }
    }
  }
}

// fused conv2: per-node stats + 2-col dot, wave reduce
__global__ void fused_conv2(const float* __restrict__ h1, const float* __restrict__ A,
                            const float* __restrict__ B, const int* __restrict__ rowptr,
                            const int* __restrict__ col, const float* __restrict__ amp,
                            const float* __restrict__ inv, const float* __restrict__ W2eff,
                            const float* __restrict__ b2eff, float* __restrict__ out, int n) {
  int tid = threadIdx.x;
  int lane = tid & 63, wid = tid >> 6;
  int stride = gridDim.x * 4;
  for (int node = blockIdx.x * 4 + wid; node < n; node += stride) {
    int s0 = rowptr[node], s1 = rowptr[node + 1];
    float sum = 0.f, sq = 0.f, mx = -3.4e38f, mn = 3.4e38f;
    int e = s0;
    for (; e + 4 <= s1; e += 4) {
      int i0 = col[e], i1 = col[e + 1], i2 = col[e + 2], i3 = col[e + 3];
      float b0 = B[(size_t)i0 * 64 + lane];
      float b1 = B[(size_t)i1 * 64 + lane];
      float b2 = B[(size_t)i2 * 64 + lane];
      float b3 = B[(size_t)i3 * 64 + lane];
      sum += b0 + b1 + b2 + b3;
      sq = fmaf(b0, b0, sq); sq = fmaf(b1, b1, sq);
      sq = fmaf(b2, b2, sq); sq = fmaf(b3, b3, sq);
      mx = fmaxf(mx, fmaxf(fmaxf(b0, b1), fmaxf(b2, b3)));
      mn = fminf(mn, fminf(fminf(b0, b1), fminf(b2, b3)));
    }
    for (; e < s1; ++e) {
      int s = col[e];
      float b = B[(size_t)s * 64 + lane];
      sum += b; sq = fmaf(b, b, sq);
      mx = fmaxf(mx, b); mn = fminf(mn, b);
    }
    int d = s1 - s0;
    float st[4];
    if (d > 0) {
      float idn = 1.0f / (float)d;
      float mB = sum * idn;
      float a = A[(size_t)node * 64 + lane];
      st[0] = a + mB;
      st[1] = a + mn;
      st[2] = a + mx;
      float var = fmaf(-mB, mB, sq * idn);
      st[3] = sqrtf(fmaxf(var, 0.0f) + 1e-5f);
    } else {
      st[0] = 0.f; st[1] = 0.f; st[2] = 0.f; st[3] = sqrtf(1e-5f);
    }
    float av = amp[node], iv = inv[node];
    float xv = h1[(size_t)node * 64 + lane];
    float p0 = W2eff[lane] * xv;
    float p1 = W2eff[832 + lane] * xv;
#pragma unroll
    for (int m = 0; m < 4; ++m) {
      int j = m * 64 + lane;
      p0 = fmaf(st[m], fmaf(av, W2eff[320 + j], fmaf(iv, W2eff[576 + j], W2eff[64 + j])), p0);
      p1 = fmaf(st[m], fmaf(av, W2eff[832 + 320 + j], fmaf(iv, W2eff[832 + 576 + j], W2eff[832 + 64 + j])), p1);
    }
    for (int off = 32; off; off >>= 1) {
      p0 += __shfl_down(p0, off);
      p1 += __shfl_down(p1, off);
    }
    if (lane == 0) {
      out[(size_t)node * 2 + 0] = p0 + b2eff[0];
      out[(size_t)node * 2 + 1] = p1 + b2eff[1];
    }
  }
}

extern "C" void kernel_launch(void* const* d_in, const int* in_sizes, int n_in,
                              void* d_out, int out_size, void* d_ws, size_t ws_size,
                              hipStream_t stream) {
  const float* x = (const float*)d_in[0];
  const int* ei = (const int*)d_in[1];
  const float* W1_pre = (const float*)d_in[2];
  const float* b1_pre = (const float*)d_in[3];
  const float* W1_post = (const float*)d_in[4];
  const float* b1_post = (const float*)d_in[5];
  const float* W1_lin = (const float*)d_in[6];
  const float* b1_lin = (const float*)d_in[7];
  const float* W2_pre = (const float*)d_in[8];
  const float* b2_pre = (const float*)d_in[9];
  const float* W2_post = (const float*)d_in[10];
  const float* b2_post = (const float*)d_in[11];
  const float* W2_lin = (const float*)d_in[12];
  const float* b2_lin = (const float*)d_in[13];

  const int N = in_sizes[0] / 64;
  const int E = in_sizes[1] / 2;
  const int* srcp = ei;
  const int* dstp = ei + E;
  const int nb = (N + 255) / 256;

  char* ws = (char*)d_ws;
  size_t off = 0;
  auto take = [&](size_t bytes) -> void* {
    void* p = ws + off;
    off = (off + bytes + 255) & ~(size_t)255;
    return p;
  };
  int* deg = (int*)take((size_t)N * 4);
  int* rowptr = (int*)take((size_t)(N + 1) * 4);
  int* cursor = (int*)take((size_t)N * 4);
  int* tmp = (int*)take((size_t)N * 4);
  int* partial = (int*)take(4096);
  float* amp = (float*)take((size_t)N * 4);
  float* inv = (float*)take((size_t)N * 4);
  float* avgsum = (float*)take(4);
  unsigned short* W1h = (unsigned short*)take((size_t)64 * 832 * 2);
  unsigned short* W1l = (unsigned short*)take((size_t)64 * 832 * 2);
  float* b1eff = (float*)take(64 * 4);
  float* W2eff = (float*)take((size_t)2 * 832 * 4);
  float* b2eff = (float*)take(2 * 4);
  unsigned short* Wp1h = (unsigned short*)take((size_t)128 * 64 * 2);
  unsigned short* Wp1l = (unsigned short*)take((size_t)128 * 64 * 2);
  unsigned short* Wp2h = (unsigned short*)take((size_t)128 * 64 * 2);
  unsigned short* Wp2l = (unsigned short*)take((size_t)128 * 64 * 2);
  int* col = (int*)take((size_t)E * 4);
  float* Abuf = (float*)take((size_t)N * 64 * 4);
  float* Bbuf = (float*)take((size_t)N * 64 * 4);
  float* h1 = (float*)take((size_t)N * 64 * 4);
  (void)ws_size; (void)n_in; (void)out_size;

  hipMemsetAsync(deg, 0, (size_t)N * 4, stream);
  hipMemsetAsync(avgsum, 0, 4, stream);

  make_eff_kernel<<<(ME_S5 + 255) / 256, 256, 0, stream>>>(
      W1_post, b1_post, W1_lin, b1_lin, W2_post, b2_post, W2_lin, b2_lin,
      W1_pre, W2_pre, W1h, W1l, b1eff, W2eff, b2eff, Wp1h, Wp1l, Wp2h, Wp2l);
  hist_kernel<<<(E + 255) / 256, 256, 0, stream>>>(dstp, deg, E);
  avglog_kernel<<<(N + 255) / 256, 256, 0, stream>>>(deg, avgsum, N);
  scan1_kernel<<<nb, 256, 0, stream>>>(deg, tmp, partial, N);
  scan2_kernel<<<1, 1024, 0, stream>>>(partial, nb);
  scan3_kernel<<<nb, 256, 0, stream>>>(deg, tmp, partial, rowptr, cursor, amp, inv,
                                       avgsum, N, E);
  fill_kernel<<<(E + 255) / 256, 256, 0, stream>>>(srcp, dstp, cursor, col, E);

  // conv1
  pre_mfma<<<(N + 127) / 128, 256, 0, stream>>>(x, Wp1h, Wp1l, b1_pre, Abuf, Bbuf, N);
  fused_conv1<<<(N + 127) / 128, 512, 0, stream>>>(x, Abuf, Bbuf, rowptr, col, amp, inv,
                                                   W1h, W1l, b1eff, h1, N);
  // conv2
  pre_mfma<<<(N + 127) / 128, 256, 0, stream>>>(h1, Wp2h, Wp2l, b2_pre, Abuf, Bbuf, N);
  fused_conv2<<<4096, 256, 0, stream>>>(h1, Abuf, Bbuf, rowptr, col, amp, inv,
                                        W2eff, b2eff, (float*)d_out, N);
}

// Round 5
// 549.393 us; speedup vs baseline: 1.7582x; 1.4178x over previous
//
#include <hip/hip_runtime.h>
#include <math.h>

// ---------------------------------------------------------------------------
// PNA (2 conv layers) on MI355X.
//   pre:  [A|B] = x @ [Wl|Wr]^T (+b on B)        (bf16-split MFMA GEMM)
//   aggr_pack: wave/node CSR gather stats of B (8-deep pipeline) ->
//              packed bf16 hi/lo aggr[N][256]
//   post1: no-LDS bf16-split MFMA GEMM: relu(P + amp*Q + inv*R + beff)
//   fused_conv2: wave/node stats + 2-col dot (no aggr materialization)
// ---------------------------------------------------------------------------

typedef __attribute__((ext_vector_type(4))) float f32x4;
typedef __attribute__((ext_vector_type(8))) short s16x8;

__device__ inline unsigned short f2bf(float f) {
  unsigned int u = __float_as_uint(f);
  unsigned int r = u + 0x7fff + ((u >> 16) & 1);  // RNE
  return (unsigned short)(r >> 16);
}
__device__ inline float bf2f(unsigned short s) {
  return __uint_as_float(((unsigned int)s) << 16);
}
// truncation split: v = hi + rest, lo = bf16(rest)
__device__ inline void tsplit(float v, unsigned short& h, unsigned short& l) {
  unsigned int u = __float_as_uint(v);
  unsigned int hu = u & 0xffff0000u;
  h = (unsigned short)(hu >> 16);
  float lf = v - __uint_as_float(hu);
  l = (unsigned short)(__float_as_uint(lf) >> 16);
}

#define ME_S0 (64 * 832)
#define ME_S1 (ME_S0 + 64)
#define ME_S2 (ME_S1 + 2 * 832)
#define ME_S3 (ME_S2 + 2)
#define ME_S4 (ME_S3 + 128 * 64)
#define ME_S5 (ME_S4 + 128 * 64)

__global__ void make_eff_kernel(const float* __restrict__ W1_post, const float* __restrict__ b1_post,
                                const float* __restrict__ W1_lin, const float* __restrict__ b1_lin,
                                const float* __restrict__ W2_post, const float* __restrict__ b2_post,
                                const float* __restrict__ W2_lin, const float* __restrict__ b2_lin,
                                const float* __restrict__ W1_pre, const float* __restrict__ W2_pre,
                                unsigned short* __restrict__ W1h, unsigned short* __restrict__ W1l,
                                float* __restrict__ b1eff,
                                float* __restrict__ W2eff, float* __restrict__ b2eff,
                                unsigned short* __restrict__ Wp1h, unsigned short* __restrict__ Wp1l,
                                unsigned short* __restrict__ Wp2h, unsigned short* __restrict__ Wp2l) {
  int id = blockIdx.x * blockDim.x + threadIdx.x;
  if (id < ME_S0) {
    int o = id / 832, k = id - o * 832;
    float s = 0.f;
#pragma unroll 8
    for (int j = 0; j < 64; ++j) s = fmaf(W1_lin[o * 64 + j], W1_post[j * 832 + k], s);
    unsigned short h = f2bf(s);
    W1h[id] = h;
    W1l[id] = f2bf(s - bf2f(h));
  } else if (id < ME_S1) {
    int o = id - ME_S0;
    float s = b1_lin[o];
    for (int j = 0; j < 64; ++j) s = fmaf(W1_lin[o * 64 + j], b1_post[j], s);
    b1eff[o] = s;
  } else if (id < ME_S2) {
    int t = id - ME_S1;
    int o = t / 832, k = t - o * 832;
    W2eff[t] = fmaf(W2_lin[o * 2 + 0], W2_post[k], W2_lin[o * 2 + 1] * W2_post[832 + k]);
  } else if (id < ME_S3) {
    int o = id - ME_S2;
    b2eff[o] = b2_lin[o] + W2_lin[o * 2 + 0] * b2_post[0] + W2_lin[o * 2 + 1] * b2_post[1];
  } else if (id < ME_S4) {
    int t = id - ME_S3;
    int c = t >> 6, k = t & 63;
    float v = (c < 64) ? W1_pre[c * 128 + k] : W1_pre[(c - 64) * 128 + 64 + k];
    unsigned short h = f2bf(v);
    Wp1h[t] = h;
    Wp1l[t] = f2bf(v - bf2f(h));
  } else if (id < ME_S5) {
    int t = id - ME_S4;
    int c = t >> 6, k = t & 63;
    float v = (c < 64) ? W2_pre[c * 128 + k] : W2_pre[(c - 64) * 128 + 64 + k];
    unsigned short h = f2bf(v);
    Wp2h[t] = h;
    Wp2l[t] = f2bf(v - bf2f(h));
  }
}

__global__ void hist_kernel(const int* __restrict__ dst, int* __restrict__ deg, int E) {
  int i = blockIdx.x * blockDim.x + threadIdx.x;
  if (i < E) atomicAdd(&deg[dst[i]], 1);
}

__global__ void avglog_kernel(const int* __restrict__ deg, float* __restrict__ out_sum, int n) {
  int i = blockIdx.x * blockDim.x + threadIdx.x;
  float v = (i < n) ? logf((float)deg[i] + 1.0f) : 0.0f;
  __shared__ float red[4];
  int lane = threadIdx.x & 63, wid = threadIdx.x >> 6;
  for (int off = 32; off; off >>= 1) v += __shfl_down(v, off);
  if (lane == 0) red[wid] = v;
  __syncthreads();
  if (threadIdx.x == 0) atomicAdd(out_sum, red[0] + red[1] + red[2] + red[3]);
}

__global__ void scan1_kernel(const int* __restrict__ deg, int* __restrict__ excl,
                             int* __restrict__ partial, int n) {
  __shared__ int wsums[4];
  int tid = threadIdx.x, b = blockIdx.x;
  int i = b * 256 + tid;
  int lane = tid & 63, wid = tid >> 6;
  int v = (i < n) ? deg[i] : 0;
  int x = v;
  for (int off = 1; off < 64; off <<= 1) {
    int t = __shfl_up(x, off);
    if (lane >= off) x += t;
  }
  if (lane == 63) wsums[wid] = x;
  __syncthreads();
  int wo = 0;
#pragma unroll
  for (int j = 0; j < 4; ++j) wo += (j < wid) ? wsums[j] : 0;
  if (i < n) excl[i] = wo + x - v;
  if (tid == 255) partial[b] = wo + x;
}

__global__ void scan2_kernel(int* __restrict__ partial, int nb) {
  __shared__ int wsums[16];
  int tid = threadIdx.x;
  int lane = tid & 63, wid = tid >> 6;
  int v = (tid < nb) ? partial[tid] : 0;
  int x = v;
  for (int off = 1; off < 64; off <<= 1) {
    int t = __shfl_up(x, off);
    if (lane >= off) x += t;
  }
  if (lane == 63) wsums[wid] = x;
  __syncthreads();
  if (wid == 0) {
    int w2 = (lane < 16) ? wsums[lane] : 0;
    for (int off = 1; off < 16; off <<= 1) {
      int t = __shfl_up(w2, off);
      if (lane >= off) w2 += t;
    }
    if (lane < 16) wsums[lane] = w2;
  }
  __syncthreads();
  int wo = (wid > 0) ? wsums[wid - 1] : 0;
  if (tid < nb) partial[tid] = wo + x - v;
}

__global__ void scan3_kernel(const int* __restrict__ deg, const int* __restrict__ excl,
                             const int* __restrict__ partial, int* __restrict__ rowptr,
                             int* __restrict__ cursor, float* __restrict__ amp,
                             float* __restrict__ inv, const float* __restrict__ avgsum,
                             int n, int E) {
  int i = blockIdx.x * 256 + threadIdx.x;
  if (i < n) {
    int r = excl[i] + partial[blockIdx.x];
    rowptr[i] = r;
    cursor[i] = r;
    int v = deg[i];
    float dnm = (float)(v > 0 ? v : 1);
    float a = logf(dnm + 1.0f) * ((float)n / avgsum[0]);
    amp[i] = a;
    inv[i] = 1.0f / a;
  }
  if (i == 0) rowptr[n] = E;
}

__global__ void fill_kernel(const int* __restrict__ src, const int* __restrict__ dst,
                            int* __restrict__ cursor, int* __restrict__ col, int E) {
  int i = blockIdx.x * blockDim.x + threadIdx.x;
  if (i < E) {
    int d = dst[i];
    int pos = atomicAdd(&cursor[d], 1);
    col[pos] = src[i];
  }
}

// [A|B] = x @ [Wl|Wr]^T, bias folded into B. bf16-split MFMA, 128-row blocks.
__global__ __launch_bounds__(256, 2) void pre_mfma(
    const float* __restrict__ xin, const unsigned short* __restrict__ Wh,
    const unsigned short* __restrict__ Wl, const float* __restrict__ bias,
    float* __restrict__ A, float* __restrict__ Bo, int n) {
  __shared__ __attribute__((aligned(16))) unsigned short XH[128 * 64];
  __shared__ __attribute__((aligned(16))) unsigned short XL[128 * 64];
  int tid = threadIdx.x;
  int lane = tid & 63, w = tid >> 6;
  int row0 = blockIdx.x * 128;
  int sr = tid >> 1, hf = tid & 1;
  int grow = row0 + sr;
  {
    float v[32];
    if (grow < n) {
      const float4* p = (const float4*)(xin + (size_t)grow * 64 + hf * 32);
#pragma unroll
      for (int q = 0; q < 8; ++q) {
        float4 t = p[q];
        v[q * 4 + 0] = t.x; v[q * 4 + 1] = t.y; v[q * 4 + 2] = t.z; v[q * 4 + 3] = t.w;
      }
    } else {
#pragma unroll
      for (int j = 0; j < 32; ++j) v[j] = 0.f;
    }
    unsigned short hs[32], ls[32];
#pragma unroll
    for (int j = 0; j < 32; ++j) tsplit(v[j], hs[j], ls[j]);
    int rsw = sr & 7;
#pragma unroll
    for (int q = 0; q < 4; ++q) {
      int g = hf * 4 + q;
      int off = sr * 64 + ((g ^ rsw) << 3);
      *(s16x8*)&XH[off] = *(const s16x8*)&hs[q * 8];
      *(s16x8*)&XL[off] = *(const s16x8*)&ls[q * 8];
    }
  }
  __syncthreads();
  int ar = lane & 15, klg = lane >> 4;
  f32x4 acc[2][8];
#pragma unroll
  for (int rf = 0; rf < 2; ++rf)
#pragma unroll
    for (int ct = 0; ct < 8; ++ct) acc[rf][ct] = (f32x4){0.f, 0.f, 0.f, 0.f};
#pragma unroll
  for (int kk = 0; kk < 64; kk += 32) {
    s16x8 ah[2], al[2];
#pragma unroll
    for (int rf = 0; rf < 2; ++rf) {
      int lrow = w * 32 + rf * 16 + ar;
      int g = (kk >> 3) + klg;
      int off = lrow * 64 + ((g ^ (lrow & 7)) << 3);
      ah[rf] = *(const s16x8*)&XH[off];
      al[rf] = *(const s16x8*)&XL[off];
    }
    int ko = kk + klg * 8;
#pragma unroll
    for (int ct = 0; ct < 8; ++ct) {
      size_t br = (size_t)(ct * 16 + ar) * 64 + ko;
      s16x8 bh = *(const s16x8*)&Wh[br];
      s16x8 bl = *(const s16x8*)&Wl[br];
#pragma unroll
      for (int rf = 0; rf < 2; ++rf) {
        acc[rf][ct] = __builtin_amdgcn_mfma_f32_16x16x32_bf16(ah[rf], bh, acc[rf][ct], 0, 0, 0);
        acc[rf][ct] = __builtin_amdgcn_mfma_f32_16x16x32_bf16(ah[rf], bl, acc[rf][ct], 0, 0, 0);
        acc[rf][ct] = __builtin_amdgcn_mfma_f32_16x16x32_bf16(al[rf], bh, acc[rf][ct], 0, 0, 0);
      }
    }
  }
#pragma unroll
  for (int rf = 0; rf < 2; ++rf)
#pragma unroll
    for (int i = 0; i < 4; ++i) {
      int r = row0 + w * 32 + rf * 16 + klg * 4 + i;
      if (r < n) {
#pragma unroll
        for (int ct = 0; ct < 8; ++ct) {
          int c = ct * 16 + ar;
          float vv = acc[rf][ct][i];
          if (ct < 4) A[(size_t)r * 64 + c] = vv;
          else Bo[(size_t)r * 64 + (c - 64)] = vv + bias[c - 64];
        }
      }
    }
}

// wave per node: CSR gather stats of B, 8-deep load pipeline; writes packed
// bf16 hi/lo aggr: AggH/AggL[node*256 + c*64 + feat], c = mean,min,max,std
__global__ __launch_bounds__(256) void aggr_pack(
    const float* __restrict__ A, const float* __restrict__ B,
    const int* __restrict__ rowptr, const int* __restrict__ col,
    unsigned short* __restrict__ AggH, unsigned short* __restrict__ AggL, int n) {
  int tid = threadIdx.x;
  int lane = tid & 63, wid = tid >> 6;
  int node = blockIdx.x * 4 + wid;
  if (node >= n) return;
  int s0 = rowptr[node], s1 = rowptr[node + 1];
  float a = A[(size_t)node * 64 + lane];
  float sum = 0.f, sq = 0.f, mx = -3.4e38f, mn = 3.4e38f;
  int e = s0;
  for (; e + 8 <= s1; e += 8) {
    int i0 = col[e], i1 = col[e + 1], i2 = col[e + 2], i3 = col[e + 3];
    int i4 = col[e + 4], i5 = col[e + 5], i6 = col[e + 6], i7 = col[e + 7];
    float b0 = B[(size_t)i0 * 64 + lane];
    float b1 = B[(size_t)i1 * 64 + lane];
    float b2 = B[(size_t)i2 * 64 + lane];
    float b3 = B[(size_t)i3 * 64 + lane];
    float b4 = B[(size_t)i4 * 64 + lane];
    float b5 = B[(size_t)i5 * 64 + lane];
    float b6 = B[(size_t)i6 * 64 + lane];
    float b7 = B[(size_t)i7 * 64 + lane];
    sum += ((b0 + b1) + (b2 + b3)) + ((b4 + b5) + (b6 + b7));
    sq = fmaf(b0, b0, sq); sq = fmaf(b1, b1, sq);
    sq = fmaf(b2, b2, sq); sq = fmaf(b3, b3, sq);
    sq = fmaf(b4, b4, sq); sq = fmaf(b5, b5, sq);
    sq = fmaf(b6, b6, sq); sq = fmaf(b7, b7, sq);
    mx = fmaxf(mx, fmaxf(fmaxf(b0, b1), fmaxf(b2, b3)));
    mx = fmaxf(mx, fmaxf(fmaxf(b4, b5), fmaxf(b6, b7)));
    mn = fminf(mn, fminf(fminf(b0, b1), fminf(b2, b3)));
    mn = fminf(mn, fminf(fminf(b4, b5), fminf(b6, b7)));
  }
  for (; e < s1; ++e) {
    int s = col[e];
    float b = B[(size_t)s * 64 + lane];
    sum += b; sq = fmaf(b, b, sq);
    mx = fmaxf(mx, b); mn = fminf(mn, b);
  }
  int d = s1 - s0;
  float st[4];
  if (d > 0) {
    float idn = 1.0f / (float)d;
    float mB = sum * idn;
    st[0] = a + mB;
    st[1] = a + mn;
    st[2] = a + mx;
    float var = fmaf(-mB, mB, sq * idn);
    st[3] = sqrtf(fmaxf(var, 0.0f) + 1e-5f);
  } else {
    st[0] = 0.f; st[1] = 0.f; st[2] = 0.f; st[3] = sqrtf(1e-5f);
  }
  size_t o = (size_t)node * 256 + lane;
#pragma unroll
  for (int c = 0; c < 4; ++c) {
    unsigned short h, l;
    tsplit(st[c], h, l);
    AggH[o + c * 64] = h;
    AggL[o + c * 64] = l;
  }
}

// post1: no-LDS bf16-split MFMA GEMM. 128-row blocks, 4 waves x 32 rows.
// A-frags come directly from x (tsplit inline) and packed AggH/AggL.
__global__ __launch_bounds__(256) void post1_kernel(
    const float* __restrict__ x,
    const unsigned short* __restrict__ AggH, const unsigned short* __restrict__ AggL,
    const float* __restrict__ amp, const float* __restrict__ inv,
    const unsigned short* __restrict__ Wh, const unsigned short* __restrict__ Wl,
    const float* __restrict__ beff, float* __restrict__ h1, int n) {
  int tid = threadIdx.x;
  int lane = tid & 63, w = tid >> 6;
  int row0 = blockIdx.x * 128;
  int ar = lane & 15, klg = lane >> 4;
  int grow[2];
  bool rok[2];
#pragma unroll
  for (int rf = 0; rf < 2; ++rf) {
    grow[rf] = row0 + w * 32 + rf * 16 + ar;
    rok[rf] = grow[rf] < n;
  }
  f32x4 accP[2][4], accQ[2][4], accR[2][4];
#pragma unroll
  for (int rf = 0; rf < 2; ++rf)
#pragma unroll
    for (int ct = 0; ct < 4; ++ct) {
      accP[rf][ct] = (f32x4){0.f, 0.f, 0.f, 0.f};
      accQ[rf][ct] = (f32x4){0.f, 0.f, 0.f, 0.f};
      accR[rf][ct] = (f32x4){0.f, 0.f, 0.f, 0.f};
    }
  // ---- x stream (weight cols 0..63) ----
#pragma unroll
  for (int kk = 0; kk < 64; kk += 32) {
    s16x8 ah[2], al[2];
#pragma unroll
    for (int rf = 0; rf < 2; ++rf) {
      unsigned short hs[8], ls[8];
      if (rok[rf]) {
        const float* p = x + (size_t)grow[rf] * 64 + kk + klg * 8;
        float4 v0 = *(const float4*)p;
        float4 v1 = *(const float4*)(p + 4);
        float vv[8] = {v0.x, v0.y, v0.z, v0.w, v1.x, v1.y, v1.z, v1.w};
#pragma unroll
        for (int j = 0; j < 8; ++j) tsplit(vv[j], hs[j], ls[j]);
      } else {
#pragma unroll
        for (int j = 0; j < 8; ++j) { hs[j] = 0; ls[j] = 0; }
      }
      ah[rf] = *(const s16x8*)hs;
      al[rf] = *(const s16x8*)ls;
    }
    int ko = kk + klg * 8;
#pragma unroll
    for (int ct = 0; ct < 4; ++ct) {
      size_t br = (size_t)(ct * 16 + ar) * 832 + ko;
      s16x8 bh = *(const s16x8*)&Wh[br];
      s16x8 bl = *(const s16x8*)&Wl[br];
#pragma unroll
      for (int rf = 0; rf < 2; ++rf) {
        accP[rf][ct] = __builtin_amdgcn_mfma_f32_16x16x32_bf16(ah[rf], bh, accP[rf][ct], 0, 0, 0);
        accP[rf][ct] = __builtin_amdgcn_mfma_f32_16x16x32_bf16(ah[rf], bl, accP[rf][ct], 0, 0, 0);
        accP[rf][ct] = __builtin_amdgcn_mfma_f32_16x16x32_bf16(al[rf], bh, accP[rf][ct], 0, 0, 0);
      }
    }
  }
  // ---- aggr streams: P (cols 64+), Q (+256), R (+512) ----
#pragma unroll
  for (int c = 0; c < 4; ++c) {
#pragma unroll
    for (int kk = 0; kk < 64; kk += 32) {
      s16x8 ah[2], al[2];
#pragma unroll
      for (int rf = 0; rf < 2; ++rf) {
        if (rok[rf]) {
          size_t ao = (size_t)grow[rf] * 256 + c * 64 + kk + klg * 8;
          ah[rf] = *(const s16x8*)&AggH[ao];
          al[rf] = *(const s16x8*)&AggL[ao];
        } else {
          ah[rf] = (s16x8){0, 0, 0, 0, 0, 0, 0, 0};
          al[rf] = (s16x8){0, 0, 0, 0, 0, 0, 0, 0};
        }
      }
      int kofs = 64 + c * 64 + kk + klg * 8;
#pragma unroll
      for (int ct = 0; ct < 4; ++ct) {
        size_t br = (size_t)(ct * 16 + ar) * 832 + kofs;
        s16x8 bh = *(const s16x8*)&Wh[br];
        s16x8 bl = *(const s16x8*)&Wl[br];
#pragma unroll
        for (int rf = 0; rf < 2; ++rf) {
          accP[rf][ct] = __builtin_amdgcn_mfma_f32_16x16x32_bf16(ah[rf], bh, accP[rf][ct], 0, 0, 0);
          accP[rf][ct] = __builtin_amdgcn_mfma_f32_16x16x32_bf16(ah[rf], bl, accP[rf][ct], 0, 0, 0);
          accP[rf][ct] = __builtin_amdgcn_mfma_f32_16x16x32_bf16(al[rf], bh, accP[rf][ct], 0, 0, 0);
        }
        bh = *(const s16x8*)&Wh[br + 256];
        bl = *(const s16x8*)&Wl[br + 256];
#pragma unroll
        for (int rf = 0; rf < 2; ++rf) {
          accQ[rf][ct] = __builtin_amdgcn_mfma_f32_16x16x32_bf16(ah[rf], bh, accQ[rf][ct], 0, 0, 0);
          accQ[rf][ct] = __builtin_amdgcn_mfma_f32_16x16x32_bf16(ah[rf], bl, accQ[rf][ct], 0, 0, 0);
          accQ[rf][ct] = __builtin_amdgcn_mfma_f32_16x16x32_bf16(al[rf], bh, accQ[rf][ct], 0, 0, 0);
        }
        bh = *(const s16x8*)&Wh[br + 512];
        bl = *(const s16x8*)&Wl[br + 512];
#pragma unroll
        for (int rf = 0; rf < 2; ++rf) {
          accR[rf][ct] = __builtin_amdgcn_mfma_f32_16x16x32_bf16(ah[rf], bh, accR[rf][ct], 0, 0, 0);
          accR[rf][ct] = __builtin_amdgcn_mfma_f32_16x16x32_bf16(ah[rf], bl, accR[rf][ct], 0, 0, 0);
          accR[rf][ct] = __builtin_amdgcn_mfma_f32_16x16x32_bf16(al[rf], bh, accR[rf][ct], 0, 0, 0);
        }
      }
    }
  }
  // epilogue
#pragma unroll
  for (int rf = 0; rf < 2; ++rf)
#pragma unroll
    for (int i = 0; i < 4; ++i) {
      int r = row0 + w * 32 + rf * 16 + klg * 4 + i;
      if (r < n) {
        float av = amp[r], iv = inv[r];
#pragma unroll
        for (int ct = 0; ct < 4; ++ct) {
          int colo = ct * 16 + ar;
          float vv = accP[rf][ct][i] + av * accQ[rf][ct][i] + iv * accR[rf][ct][i] + beff[colo];
          h1[(size_t)r * 64 + colo] = fmaxf(vv, 0.f);
        }
      }
    }
}

// fused conv2: wave/node stats (8-deep pipeline) + 2-col dot, wave reduce
__global__ __launch_bounds__(256) void fused_conv2(
    const float* __restrict__ h1, const float* __restrict__ A,
    const float* __restrict__ B, const int* __restrict__ rowptr,
    const int* __restrict__ col, const float* __restrict__ amp,
    const float* __restrict__ inv, const float* __restrict__ W2eff,
    const float* __restrict__ b2eff, float* __restrict__ out, int n) {
  int tid = threadIdx.x;
  int lane = tid & 63, wid = tid >> 6;
  int node = blockIdx.x * 4 + wid;
  if (node >= n) return;
  int s0 = rowptr[node], s1 = rowptr[node + 1];
  float a = A[(size_t)node * 64 + lane];
  float sum = 0.f, sq = 0.f, mx = -3.4e38f, mn = 3.4e38f;
  int e = s0;
  for (; e + 8 <= s1; e += 8) {
    int i0 = col[e], i1 = col[e + 1], i2 = col[e + 2], i3 = col[e + 3];
    int i4 = col[e + 4], i5 = col[e + 5], i6 = col[e + 6], i7 = col[e + 7];
    float b0 = B[(size_t)i0 * 64 + lane];
    float b1 = B[(size_t)i1 * 64 + lane];
    float b2 = B[(size_t)i2 * 64 + lane];
    float b3 = B[(size_t)i3 * 64 + lane];
    float b4 = B[(size_t)i4 * 64 + lane];
    float b5 = B[(size_t)i5 * 64 + lane];
    float b6 = B[(size_t)i6 * 64 + lane];
    float b7 = B[(size_t)i7 * 64 + lane];
    sum += ((b0 + b1) + (b2 + b3)) + ((b4 + b5) + (b6 + b7));
    sq = fmaf(b0, b0, sq); sq = fmaf(b1, b1, sq);
    sq = fmaf(b2, b2, sq); sq = fmaf(b3, b3, sq);
    sq = fmaf(b4, b4, sq); sq = fmaf(b5, b5, sq);
    sq = fmaf(b6, b6, sq); sq = fmaf(b7, b7, sq);
    mx = fmaxf(mx, fmaxf(fmaxf(b0, b1), fmaxf(b2, b3)));
    mx = fmaxf(mx, fmaxf(fmaxf(b4, b5), fmaxf(b6, b7)));
    mn = fminf(mn, fminf(fminf(b0, b1), fminf(b2, b3)));
    mn = fminf(mn, fminf(fminf(b4, b5), fminf(b6, b7)));
  }
  for (; e < s1; ++e) {
    int s = col[e];
    float b = B[(size_t)s * 64 + lane];
    sum += b; sq = fmaf(b, b, sq);
    mx = fmaxf(mx, b); mn = fminf(mn, b);
  }
  int d = s1 - s0;
  float st[4];
  if (d > 0) {
    float idn = 1.0f / (float)d;
    float mB = sum * idn;
    st[0] = a + mB;
    st[1] = a + mn;
    st[2] = a + mx;
    float var = fmaf(-mB, mB, sq * idn);
    st[3] = sqrtf(fmaxf(var, 0.0f) + 1e-5f);
  } else {
    st[0] = 0.f; st[1] = 0.f; st[2] = 0.f; st[3] = sqrtf(1e-5f);
  }
  float av = amp[node], iv = inv[node];
  float xv = h1[(size_t)node * 64 + lane];
  float p0 = W2eff[lane] * xv;
  float p1 = W2eff[832 + lane] * xv;
#pragma unroll
  for (int m = 0; m < 4; ++m) {
    int j = m * 64 + lane;
    p0 = fmaf(st[m], fmaf(av, W2eff[320 + j], fmaf(iv, W2eff[576 + j], W2eff[64 + j])), p0);
    p1 = fmaf(st[m], fmaf(av, W2eff[832 + 320 + j], fmaf(iv, W2eff[832 + 576 + j], W2eff[832 + 64 + j])), p1);
  }
  for (int off = 32; off; off >>= 1) {
    p0 += __shfl_down(p0, off);
    p1 += __shfl_down(p1, off);
  }
  if (lane == 0) {
    out[(size_t)node * 2 + 0] = p0 + b2eff[0];
    out[(size_t)node * 2 + 1] = p1 + b2eff[1];
  }
}

extern "C" void kernel_launch(void* const* d_in, const int* in_sizes, int n_in,
                              void* d_out, int out_size, void* d_ws, size_t ws_size,
                              hipStream_t stream) {
  const float* x = (const float*)d_in[0];
  const int* ei = (const int*)d_in[1];
  const float* W1_pre = (const float*)d_in[2];
  const float* b1_pre = (const float*)d_in[3];
  const float* W1_post = (const float*)d_in[4];
  const float* b1_post = (const float*)d_in[5];
  const float* W1_lin = (const float*)d_in[6];
  const float* b1_lin = (const float*)d_in[7];
  const float* W2_pre = (const float*)d_in[8];
  const float* b2_pre = (const float*)d_in[9];
  const float* W2_post = (const float*)d_in[10];
  const float* b2_post = (const float*)d_in[11];
  const float* W2_lin = (const float*)d_in[12];
  const float* b2_lin = (const float*)d_in[13];

  const int N = in_sizes[0] / 64;
  const int E = in_sizes[1] / 2;
  const int* srcp = ei;
  const int* dstp = ei + E;
  const int nb = (N + 255) / 256;

  char* ws = (char*)d_ws;
  size_t off = 0;
  auto take = [&](size_t bytes) -> void* {
    void* p = ws + off;
    off = (off + bytes + 255) & ~(size_t)255;
    return p;
  };
  int* deg = (int*)take((size_t)N * 4);
  int* rowptr = (int*)take((size_t)(N + 1) * 4);
  int* cursor = (int*)take((size_t)N * 4);
  int* tmp = (int*)take((size_t)N * 4);
  int* partial = (int*)take(4096);
  float* amp = (float*)take((size_t)N * 4);
  float* inv = (float*)take((size_t)N * 4);
  float* avgsum = (float*)take(4);
  unsigned short* W1h = (unsigned short*)take((size_t)64 * 832 * 2);
  unsigned short* W1l = (unsigned short*)take((size_t)64 * 832 * 2);
  float* b1eff = (float*)take(64 * 4);
  float* W2eff = (float*)take((size_t)2 * 832 * 4);
  float* b2eff = (float*)take(2 * 4);
  unsigned short* Wp1h = (unsigned short*)take((size_t)128 * 64 * 2);
  unsigned short* Wp1l = (unsigned short*)take((size_t)128 * 64 * 2);
  unsigned short* Wp2h = (unsigned short*)take((size_t)128 * 64 * 2);
  unsigned short* Wp2l = (unsigned short*)take((size_t)128 * 64 * 2);
  int* col = (int*)take((size_t)E * 4);
  float* Abuf = (float*)take((size_t)N * 64 * 4);
  float* Bbuf = (float*)take((size_t)N * 64 * 4);
  unsigned short* AggH = (unsigned short*)take((size_t)N * 256 * 2);
  unsigned short* AggL = (unsigned short*)take((size_t)N * 256 * 2);
  float* h1 = (float*)take((size_t)N * 64 * 4);
  (void)ws_size; (void)n_in; (void)out_size;

  hipMemsetAsync(deg, 0, (size_t)N * 4, stream);
  hipMemsetAsync(avgsum, 0, 4, stream);

  make_eff_kernel<<<(ME_S5 + 255) / 256, 256, 0, stream>>>(
      W1_post, b1_post, W1_lin, b1_lin, W2_post, b2_post, W2_lin, b2_lin,
      W1_pre, W2_pre, W1h, W1l, b1eff, W2eff, b2eff, Wp1h, Wp1l, Wp2h, Wp2l);
  hist_kernel<<<(E + 255) / 256, 256, 0, stream>>>(dstp, deg, E);
  avglog_kernel<<<(N + 255) / 256, 256, 0, stream>>>(deg, avgsum, N);
  scan1_kernel<<<nb, 256, 0, stream>>>(deg, tmp, partial, N);
  scan2_kernel<<<1, 1024, 0, stream>>>(partial, nb);
  scan3_kernel<<<nb, 256, 0, stream>>>(deg, tmp, partial, rowptr, cursor, amp, inv,
                                       avgsum, N, E);
  fill_kernel<<<(E + 255) / 256, 256, 0, stream>>>(srcp, dstp, cursor, col, E);

  // conv1
  pre_mfma<<<(N + 127) / 128, 256, 0, stream>>>(x, Wp1h, Wp1l, b1_pre, Abuf, Bbuf, N);
  aggr_pack<<<(N + 3) / 4, 256, 0, stream>>>(Abuf, Bbuf, rowptr, col, AggH, AggL, N);
  post1_kernel<<<(N + 127) / 128, 256, 0, stream>>>(x, AggH, AggL, amp, inv,
                                                    W1h, W1l, b1eff, h1, N);
  // conv2
  pre_mfma<<<(N + 127) / 128, 256, 0, stream>>>(h1, Wp2h, Wp2l, b2_pre, Abuf, Bbuf, N);
  fused_conv2<<<(N + 3) / 4, 256, 0, stream>>>(h1, Abuf, Bbuf, rowptr, col, amp, inv,
                                               W2eff, b2eff, (float*)d_out, N);
}

// Round 6
// 464.472 us; speedup vs baseline: 2.0796x; 1.1828x over previous
//
#include <hip/hip_runtime.h>
#include <math.h>

// ---------------------------------------------------------------------------
// PNA (2 conv layers) on MI355X.
//   pre:  [A|B] = x @ [Wl|Wr]^T (+b on B)        (bf16-split MFMA GEMM)
//   CSR build: hist -> scan -> 2-level bucket sort (LDS-binned scatter,
//              then per-bucket exact scatter; kills write amplification)
//   aggr_pack: wave/node CSR gather stats of B -> packed bf16 hi/lo aggr
//   post1: no-LDS bf16-split MFMA GEMM, weights in fragment-major layout
//   fused_conv2: wave/node stats + 2-col dot (no aggr materialization)
// ---------------------------------------------------------------------------

typedef __attribute__((ext_vector_type(4))) float f32x4;
typedef __attribute__((ext_vector_type(8))) short s16x8;

__device__ inline unsigned short f2bf(float f) {
  unsigned int u = __float_as_uint(f);
  unsigned int r = u + 0x7fff + ((u >> 16) & 1);  // RNE
  return (unsigned short)(r >> 16);
}
__device__ inline float bf2f(unsigned short s) {
  return __uint_as_float(((unsigned int)s) << 16);
}
// truncation split: v = hi + rest, lo = bf16(rest)
__device__ inline void tsplit(float v, unsigned short& h, unsigned short& l) {
  unsigned int u = __float_as_uint(v);
  unsigned int hu = u & 0xffff0000u;
  h = (unsigned short)(hu >> 16);
  float lf = v - __uint_as_float(hu);
  l = (unsigned short)(__float_as_uint(lf) >> 16);
}

#define ME_S0 (64 * 832)
#define ME_S1 (ME_S0 + 64)
#define ME_S2 (ME_S1 + 2 * 832)
#define ME_S3 (ME_S2 + 2)
#define ME_S4 (ME_S3 + 128 * 64)
#define ME_S5 (ME_S4 + 128 * 64)

__global__ void make_eff_kernel(const float* __restrict__ W1_post, const float* __restrict__ b1_post,
                                const float* __restrict__ W1_lin, const float* __restrict__ b1_lin,
                                const float* __restrict__ W2_post, const float* __restrict__ b2_post,
                                const float* __restrict__ W2_lin, const float* __restrict__ b2_lin,
                                const float* __restrict__ W1_pre, const float* __restrict__ W2_pre,
                                unsigned short* __restrict__ W1h, unsigned short* __restrict__ W1l,
                                float* __restrict__ b1eff,
                                float* __restrict__ W2eff, float* __restrict__ b2eff,
                                unsigned short* __restrict__ Wp1h, unsigned short* __restrict__ Wp1l,
                                unsigned short* __restrict__ Wp2h, unsigned short* __restrict__ Wp2l) {
  int id = blockIdx.x * blockDim.x + threadIdx.x;
  if (id < ME_S0) {
    int o = id / 832, k = id - o * 832;
    float s = 0.f;
#pragma unroll 8
    for (int j = 0; j < 64; ++j) s = fmaf(W1_lin[o * 64 + j], W1_post[j * 832 + k], s);
    unsigned short h = f2bf(s);
    unsigned short l = f2bf(s - bf2f(h));
    // fragment-major layout: lane = klg*16 + ar holds elems j for (col, k)
    int q = k >> 5, klg = (k >> 3) & 3, jj = k & 7;
    int ct = o >> 4, ar = o & 15;
    int idx = ((q * 4 + ct) * 64 + (klg * 16 + ar)) * 8 + jj;
    W1h[idx] = h;
    W1l[idx] = l;
  } else if (id < ME_S1) {
    int o = id - ME_S0;
    float s = b1_lin[o];
    for (int j = 0; j < 64; ++j) s = fmaf(W1_lin[o * 64 + j], b1_post[j], s);
    b1eff[o] = s;
  } else if (id < ME_S2) {
    int t = id - ME_S1;
    int o = t / 832, k = t - o * 832;
    W2eff[t] = fmaf(W2_lin[o * 2 + 0], W2_post[k], W2_lin[o * 2 + 1] * W2_post[832 + k]);
  } else if (id < ME_S3) {
    int o = id - ME_S2;
    b2eff[o] = b2_lin[o] + W2_lin[o * 2 + 0] * b2_post[0] + W2_lin[o * 2 + 1] * b2_post[1];
  } else if (id < ME_S4) {
    int t = id - ME_S3;
    int c = t >> 6, k = t & 63;
    float v = (c < 64) ? W1_pre[c * 128 + k] : W1_pre[(c - 64) * 128 + 64 + k];
    unsigned short h = f2bf(v);
    Wp1h[t] = h;
    Wp1l[t] = f2bf(v - bf2f(h));
  } else if (id < ME_S5) {
    int t = id - ME_S4;
    int c = t >> 6, k = t & 63;
    float v = (c < 64) ? W2_pre[c * 128 + k] : W2_pre[(c - 64) * 128 + 64 + k];
    unsigned short h = f2bf(v);
    Wp2h[t] = h;
    Wp2l[t] = f2bf(v - bf2f(h));
  }
}

__global__ void hist_kernel(const int* __restrict__ dst, int* __restrict__ deg, int E) {
  int i = blockIdx.x * blockDim.x + threadIdx.x;
  if (i < E) atomicAdd(&deg[dst[i]], 1);
}

__global__ void avglog_kernel(const int* __restrict__ deg, float* __restrict__ out_sum, int n) {
  int i = blockIdx.x * blockDim.x + threadIdx.x;
  float v = (i < n) ? logf((float)deg[i] + 1.0f) : 0.0f;
  __shared__ float red[4];
  int lane = threadIdx.x & 63, wid = threadIdx.x >> 6;
  for (int off = 32; off; off >>= 1) v += __shfl_down(v, off);
  if (lane == 0) red[wid] = v;
  __syncthreads();
  if (threadIdx.x == 0) atomicAdd(out_sum, red[0] + red[1] + red[2] + red[3]);
}

__global__ void scan1_kernel(const int* __restrict__ deg, int* __restrict__ excl,
                             int* __restrict__ partial, int n) {
  __shared__ int wsums[4];
  int tid = threadIdx.x, b = blockIdx.x;
  int i = b * 256 + tid;
  int lane = tid & 63, wid = tid >> 6;
  int v = (i < n) ? deg[i] : 0;
  int x = v;
  for (int off = 1; off < 64; off <<= 1) {
    int t = __shfl_up(x, off);
    if (lane >= off) x += t;
  }
  if (lane == 63) wsums[wid] = x;
  __syncthreads();
  int wo = 0;
#pragma unroll
  for (int j = 0; j < 4; ++j) wo += (j < wid) ? wsums[j] : 0;
  if (i < n) excl[i] = wo + x - v;
  if (tid == 255) partial[b] = wo + x;
}

__global__ void scan2_kernel(int* __restrict__ partial, int nb) {
  __shared__ int wsums[16];
  int tid = threadIdx.x;
  int lane = tid & 63, wid = tid >> 6;
  int v = (tid < nb) ? partial[tid] : 0;
  int x = v;
  for (int off = 1; off < 64; off <<= 1) {
    int t = __shfl_up(x, off);
    if (lane >= off) x += t;
  }
  if (lane == 63) wsums[wid] = x;
  __syncthreads();
  if (wid == 0) {
    int w2 = (lane < 16) ? wsums[lane] : 0;
    for (int off = 1; off < 16; off <<= 1) {
      int t = __shfl_up(w2, off);
      if (lane >= off) w2 += t;
    }
    if (lane < 16) wsums[lane] = w2;
  }
  __syncthreads();
  int wo = (wid > 0) ? wsums[wid - 1] : 0;
  if (tid < nb) partial[tid] = wo + x - v;
}

__global__ void scan3_kernel(const int* __restrict__ deg, const int* __restrict__ excl,
                             const int* __restrict__ partial, int* __restrict__ rowptr,
                             int* __restrict__ cursor, float* __restrict__ amp,
                             float* __restrict__ inv, const float* __restrict__ avgsum,
                             int n, int E) {
  int i = blockIdx.x * 256 + threadIdx.x;
  if (i < n) {
    int r = excl[i] + partial[blockIdx.x];
    rowptr[i] = r;
    cursor[i] = r;
    int v = deg[i];
    float dnm = (float)(v > 0 ? v : 1);
    float a = logf(dnm + 1.0f) * ((float)n / avgsum[0]);
    amp[i] = a;
    inv[i] = 1.0f / a;
  }
  if (i == 0) rowptr[n] = E;
}

// ---- 2-level bucket sort CSR build (bucket = 1024 dst nodes) ----
#define BMAX 104
#define BINCAP 72
#define ACHUNK 4096

__global__ void bucket_init(const int* __restrict__ rowptr, int* __restrict__ bcur,
                            int n, int nbuk) {
  int b = blockIdx.x * blockDim.x + threadIdx.x;
  if (b < nbuk) {
    int idx = b << 10;
    if (idx > n) idx = n;
    bcur[b] = rowptr[idx];
  }
}

// pass A: scatter edges into bucket-major bmaj via LDS bins (coalesced flushes)
__global__ __launch_bounds__(256) void bucket_scatter(
    const int* __restrict__ src, const int* __restrict__ dst,
    int* __restrict__ bcur, int2* __restrict__ bmaj, int E, int nbuk) {
  __shared__ int bin_cnt[BMAX];
  __shared__ int bin_len[BMAX];
  __shared__ int bin_base[BMAX];
  __shared__ int bin_pref[BMAX + 1];
  __shared__ int2 bin_buf[BMAX * BINCAP];
  int tid = threadIdx.x;
  for (int b = tid; b < BMAX; b += 256) bin_cnt[b] = 0;
  __syncthreads();
  int start = blockIdx.x * ACHUNK;
  int end = start + ACHUNK;
  if (end > E) end = E;
  for (int i = start + tid; i < end; i += 256) {
    int s = src[i], d = dst[i];
    int b = d >> 10;
    int slot = atomicAdd(&bin_cnt[b], 1);
    if (slot < BINCAP) {
      bin_buf[b * BINCAP + slot] = make_int2(s, d);
    } else {
      int pos = atomicAdd(&bcur[b], 1);
      bmaj[pos] = make_int2(s, d);
    }
  }
  __syncthreads();
  if (tid < nbuk) {
    int c = bin_cnt[tid];
    bin_len[tid] = (c < BINCAP) ? c : BINCAP;
  }
  __syncthreads();
  if (tid == 0) {
    int acc = 0;
    for (int b = 0; b < nbuk; ++b) {
      bin_pref[b] = acc;
      acc += bin_len[b];
    }
    bin_pref[nbuk] = acc;
  }
  __syncthreads();
  if (tid < nbuk && bin_len[tid] > 0) bin_base[tid] = atomicAdd(&bcur[tid], bin_len[tid]);
  __syncthreads();
  int T = bin_pref[nbuk];
  for (int t = tid; t < T; t += 256) {
    int lo = 0, hi = nbuk - 1;
    while (lo < hi) {
      int mid = (lo + hi + 1) >> 1;
      if (bin_pref[mid] <= t) lo = mid; else hi = mid - 1;
    }
    int j = t - bin_pref[lo];
    bmaj[bin_base[lo] + j] = bin_buf[lo * BINCAP + j];
  }
}

// pass B: per-bucket exact scatter into col (one block per bucket -> L2-local)
__global__ __launch_bounds__(1024) void bucket_fill(
    const int2* __restrict__ bmaj, const int* __restrict__ rowptr,
    int* __restrict__ cursor, int* __restrict__ col, int n, int E) {
  int b = blockIdx.x;
  int i0 = b << 10;
  int i1 = i0 + 1024;
  if (i0 > n) i0 = n;
  if (i1 > n) i1 = n;
  int start = rowptr[i0];
  int end = rowptr[i1];
  for (int e = start + (int)threadIdx.x; e < end; e += 1024) {
    int2 p = bmaj[e];
    int pos = atomicAdd(&cursor[p.y], 1);
    col[pos] = p.x;
  }
}

// [A|B] = x @ [Wl|Wr]^T, bias folded into B. bf16-split MFMA, 128-row blocks.
__global__ __launch_bounds__(256, 2) void pre_mfma(
    const float* __restrict__ xin, const unsigned short* __restrict__ Wh,
    const unsigned short* __restrict__ Wl, const float* __restrict__ bias,
    float* __restrict__ A, float* __restrict__ Bo, int n) {
  __shared__ __attribute__((aligned(16))) unsigned short XH[128 * 64];
  __shared__ __attribute__((aligned(16))) unsigned short XL[128 * 64];
  int tid = threadIdx.x;
  int lane = tid & 63, w = tid >> 6;
  int row0 = blockIdx.x * 128;
  int sr = tid >> 1, hf = tid & 1;
  int grow = row0 + sr;
  {
    float v[32];
    if (grow < n) {
      const float4* p = (const float4*)(xin + (size_t)grow * 64 + hf * 32);
#pragma unroll
      for (int q = 0; q < 8; ++q) {
        float4 t = p[q];
        v[q * 4 + 0] = t.x; v[q * 4 + 1] = t.y; v[q * 4 + 2] = t.z; v[q * 4 + 3] = t.w;
      }
    } else {
#pragma unroll
      for (int j = 0; j < 32; ++j) v[j] = 0.f;
    }
    unsigned short hs[32], ls[32];
#pragma unroll
    for (int j = 0; j < 32; ++j) tsplit(v[j], hs[j], ls[j]);
    int rsw = sr & 7;
#pragma unroll
    for (int q = 0; q < 4; ++q) {
      int g = hf * 4 + q;
      int off = sr * 64 + ((g ^ rsw) << 3);
      *(s16x8*)&XH[off] = *(const s16x8*)&hs[q * 8];
      *(s16x8*)&XL[off] = *(const s16x8*)&ls[q * 8];
    }
  }
  __syncthreads();
  int ar = lane & 15, klg = lane >> 4;
  f32x4 acc[2][8];
#pragma unroll
  for (int rf = 0; rf < 2; ++rf)
#pragma unroll
    for (int ct = 0; ct < 8; ++ct) acc[rf][ct] = (f32x4){0.f, 0.f, 0.f, 0.f};
#pragma unroll
  for (int kk = 0; kk < 64; kk += 32) {
    s16x8 ah[2], al[2];
#pragma unroll
    for (int rf = 0; rf < 2; ++rf) {
      int lrow = w * 32 + rf * 16 + ar;
      int g = (kk >> 3) + klg;
      int off = lrow * 64 + ((g ^ (lrow & 7)) << 3);
      ah[rf] = *(const s16x8*)&XH[off];
      al[rf] = *(const s16x8*)&XL[off];
    }
    int ko = kk + klg * 8;
#pragma unroll
    for (int ct = 0; ct < 8; ++ct) {
      size_t br = (size_t)(ct * 16 + ar) * 64 + ko;
      s16x8 bh = *(const s16x8*)&Wh[br];
      s16x8 bl = *(const s16x8*)&Wl[br];
#pragma unroll
      for (int rf = 0; rf < 2; ++rf) {
        acc[rf][ct] = __builtin_amdgcn_mfma_f32_16x16x32_bf16(ah[rf], bh, acc[rf][ct], 0, 0, 0);
        acc[rf][ct] = __builtin_amdgcn_mfma_f32_16x16x32_bf16(ah[rf], bl, acc[rf][ct], 0, 0, 0);
        acc[rf][ct] = __builtin_amdgcn_mfma_f32_16x16x32_bf16(al[rf], bh, acc[rf][ct], 0, 0, 0);
      }
    }
  }
#pragma unroll
  for (int rf = 0; rf < 2; ++rf)
#pragma unroll
    for (int i = 0; i < 4; ++i) {
      int r = row0 + w * 32 + rf * 16 + klg * 4 + i;
      if (r < n) {
#pragma unroll
        for (int ct = 0; ct < 8; ++ct) {
          int c = ct * 16 + ar;
          float vv = acc[rf][ct][i];
          if (ct < 4) A[(size_t)r * 64 + c] = vv;
          else Bo[(size_t)r * 64 + (c - 64)] = vv + bias[c - 64];
        }
      }
    }
}

// wave per node: CSR gather stats of B, 8-deep load pipeline; writes packed
// bf16 hi/lo aggr: AggH/AggL[node*256 + c*64 + feat], c = mean,min,max,std
__global__ __launch_bounds__(256) void aggr_pack(
    const float* __restrict__ A, const float* __restrict__ B,
    const int* __restrict__ rowptr, const int* __restrict__ col,
    unsigned short* __restrict__ AggH, unsigned short* __restrict__ AggL, int n) {
  int tid = threadIdx.x;
  int lane = tid & 63, wid = tid >> 6;
  int node = blockIdx.x * 4 + wid;
  if (node >= n) return;
  int s0 = rowptr[node], s1 = rowptr[node + 1];
  float a = A[(size_t)node * 64 + lane];
  float sum = 0.f, sq = 0.f, mx = -3.4e38f, mn = 3.4e38f;
  int e = s0;
  for (; e + 8 <= s1; e += 8) {
    int i0 = col[e], i1 = col[e + 1], i2 = col[e + 2], i3 = col[e + 3];
    int i4 = col[e + 4], i5 = col[e + 5], i6 = col[e + 6], i7 = col[e + 7];
    float b0 = B[(size_t)i0 * 64 + lane];
    float b1 = B[(size_t)i1 * 64 + lane];
    float b2 = B[(size_t)i2 * 64 + lane];
    float b3 = B[(size_t)i3 * 64 + lane];
    float b4 = B[(size_t)i4 * 64 + lane];
    float b5 = B[(size_t)i5 * 64 + lane];
    float b6 = B[(size_t)i6 * 64 + lane];
    float b7 = B[(size_t)i7 * 64 + lane];
    sum += ((b0 + b1) + (b2 + b3)) + ((b4 + b5) + (b6 + b7));
    sq = fmaf(b0, b0, sq); sq = fmaf(b1, b1, sq);
    sq = fmaf(b2, b2, sq); sq = fmaf(b3, b3, sq);
    sq = fmaf(b4, b4, sq); sq = fmaf(b5, b5, sq);
    sq = fmaf(b6, b6, sq); sq = fmaf(b7, b7, sq);
    mx = fmaxf(mx, fmaxf(fmaxf(b0, b1), fmaxf(b2, b3)));
    mx = fmaxf(mx, fmaxf(fmaxf(b4, b5), fmaxf(b6, b7)));
    mn = fminf(mn, fminf(fminf(b0, b1), fminf(b2, b3)));
    mn = fminf(mn, fminf(fminf(b4, b5), fminf(b6, b7)));
  }
  for (; e < s1; ++e) {
    int s = col[e];
    float b = B[(size_t)s * 64 + lane];
    sum += b; sq = fmaf(b, b, sq);
    mx = fmaxf(mx, b); mn = fminf(mn, b);
  }
  int d = s1 - s0;
  float st[4];
  if (d > 0) {
    float idn = 1.0f / (float)d;
    float mB = sum * idn;
    st[0] = a + mB;
    st[1] = a + mn;
    st[2] = a + mx;
    float var = fmaf(-mB, mB, sq * idn);
    st[3] = sqrtf(fmaxf(var, 0.0f) + 1e-5f);
  } else {
    st[0] = 0.f; st[1] = 0.f; st[2] = 0.f; st[3] = sqrtf(1e-5f);
  }
  size_t o = (size_t)node * 256 + lane;
#pragma unroll
  for (int c = 0; c < 4; ++c) {
    unsigned short h, l;
    tsplit(st[c], h, l);
    AggH[o + c * 64] = h;
    AggL[o + c * 64] = l;
  }
}

// post1: no-LDS bf16-split MFMA GEMM. 128-row blocks, 4 waves x 32 rows.
// Weights in fragment-major layout: frag base = ((q*4+ct)*64 + lane)*8,
// q = K/32 over [x(0..63) | P(64..319) | Q(320..575) | R(576..831)].
__global__ __launch_bounds__(256) void post1_kernel(
    const float* __restrict__ x,
    const unsigned short* __restrict__ AggH, const unsigned short* __restrict__ AggL,
    const float* __restrict__ amp, const float* __restrict__ inv,
    const unsigned short* __restrict__ Wh, const unsigned short* __restrict__ Wl,
    const float* __restrict__ beff, float* __restrict__ h1, int n) {
  int tid = threadIdx.x;
  int lane = tid & 63, w = tid >> 6;
  int row0 = blockIdx.x * 128;
  int ar = lane & 15, klg = lane >> 4;
  int grow[2];
  bool rok[2];
#pragma unroll
  for (int rf = 0; rf < 2; ++rf) {
    grow[rf] = row0 + w * 32 + rf * 16 + ar;
    rok[rf] = grow[rf] < n;
  }
  f32x4 accP[2][4], accQ[2][4], accR[2][4];
#pragma unroll
  for (int rf = 0; rf < 2; ++rf)
#pragma unroll
    for (int ct = 0; ct < 4; ++ct) {
      accP[rf][ct] = (f32x4){0.f, 0.f, 0.f, 0.f};
      accQ[rf][ct] = (f32x4){0.f, 0.f, 0.f, 0.f};
      accR[rf][ct] = (f32x4){0.f, 0.f, 0.f, 0.f};
    }
  // ---- x stream (q = 0,1) ----
#pragma unroll
  for (int kk = 0; kk < 64; kk += 32) {
    s16x8 ah[2], al[2];
#pragma unroll
    for (int rf = 0; rf < 2; ++rf) {
      unsigned short hs[8], ls[8];
      if (rok[rf]) {
        const float* p = x + (size_t)grow[rf] * 64 + kk + klg * 8;
        float4 v0 = *(const float4*)p;
        float4 v1 = *(const float4*)(p + 4);
        float vv[8] = {v0.x, v0.y, v0.z, v0.w, v1.x, v1.y, v1.z, v1.w};
#pragma unroll
        for (int j = 0; j < 8; ++j) tsplit(vv[j], hs[j], ls[j]);
      } else {
#pragma unroll
        for (int j = 0; j < 8; ++j) { hs[j] = 0; ls[j] = 0; }
      }
      ah[rf] = *(const s16x8*)hs;
      al[rf] = *(const s16x8*)ls;
    }
    int q = kk >> 5;
#pragma unroll
    for (int ct = 0; ct < 4; ++ct) {
      size_t wb = (size_t)(((q * 4 + ct) * 64 + lane)) * 8;
      s16x8 bh = *(const s16x8*)&Wh[wb];
      s16x8 bl = *(const s16x8*)&Wl[wb];
#pragma unroll
      for (int rf = 0; rf < 2; ++rf) {
        accP[rf][ct] = __builtin_amdgcn_mfma_f32_16x16x32_bf16(ah[rf], bh, accP[rf][ct], 0, 0, 0);
        accP[rf][ct] = __builtin_amdgcn_mfma_f32_16x16x32_bf16(ah[rf], bl, accP[rf][ct], 0, 0, 0);
        accP[rf][ct] = __builtin_amdgcn_mfma_f32_16x16x32_bf16(al[rf], bh, accP[rf][ct], 0, 0, 0);
      }
    }
  }
  // ---- aggr streams: P q=2+2c+kk5, Q +8, R +16 ----
#pragma unroll
  for (int c = 0; c < 4; ++c) {
#pragma unroll
    for (int kk = 0; kk < 64; kk += 32) {
      s16x8 ah[2], al[2];
#pragma unroll
      for (int rf = 0; rf < 2; ++rf) {
        if (rok[rf]) {
          size_t ao = (size_t)grow[rf] * 256 + c * 64 + kk + klg * 8;
          ah[rf] = *(const s16x8*)&AggH[ao];
          al[rf] = *(const s16x8*)&AggL[ao];
        } else {
          ah[rf] = (s16x8){0, 0, 0, 0, 0, 0, 0, 0};
          al[rf] = (s16x8){0, 0, 0, 0, 0, 0, 0, 0};
        }
      }
      int qP = 2 + c * 2 + (kk >> 5);
#pragma unroll
      for (int ct = 0; ct < 4; ++ct) {
        size_t wbP = (size_t)(((qP * 4 + ct) * 64 + lane)) * 8;
        s16x8 bh = *(const s16x8*)&Wh[wbP];
        s16x8 bl = *(const s16x8*)&Wl[wbP];
#pragma unroll
        for (int rf = 0; rf < 2; ++rf) {
          accP[rf][ct] = __builtin_amdgcn_mfma_f32_16x16x32_bf16(ah[rf], bh, accP[rf][ct], 0, 0, 0);
          accP[rf][ct] = __builtin_amdgcn_mfma_f32_16x16x32_bf16(ah[rf], bl, accP[rf][ct], 0, 0, 0);
          accP[rf][ct] = __builtin_amdgcn_mfma_f32_16x16x32_bf16(al[rf], bh, accP[rf][ct], 0, 0, 0);
        }
        size_t wbQ = wbP + (size_t)8 * 4 * 64 * 8;
        bh = *(const s16x8*)&Wh[wbQ];
        bl = *(const s16x8*)&Wl[wbQ];
#pragma unroll
        for (int rf = 0; rf < 2; ++rf) {
          accQ[rf][ct] = __builtin_amdgcn_mfma_f32_16x16x32_bf16(ah[rf], bh, accQ[rf][ct], 0, 0, 0);
          accQ[rf][ct] = __builtin_amdgcn_mfma_f32_16x16x32_bf16(ah[rf], bl, accQ[rf][ct], 0, 0, 0);
          accQ[rf][ct] = __builtin_amdgcn_mfma_f32_16x16x32_bf16(al[rf], bh, accQ[rf][ct], 0, 0, 0);
        }
        size_t wbR = wbP + (size_t)16 * 4 * 64 * 8;
        bh = *(const s16x8*)&Wh[wbR];
        bl = *(const s16x8*)&Wl[wbR];
#pragma unroll
        for (int rf = 0; rf < 2; ++rf) {
          accR[rf][ct] = __builtin_amdgcn_mfma_f32_16x16x32_bf16(ah[rf], bh, accR[rf][ct], 0, 0, 0);
          accR[rf][ct] = __builtin_amdgcn_mfma_f32_16x16x32_bf16(ah[rf], bl, accR[rf][ct], 0, 0, 0);
          accR[rf][ct] = __builtin_amdgcn_mfma_f32_16x16x32_bf16(al[rf], bh, accR[rf][ct], 0, 0, 0);
        }
      }
    }
  }
  // epilogue
#pragma unroll
  for (int rf = 0; rf < 2; ++rf)
#pragma unroll
    for (int i = 0; i < 4; ++i) {
      int r = row0 + w * 32 + rf * 16 + klg * 4 + i;
      if (r < n) {
        float av = amp[r], iv = inv[r];
#pragma unroll
        for (int ct = 0; ct < 4; ++ct) {
          int colo = ct * 16 + ar;
          float vv = accP[rf][ct][i] + av * accQ[rf][ct][i] + iv * accR[rf][ct][i] + beff[colo];
          h1[(size_t)r * 64 + colo] = fmaxf(vv, 0.f);
        }
      }
    }
}

// fused conv2: wave/node stats (8-deep pipeline) + 2-col dot, wave reduce
__global__ __launch_bounds__(256) void fused_conv2(
    const float* __restrict__ h1, const float* __restrict__ A,
    const float* __restrict__ B, const int* __restrict__ rowptr,
    const int* __restrict__ col, const float* __restrict__ amp,
    const float* __restrict__ inv, const float* __restrict__ W2eff,
    const float* __restrict__ b2eff, float* __restrict__ out, int n) {
  int tid = threadIdx.x;
  int lane = tid & 63, wid = tid >> 6;
  int node = blockIdx.x * 4 + wid;
  if (node >= n) return;
  int s0 = rowptr[node], s1 = rowptr[node + 1];
  float a = A[(size_t)node * 64 + lane];
  float sum = 0.f, sq = 0.f, mx = -3.4e38f, mn = 3.4e38f;
  int e = s0;
  for (; e + 8 <= s1; e += 8) {
    int i0 = col[e], i1 = col[e + 1], i2 = col[e + 2], i3 = col[e + 3];
    int i4 = col[e + 4], i5 = col[e + 5], i6 = col[e + 6], i7 = col[e + 7];
    float b0 = B[(size_t)i0 * 64 + lane];
    float b1 = B[(size_t)i1 * 64 + lane];
    float b2 = B[(size_t)i2 * 64 + lane];
    float b3 = B[(size_t)i3 * 64 + lane];
    float b4 = B[(size_t)i4 * 64 + lane];
    float b5 = B[(size_t)i5 * 64 + lane];
    float b6 = B[(size_t)i6 * 64 + lane];
    float b7 = B[(size_t)i7 * 64 + lane];
    sum += ((b0 + b1) + (b2 + b3)) + ((b4 + b5) + (b6 + b7));
    sq = fmaf(b0, b0, sq); sq = fmaf(b1, b1, sq);
    sq = fmaf(b2, b2, sq); sq = fmaf(b3, b3, sq);
    sq = fmaf(b4, b4, sq); sq = fmaf(b5, b5, sq);
    sq = fmaf(b6, b6, sq); sq = fmaf(b7, b7, sq);
    mx = fmaxf(mx, fmaxf(fmaxf(b0, b1), fmaxf(b2, b3)));
    mx = fmaxf(mx, fmaxf(fmaxf(b4, b5), fmaxf(b6, b7)));
    mn = fminf(mn, fminf(fminf(b0, b1), fminf(b2, b3)));
    mn = fminf(mn, fminf(fminf(b4, b5), fminf(b6, b7)));
  }
  for (; e < s1; ++e) {
    int s = col[e];
    float b = B[(size_t)s * 64 + lane];
    sum += b; sq = fmaf(b, b, sq);
    mx = fmaxf(mx, b); mn = fminf(mn, b);
  }
  int d = s1 - s0;
  float st[4];
  if (d > 0) {
    float idn = 1.0f / (float)d;
    float mB = sum * idn;
    st[0] = a + mB;
    st[1] = a + mn;
    st[2] = a + mx;
    float var = fmaf(-mB, mB, sq * idn);
    st[3] = sqrtf(fmaxf(var, 0.0f) + 1e-5f);
  } else {
    st[0] = 0.f; st[1] = 0.f; st[2] = 0.f; st[3] = sqrtf(1e-5f);
  }
  float av = amp[node], iv = inv[node];
  float xv = h1[(size_t)node * 64 + lane];
  float p0 = W2eff[lane] * xv;
  float p1 = W2eff[832 + lane] * xv;
#pragma unroll
  for (int m = 0; m < 4; ++m) {
    int j = m * 64 + lane;
    p0 = fmaf(st[m], fmaf(av, W2eff[320 + j], fmaf(iv, W2eff[576 + j], W2eff[64 + j])), p0);
    p1 = fmaf(st[m], fmaf(av, W2eff[832 + 320 + j], fmaf(iv, W2eff[832 + 576 + j], W2eff[832 + 64 + j])), p1);
  }
  for (int off = 32; off; off >>= 1) {
    p0 += __shfl_down(p0, off);
    p1 += __shfl_down(p1, off);
  }
  if (lane == 0) {
    out[(size_t)node * 2 + 0] = p0 + b2eff[0];
    out[(size_t)node * 2 + 1] = p1 + b2eff[1];
  }
}

extern "C" void kernel_launch(void* const* d_in, const int* in_sizes, int n_in,
                              void* d_out, int out_size, void* d_ws, size_t ws_size,
                              hipStream_t stream) {
  const float* x = (const float*)d_in[0];
  const int* ei = (const int*)d_in[1];
  const float* W1_pre = (const float*)d_in[2];
  const float* b1_pre = (const float*)d_in[3];
  const float* W1_post = (const float*)d_in[4];
  const float* b1_post = (const float*)d_in[5];
  const float* W1_lin = (const float*)d_in[6];
  const float* b1_lin = (const float*)d_in[7];
  const float* W2_pre = (const float*)d_in[8];
  const float* b2_pre = (const float*)d_in[9];
  const float* W2_post = (const float*)d_in[10];
  const float* b2_post = (const float*)d_in[11];
  const float* W2_lin = (const float*)d_in[12];
  const float* b2_lin = (const float*)d_in[13];

  const int N = in_sizes[0] / 64;
  const int E = in_sizes[1] / 2;
  const int* srcp = ei;
  const int* dstp = ei + E;
  const int nb = (N + 255) / 256;
  const int nbuk = (N + 1023) >> 10;

  char* ws = (char*)d_ws;
  size_t off = 0;
  auto take = [&](size_t bytes) -> void* {
    void* p = ws + off;
    off = (off + bytes + 255) & ~(size_t)255;
    return p;
  };
  int* deg = (int*)take((size_t)N * 4);
  int* rowptr = (int*)take((size_t)(N + 1) * 4);
  int* cursor = (int*)take((size_t)N * 4);
  int* tmp = (int*)take((size_t)N * 4);
  int* partial = (int*)take(4096);
  int* bcur = (int*)take(4096);
  float* amp = (float*)take((size_t)N * 4);
  float* inv = (float*)take((size_t)N * 4);
  float* avgsum = (float*)take(4);
  unsigned short* W1h = (unsigned short*)take((size_t)64 * 832 * 2);
  unsigned short* W1l = (unsigned short*)take((size_t)64 * 832 * 2);
  float* b1eff = (float*)take(64 * 4);
  float* W2eff = (float*)take((size_t)2 * 832 * 4);
  float* b2eff = (float*)take(2 * 4);
  unsigned short* Wp1h = (unsigned short*)take((size_t)128 * 64 * 2);
  unsigned short* Wp1l = (unsigned short*)take((size_t)128 * 64 * 2);
  unsigned short* Wp2h = (unsigned short*)take((size_t)128 * 64 * 2);
  unsigned short* Wp2l = (unsigned short*)take((size_t)128 * 64 * 2);
  int* col = (int*)take((size_t)E * 4);
  int2* bmaj = (int2*)take((size_t)E * 8);
  float* Abuf = (float*)take((size_t)N * 64 * 4);
  float* Bbuf = (float*)take((size_t)N * 64 * 4);
  unsigned short* AggH = (unsigned short*)take((size_t)N * 256 * 2);
  unsigned short* AggL = (unsigned short*)take((size_t)N * 256 * 2);
  float* h1 = (float*)take((size_t)N * 64 * 4);
  (void)ws_size; (void)n_in; (void)out_size;

  hipMemsetAsync(deg, 0, (size_t)N * 4, stream);
  hipMemsetAsync(avgsum, 0, 4, stream);

  make_eff_kernel<<<(ME_S5 + 255) / 256, 256, 0, stream>>>(
      W1_post, b1_post, W1_lin, b1_lin, W2_post, b2_post, W2_lin, b2_lin,
      W1_pre, W2_pre, W1h, W1l, b1eff, W2eff, b2eff, Wp1h, Wp1l, Wp2h, Wp2l);
  hist_kernel<<<(E + 255) / 256, 256, 0, stream>>>(dstp, deg, E);
  avglog_kernel<<<(N + 255) / 256, 256, 0, stream>>>(deg, avgsum, N);
  scan1_kernel<<<nb, 256, 0, stream>>>(deg, tmp, partial, N);
  scan2_kernel<<<1, 1024, 0, stream>>>(partial, nb);
  scan3_kernel<<<nb, 256, 0, stream>>>(deg, tmp, partial, rowptr, cursor, amp, inv,
                                       avgsum, N, E);
  // 2-level CSR fill
  bucket_init<<<1, 128, 0, stream>>>(rowptr, bcur, N, nbuk);
  bucket_scatter<<<(E + ACHUNK - 1) / ACHUNK, 256, 0, stream>>>(srcp, dstp, bcur, bmaj, E, nbuk);
  bucket_fill<<<nbuk, 1024, 0, stream>>>(bmaj, rowptr, cursor, col, N, E);

  // conv1
  pre_mfma<<<(N + 127) / 128, 256, 0, stream>>>(x, Wp1h, Wp1l, b1_pre, Abuf, Bbuf, N);
  aggr_pack<<<(N + 3) / 4, 256, 0, stream>>>(Abuf, Bbuf, rowptr, col, AggH, AggL, N);
  post1_kernel<<<(N + 127) / 128, 256, 0, stream>>>(x, AggH, AggL, amp, inv,
                                                    W1h, W1l, b1eff, h1, N);
  // conv2
  pre_mfma<<<(N + 127) / 128, 256, 0, stream>>>(h1, Wp2h, Wp2l, b2_pre, Abuf, Bbuf, N);
  fused_conv2<<<(N + 3) / 4, 256, 0, stream>>>(h1, Abuf, Bbuf, rowptr, col, amp, inv,
                                               W2eff, b2eff, (float*)d_out, N);
}

// Round 7
// 446.711 us; speedup vs baseline: 2.1623x; 1.0398x over previous
//
#include <hip/hip_runtime.h>
#include <hip/hip_fp16.h>
#include <math.h>

// ---------------------------------------------------------------------------
// PNA (2 conv layers) on MI355X.
//   pre:  [A|B] = x @ [Wl|Wr]^T (+b on B)   (bf16-split MFMA GEMM; B -> fp16)
//   CSR build: hist -> scan -> 2-level bucket sort (no write amplification)
//   aggr_pack: 2-nodes-per-wave CSR gather stats of fp16 B -> bf16 hi/lo Agg
//   post1: no-LDS bf16-split MFMA GEMM, fragment-major weights
//   fused_conv2: 2-nodes-per-wave stats + 2-col dot (no aggr materialization)
// ---------------------------------------------------------------------------

typedef __attribute__((ext_vector_type(4))) float f32x4;
typedef __attribute__((ext_vector_type(8))) short s16x8;

__device__ inline unsigned short f2bf(float f) {
  unsigned int u = __float_as_uint(f);
  unsigned int r = u + 0x7fff + ((u >> 16) & 1);  // RNE
  return (unsigned short)(r >> 16);
}
__device__ inline float bf2f(unsigned short s) {
  return __uint_as_float(((unsigned int)s) << 16);
}
// truncation split: v = hi + rest, lo = bf16(rest)
__device__ inline void tsplit(float v, unsigned short& h, unsigned short& l) {
  unsigned int u = __float_as_uint(v);
  unsigned int hu = u & 0xffff0000u;
  h = (unsigned short)(hu >> 16);
  float lf = v - __uint_as_float(hu);
  l = (unsigned short)(__float_as_uint(lf) >> 16);
}

#define ME_S0 (64 * 832)
#define ME_S1 (ME_S0 + 64)
#define ME_S2 (ME_S1 + 2 * 832)
#define ME_S3 (ME_S2 + 2)
#define ME_S4 (ME_S3 + 128 * 64)
#define ME_S5 (ME_S4 + 128 * 64)

__global__ void make_eff_kernel(const float* __restrict__ W1_post, const float* __restrict__ b1_post,
                                const float* __restrict__ W1_lin, const float* __restrict__ b1_lin,
                                const float* __restrict__ W2_post, const float* __restrict__ b2_post,
                                const float* __restrict__ W2_lin, const float* __restrict__ b2_lin,
                                const float* __restrict__ W1_pre, const float* __restrict__ W2_pre,
                                unsigned short* __restrict__ W1h, unsigned short* __restrict__ W1l,
                                float* __restrict__ b1eff,
                                float* __restrict__ W2eff, float* __restrict__ b2eff,
                                unsigned short* __restrict__ Wp1h, unsigned short* __restrict__ Wp1l,
                                unsigned short* __restrict__ Wp2h, unsigned short* __restrict__ Wp2l) {
  int id = blockIdx.x * blockDim.x + threadIdx.x;
  if (id < ME_S0) {
    int o = id / 832, k = id - o * 832;
    float s = 0.f;
#pragma unroll 8
    for (int j = 0; j < 64; ++j) s = fmaf(W1_lin[o * 64 + j], W1_post[j * 832 + k], s);
    unsigned short h = f2bf(s);
    unsigned short l = f2bf(s - bf2f(h));
    // fragment-major layout: lane = klg*16 + ar holds elems j for (col, k)
    int q = k >> 5, klg = (k >> 3) & 3, jj = k & 7;
    int ct = o >> 4, ar = o & 15;
    int idx = ((q * 4 + ct) * 64 + (klg * 16 + ar)) * 8 + jj;
    W1h[idx] = h;
    W1l[idx] = l;
  } else if (id < ME_S1) {
    int o = id - ME_S0;
    float s = b1_lin[o];
    for (int j = 0; j < 64; ++j) s = fmaf(W1_lin[o * 64 + j], b1_post[j], s);
    b1eff[o] = s;
  } else if (id < ME_S2) {
    int t = id - ME_S1;
    int o = t / 832, k = t - o * 832;
    W2eff[t] = fmaf(W2_lin[o * 2 + 0], W2_post[k], W2_lin[o * 2 + 1] * W2_post[832 + k]);
  } else if (id < ME_S3) {
    int o = id - ME_S2;
    b2eff[o] = b2_lin[o] + W2_lin[o * 2 + 0] * b2_post[0] + W2_lin[o * 2 + 1] * b2_post[1];
  } else if (id < ME_S4) {
    int t = id - ME_S3;
    int c = t >> 6, k = t & 63;
    float v = (c < 64) ? W1_pre[c * 128 + k] : W1_pre[(c - 64) * 128 + 64 + k];
    unsigned short h = f2bf(v);
    Wp1h[t] = h;
    Wp1l[t] = f2bf(v - bf2f(h));
  } else if (id < ME_S5) {
    int t = id - ME_S4;
    int c = t >> 6, k = t & 63;
    float v = (c < 64) ? W2_pre[c * 128 + k] : W2_pre[(c - 64) * 128 + 64 + k];
    unsigned short h = f2bf(v);
    Wp2h[t] = h;
    Wp2l[t] = f2bf(v - bf2f(h));
  }
}

__global__ void hist_kernel(const int* __restrict__ dst, int* __restrict__ deg, int E) {
  int i = blockIdx.x * blockDim.x + threadIdx.x;
  if (i < E) atomicAdd(&deg[dst[i]], 1);
}

__global__ void avglog_kernel(const int* __restrict__ deg, float* __restrict__ out_sum, int n) {
  int i = blockIdx.x * blockDim.x + threadIdx.x;
  float v = (i < n) ? logf((float)deg[i] + 1.0f) : 0.0f;
  __shared__ float red[4];
  int lane = threadIdx.x & 63, wid = threadIdx.x >> 6;
  for (int off = 32; off; off >>= 1) v += __shfl_down(v, off);
  if (lane == 0) red[wid] = v;
  __syncthreads();
  if (threadIdx.x == 0) atomicAdd(out_sum, red[0] + red[1] + red[2] + red[3]);
}

__global__ void scan1_kernel(const int* __restrict__ deg, int* __restrict__ excl,
                             int* __restrict__ partial, int n) {
  __shared__ int wsums[4];
  int tid = threadIdx.x, b = blockIdx.x;
  int i = b * 256 + tid;
  int lane = tid & 63, wid = tid >> 6;
  int v = (i < n) ? deg[i] : 0;
  int x = v;
  for (int off = 1; off < 64; off <<= 1) {
    int t = __shfl_up(x, off);
    if (lane >= off) x += t;
  }
  if (lane == 63) wsums[wid] = x;
  __syncthreads();
  int wo = 0;
#pragma unroll
  for (int j = 0; j < 4; ++j) wo += (j < wid) ? wsums[j] : 0;
  if (i < n) excl[i] = wo + x - v;
  if (tid == 255) partial[b] = wo + x;
}

__global__ void scan2_kernel(int* __restrict__ partial, int nb) {
  __shared__ int wsums[16];
  int tid = threadIdx.x;
  int lane = tid & 63, wid = tid >> 6;
  int v = (tid < nb) ? partial[tid] : 0;
  int x = v;
  for (int off = 1; off < 64; off <<= 1) {
    int t = __shfl_up(x, off);
    if (lane >= off) x += t;
  }
  if (lane == 63) wsums[wid] = x;
  __syncthreads();
  if (wid == 0) {
    int w2 = (lane < 16) ? wsums[lane] : 0;
    for (int off = 1; off < 16; off <<= 1) {
      int t = __shfl_up(w2, off);
      if (lane >= off) w2 += t;
    }
    if (lane < 16) wsums[lane] = w2;
  }
  __syncthreads();
  int wo = (wid > 0) ? wsums[wid - 1] : 0;
  if (tid < nb) partial[tid] = wo + x - v;
}

__global__ void scan3_kernel(const int* __restrict__ deg, const int* __restrict__ excl,
                             const int* __restrict__ partial, int* __restrict__ rowptr,
                             int* __restrict__ cursor, float* __restrict__ amp,
                             float* __restrict__ inv, const float* __restrict__ avgsum,
                             int n, int E) {
  int i = blockIdx.x * 256 + threadIdx.x;
  if (i < n) {
    int r = excl[i] + partial[blockIdx.x];
    rowptr[i] = r;
    cursor[i] = r;
    int v = deg[i];
    float dnm = (float)(v > 0 ? v : 1);
    float a = logf(dnm + 1.0f) * ((float)n / avgsum[0]);
    amp[i] = a;
    inv[i] = 1.0f / a;
  }
  if (i == 0) rowptr[n] = E;
}

// ---- 2-level bucket sort CSR build (bucket = 1024 dst nodes) ----
#define BMAX 104
#define BINCAP 72
#define ACHUNK 4096

__global__ void bucket_init(const int* __restrict__ rowptr, int* __restrict__ bcur,
                            int n, int nbuk) {
  int b = blockIdx.x * blockDim.x + threadIdx.x;
  if (b < nbuk) {
    int idx = b << 10;
    if (idx > n) idx = n;
    bcur[b] = rowptr[idx];
  }
}

__global__ __launch_bounds__(256) void bucket_scatter(
    const int* __restrict__ src, const int* __restrict__ dst,
    int* __restrict__ bcur, int2* __restrict__ bmaj, int E, int nbuk) {
  __shared__ int bin_cnt[BMAX];
  __shared__ int bin_len[BMAX];
  __shared__ int bin_base[BMAX];
  __shared__ int bin_pref[BMAX + 1];
  __shared__ int2 bin_buf[BMAX * BINCAP];
  int tid = threadIdx.x;
  for (int b = tid; b < BMAX; b += 256) bin_cnt[b] = 0;
  __syncthreads();
  int start = blockIdx.x * ACHUNK;
  int end = start + ACHUNK;
  if (end > E) end = E;
  for (int i = start + tid; i < end; i += 256) {
    int s = src[i], d = dst[i];
    int b = d >> 10;
    int slot = atomicAdd(&bin_cnt[b], 1);
    if (slot < BINCAP) {
      bin_buf[b * BINCAP + slot] = make_int2(s, d);
    } else {
      int pos = atomicAdd(&bcur[b], 1);
      bmaj[pos] = make_int2(s, d);
    }
  }
  __syncthreads();
  if (tid < nbuk) {
    int c = bin_cnt[tid];
    bin_len[tid] = (c < BINCAP) ? c : BINCAP;
  }
  __syncthreads();
  if (tid == 0) {
    int acc = 0;
    for (int b = 0; b < nbuk; ++b) {
      bin_pref[b] = acc;
      acc += bin_len[b];
    }
    bin_pref[nbuk] = acc;
  }
  __syncthreads();
  if (tid < nbuk && bin_len[tid] > 0) bin_base[tid] = atomicAdd(&bcur[tid], bin_len[tid]);
  __syncthreads();
  int T = bin_pref[nbuk];
  for (int t = tid; t < T; t += 256) {
    int lo = 0, hi = nbuk - 1;
    while (lo < hi) {
      int mid = (lo + hi + 1) >> 1;
      if (bin_pref[mid] <= t) lo = mid; else hi = mid - 1;
    }
    int j = t - bin_pref[lo];
    bmaj[bin_base[lo] + j] = bin_buf[lo * BINCAP + j];
  }
}

__global__ __launch_bounds__(1024) void bucket_fill(
    const int2* __restrict__ bmaj, const int* __restrict__ rowptr,
    int* __restrict__ cursor, int* __restrict__ col, int n, int E) {
  int b = blockIdx.x;
  int i0 = b << 10;
  int i1 = i0 + 1024;
  if (i0 > n) i0 = n;
  if (i1 > n) i1 = n;
  int start = rowptr[i0];
  int end = rowptr[i1];
  for (int e = start + (int)threadIdx.x; e < end; e += 1024) {
    int2 p = bmaj[e];
    int pos = atomicAdd(&cursor[p.y], 1);
    col[pos] = p.x;
  }
}

// [A|B] = x @ [Wl|Wr]^T, bias folded into B (B stored fp16). 128-row blocks.
__global__ __launch_bounds__(256, 2) void pre_mfma(
    const float* __restrict__ xin, const unsigned short* __restrict__ Wh,
    const unsigned short* __restrict__ Wl, const float* __restrict__ bias,
    float* __restrict__ A, __half* __restrict__ Bo, int n) {
  __shared__ __attribute__((aligned(16))) unsigned short XH[128 * 64];
  __shared__ __attribute__((aligned(16))) unsigned short XL[128 * 64];
  int tid = threadIdx.x;
  int lane = tid & 63, w = tid >> 6;
  int row0 = blockIdx.x * 128;
  int sr = tid >> 1, hf = tid & 1;
  int grow = row0 + sr;
  {
    float v[32];
    if (grow < n) {
      const float4* p = (const float4*)(xin + (size_t)grow * 64 + hf * 32);
#pragma unroll
      for (int q = 0; q < 8; ++q) {
        float4 t = p[q];
        v[q * 4 + 0] = t.x; v[q * 4 + 1] = t.y; v[q * 4 + 2] = t.z; v[q * 4 + 3] = t.w;
      }
    } else {
#pragma unroll
      for (int j = 0; j < 32; ++j) v[j] = 0.f;
    }
    unsigned short hs[32], ls[32];
#pragma unroll
    for (int j = 0; j < 32; ++j) tsplit(v[j], hs[j], ls[j]);
    int rsw = sr & 7;
#pragma unroll
    for (int q = 0; q < 4; ++q) {
      int g = hf * 4 + q;
      int off = sr * 64 + ((g ^ rsw) << 3);
      *(s16x8*)&XH[off] = *(const s16x8*)&hs[q * 8];
      *(s16x8*)&XL[off] = *(const s16x8*)&ls[q * 8];
    }
  }
  __syncthreads();
  int ar = lane & 15, klg = lane >> 4;
  f32x4 acc[2][8];
#pragma unroll
  for (int rf = 0; rf < 2; ++rf)
#pragma unroll
    for (int ct = 0; ct < 8; ++ct) acc[rf][ct] = (f32x4){0.f, 0.f, 0.f, 0.f};
#pragma unroll
  for (int kk = 0; kk < 64; kk += 32) {
    s16x8 ah[2], al[2];
#pragma unroll
    for (int rf = 0; rf < 2; ++rf) {
      int lrow = w * 32 + rf * 16 + ar;
      int g = (kk >> 3) + klg;
      int off = lrow * 64 + ((g ^ (lrow & 7)) << 3);
      ah[rf] = *(const s16x8*)&XH[off];
      al[rf] = *(const s16x8*)&XL[off];
    }
    int ko = kk + klg * 8;
#pragma unroll
    for (int ct = 0; ct < 8; ++ct) {
      size_t br = (size_t)(ct * 16 + ar) * 64 + ko;
      s16x8 bh = *(const s16x8*)&Wh[br];
      s16x8 bl = *(const s16x8*)&Wl[br];
#pragma unroll
      for (int rf = 0; rf < 2; ++rf) {
        acc[rf][ct] = __builtin_amdgcn_mfma_f32_16x16x32_bf16(ah[rf], bh, acc[rf][ct], 0, 0, 0);
        acc[rf][ct] = __builtin_amdgcn_mfma_f32_16x16x32_bf16(ah[rf], bl, acc[rf][ct], 0, 0, 0);
        acc[rf][ct] = __builtin_amdgcn_mfma_f32_16x16x32_bf16(al[rf], bh, acc[rf][ct], 0, 0, 0);
      }
    }
  }
#pragma unroll
  for (int rf = 0; rf < 2; ++rf)
#pragma unroll
    for (int i = 0; i < 4; ++i) {
      int r = row0 + w * 32 + rf * 16 + klg * 4 + i;
      if (r < n) {
#pragma unroll
        for (int ct = 0; ct < 8; ++ct) {
          int c = ct * 16 + ar;
          float vv = acc[rf][ct][i];
          if (ct < 4) A[(size_t)r * 64 + c] = vv;
          else Bo[(size_t)r * 64 + (c - 64)] = __float2half(vv + bias[c - 64]);
        }
      }
    }
}

// 2 nodes per wave (32 lanes x 2 fp16 feats/lane): CSR gather stats of B ->
// packed bf16 hi/lo Agg[node*256 + c*64 + feat]
__global__ __launch_bounds__(256) void aggr_pack(
    const float* __restrict__ A, const __half* __restrict__ B,
    const int* __restrict__ rowptr, const int* __restrict__ col,
    unsigned short* __restrict__ AggH, unsigned short* __restrict__ AggL, int n) {
  int tid = threadIdx.x;
  int lane = tid & 63, wv = tid >> 6;
  int half = lane >> 5, fl = lane & 31;
  int node = (blockIdx.x * 4 + wv) * 2 + half;
  bool ok = node < n;
  int s0 = ok ? rowptr[node] : 0;
  int s1 = ok ? rowptr[node + 1] : 0;
  float2 sum = make_float2(0.f, 0.f), sq = make_float2(0.f, 0.f);
  float2 mx = make_float2(-3.4e38f, -3.4e38f), mn = make_float2(3.4e38f, 3.4e38f);
  int e = s0;
  for (; e + 8 <= s1; e += 8) {
    int idx[8];
#pragma unroll
    for (int j = 0; j < 8; ++j) idx[j] = col[e + j];
    __half2 hv[8];
#pragma unroll
    for (int j = 0; j < 8; ++j) hv[j] = *(const __half2*)&B[(size_t)idx[j] * 64 + fl * 2];
#pragma unroll
    for (int j = 0; j < 8; ++j) {
      float2 b = __half22float2(hv[j]);
      sum.x += b.x; sum.y += b.y;
      sq.x = fmaf(b.x, b.x, sq.x); sq.y = fmaf(b.y, b.y, sq.y);
      mx.x = fmaxf(mx.x, b.x); mx.y = fmaxf(mx.y, b.y);
      mn.x = fminf(mn.x, b.x); mn.y = fminf(mn.y, b.y);
    }
  }
  for (; e < s1; ++e) {
    float2 b = __half22float2(*(const __half2*)&B[(size_t)col[e] * 64 + fl * 2]);
    sum.x += b.x; sum.y += b.y;
    sq.x = fmaf(b.x, b.x, sq.x); sq.y = fmaf(b.y, b.y, sq.y);
    mx.x = fmaxf(mx.x, b.x); mx.y = fmaxf(mx.y, b.y);
    mn.x = fminf(mn.x, b.x); mn.y = fminf(mn.y, b.y);
  }
  if (!ok) return;
  int d = s1 - s0;
  float2 st[4];
  if (d > 0) {
    float idn = 1.0f / (float)d;
    float2 a2 = *(const float2*)&A[(size_t)node * 64 + fl * 2];
    float2 mB = make_float2(sum.x * idn, sum.y * idn);
    st[0] = make_float2(a2.x + mB.x, a2.y + mB.y);
    st[1] = make_float2(a2.x + mn.x, a2.y + mn.y);
    st[2] = make_float2(a2.x + mx.x, a2.y + mx.y);
    float vx = fmaf(-mB.x, mB.x, sq.x * idn);
    float vy = fmaf(-mB.y, mB.y, sq.y * idn);
    st[3] = make_float2(sqrtf(fmaxf(vx, 0.f) + 1e-5f), sqrtf(fmaxf(vy, 0.f) + 1e-5f));
  } else {
    st[0] = make_float2(0.f, 0.f); st[1] = st[0]; st[2] = st[0];
    float s = sqrtf(1e-5f);
    st[3] = make_float2(s, s);
  }
  size_t o = (size_t)node * 256 + fl * 2;
#pragma unroll
  for (int c = 0; c < 4; ++c) {
    unsigned short h0, l0, h1, l1;
    tsplit(st[c].x, h0, l0);
    tsplit(st[c].y, h1, l1);
    *(unsigned int*)&AggH[o + c * 64] = (unsigned int)h0 | ((unsigned int)h1 << 16);
    *(unsigned int*)&AggL[o + c * 64] = (unsigned int)l0 | ((unsigned int)l1 << 16);
  }
}

// post1: no-LDS bf16-split MFMA GEMM. 128-row blocks, 4 waves x 32 rows.
// Weights fragment-major: frag base = ((q*4+ct)*64 + lane)*8.
__global__ __launch_bounds__(256) void post1_kernel(
    const float* __restrict__ x,
    const unsigned short* __restrict__ AggH, const unsigned short* __restrict__ AggL,
    const float* __restrict__ amp, const float* __restrict__ inv,
    const unsigned short* __restrict__ Wh, const unsigned short* __restrict__ Wl,
    const float* __restrict__ beff, float* __restrict__ h1, int n) {
  int tid = threadIdx.x;
  int lane = tid & 63, w = tid >> 6;
  int row0 = blockIdx.x * 128;
  int ar = lane & 15, klg = lane >> 4;
  int grow[2];
  bool rok[2];
#pragma unroll
  for (int rf = 0; rf < 2; ++rf) {
    grow[rf] = row0 + w * 32 + rf * 16 + ar;
    rok[rf] = grow[rf] < n;
  }
  f32x4 accP[2][4], accQ[2][4], accR[2][4];
#pragma unroll
  for (int rf = 0; rf < 2; ++rf)
#pragma unroll
    for (int ct = 0; ct < 4; ++ct) {
      accP[rf][ct] = (f32x4){0.f, 0.f, 0.f, 0.f};
      accQ[rf][ct] = (f32x4){0.f, 0.f, 0.f, 0.f};
      accR[rf][ct] = (f32x4){0.f, 0.f, 0.f, 0.f};
    }
#pragma unroll
  for (int kk = 0; kk < 64; kk += 32) {
    s16x8 ah[2], al[2];
#pragma unroll
    for (int rf = 0; rf < 2; ++rf) {
      unsigned short hs[8], ls[8];
      if (rok[rf]) {
        const float* p = x + (size_t)grow[rf] * 64 + kk + klg * 8;
        float4 v0 = *(const float4*)p;
        float4 v1 = *(const float4*)(p + 4);
        float vv[8] = {v0.x, v0.y, v0.z, v0.w, v1.x, v1.y, v1.z, v1.w};
#pragma unroll
        for (int j = 0; j < 8; ++j) tsplit(vv[j], hs[j], ls[j]);
      } else {
#pragma unroll
        for (int j = 0; j < 8; ++j) { hs[j] = 0; ls[j] = 0; }
      }
      ah[rf] = *(const s16x8*)hs;
      al[rf] = *(const s16x8*)ls;
    }
    int q = kk >> 5;
#pragma unroll
    for (int ct = 0; ct < 4; ++ct) {
      size_t wb = (size_t)(((q * 4 + ct) * 64 + lane)) * 8;
      s16x8 bh = *(const s16x8*)&Wh[wb];
      s16x8 bl = *(const s16x8*)&Wl[wb];
#pragma unroll
      for (int rf = 0; rf < 2; ++rf) {
        accP[rf][ct] = __builtin_amdgcn_mfma_f32_16x16x32_bf16(ah[rf], bh, accP[rf][ct], 0, 0, 0);
        accP[rf][ct] = __builtin_amdgcn_mfma_f32_16x16x32_bf16(ah[rf], bl, accP[rf][ct], 0, 0, 0);
        accP[rf][ct] = __builtin_amdgcn_mfma_f32_16x16x32_bf16(al[rf], bh, accP[rf][ct], 0, 0, 0);
      }
    }
  }
#pragma unroll
  for (int c = 0; c < 4; ++c) {
#pragma unroll
    for (int kk = 0; kk < 64; kk += 32) {
      s16x8 ah[2], al[2];
#pragma unroll
      for (int rf = 0; rf < 2; ++rf) {
        if (rok[rf]) {
          size_t ao = (size_t)grow[rf] * 256 + c * 64 + kk + klg * 8;
          ah[rf] = *(const s16x8*)&AggH[ao];
          al[rf] = *(const s16x8*)&AggL[ao];
        } else {
          ah[rf] = (s16x8){0, 0, 0, 0, 0, 0, 0, 0};
          al[rf] = (s16x8){0, 0, 0, 0, 0, 0, 0, 0};
        }
      }
      int qP = 2 + c * 2 + (kk >> 5);
#pragma unroll
      for (int ct = 0; ct < 4; ++ct) {
        size_t wbP = (size_t)(((qP * 4 + ct) * 64 + lane)) * 8;
        s16x8 bh = *(const s16x8*)&Wh[wbP];
        s16x8 bl = *(const s16x8*)&Wl[wbP];
#pragma unroll
        for (int rf = 0; rf < 2; ++rf) {
          accP[rf][ct] = __builtin_amdgcn_mfma_f32_16x16x32_bf16(ah[rf], bh, accP[rf][ct], 0, 0, 0);
          accP[rf][ct] = __builtin_amdgcn_mfma_f32_16x16x32_bf16(ah[rf], bl, accP[rf][ct], 0, 0, 0);
          accP[rf][ct] = __builtin_amdgcn_mfma_f32_16x16x32_bf16(al[rf], bh, accP[rf][ct], 0, 0, 0);
        }
        size_t wbQ = wbP + (size_t)8 * 4 * 64 * 8;
        bh = *(const s16x8*)&Wh[wbQ];
        bl = *(const s16x8*)&Wl[wbQ];
#pragma unroll
        for (int rf = 0; rf < 2; ++rf) {
          accQ[rf][ct] = __builtin_amdgcn_mfma_f32_16x16x32_bf16(ah[rf], bh, accQ[rf][ct], 0, 0, 0);
          accQ[rf][ct] = __builtin_amdgcn_mfma_f32_16x16x32_bf16(ah[rf], bl, accQ[rf][ct], 0, 0, 0);
          accQ[rf][ct] = __builtin_amdgcn_mfma_f32_16x16x32_bf16(al[rf], bh, accQ[rf][ct], 0, 0, 0);
        }
        size_t wbR = wbP + (size_t)16 * 4 * 64 * 8;
        bh = *(const s16x8*)&Wh[wbR];
        bl = *(const s16x8*)&Wl[wbR];
#pragma unroll
        for (int rf = 0; rf < 2; ++rf) {
          accR[rf][ct] = __builtin_amdgcn_mfma_f32_16x16x32_bf16(ah[rf], bh, accR[rf][ct], 0, 0, 0);
          accR[rf][ct] = __builtin_amdgcn_mfma_f32_16x16x32_bf16(ah[rf], bl, accR[rf][ct], 0, 0, 0);
          accR[rf][ct] = __builtin_amdgcn_mfma_f32_16x16x32_bf16(al[rf], bh, accR[rf][ct], 0, 0, 0);
        }
      }
    }
  }
#pragma unroll
  for (int rf = 0; rf < 2; ++rf)
#pragma unroll
    for (int i = 0; i < 4; ++i) {
      int r = row0 + w * 32 + rf * 16 + klg * 4 + i;
      if (r < n) {
        float av = amp[r], iv = inv[r];
#pragma unroll
        for (int ct = 0; ct < 4; ++ct) {
          int colo = ct * 16 + ar;
          float vv = accP[rf][ct][i] + av * accQ[rf][ct][i] + iv * accR[rf][ct][i] + beff[colo];
          h1[(size_t)r * 64 + colo] = fmaxf(vv, 0.f);
        }
      }
    }
}

// fused conv2: 2 nodes per wave, fp16 gather, butterfly reduce within 32 lanes
__global__ __launch_bounds__(256) void fused_conv2(
    const float* __restrict__ h1, const float* __restrict__ A,
    const __half* __restrict__ B, const int* __restrict__ rowptr,
    const int* __restrict__ col, const float* __restrict__ amp,
    const float* __restrict__ inv, const float* __restrict__ W2eff,
    const float* __restrict__ b2eff, float* __restrict__ out, int n) {
  int tid = threadIdx.x;
  int lane = tid & 63, wv = tid >> 6;
  int half = lane >> 5, fl = lane & 31;
  int node = (blockIdx.x * 4 + wv) * 2 + half;
  bool ok = node < n;
  int s0 = ok ? rowptr[node] : 0;
  int s1 = ok ? rowptr[node + 1] : 0;
  float2 sum = make_float2(0.f, 0.f), sq = make_float2(0.f, 0.f);
  float2 mx = make_float2(-3.4e38f, -3.4e38f), mn = make_float2(3.4e38f, 3.4e38f);
  int e = s0;
  for (; e + 8 <= s1; e += 8) {
    int idx[8];
#pragma unroll
    for (int j = 0; j < 8; ++j) idx[j] = col[e + j];
    __half2 hv[8];
#pragma unroll
    for (int j = 0; j < 8; ++j) hv[j] = *(const __half2*)&B[(size_t)idx[j] * 64 + fl * 2];
#pragma unroll
    for (int j = 0; j < 8; ++j) {
      float2 b = __half22float2(hv[j]);
      sum.x += b.x; sum.y += b.y;
      sq.x = fmaf(b.x, b.x, sq.x); sq.y = fmaf(b.y, b.y, sq.y);
      mx.x = fmaxf(mx.x, b.x); mx.y = fmaxf(mx.y, b.y);
      mn.x = fminf(mn.x, b.x); mn.y = fminf(mn.y, b.y);
    }
  }
  for (; e < s1; ++e) {
    float2 b = __half22float2(*(const __half2*)&B[(size_t)col[e] * 64 + fl * 2]);
    sum.x += b.x; sum.y += b.y;
    sq.x = fmaf(b.x, b.x, sq.x); sq.y = fmaf(b.y, b.y, sq.y);
    mx.x = fmaxf(mx.x, b.x); mx.y = fmaxf(mx.y, b.y);
    mn.x = fminf(mn.x, b.x); mn.y = fminf(mn.y, b.y);
  }
  int d = s1 - s0;
  float2 st[4];
  if (d > 0) {
    float idn = 1.0f / (float)d;
    float2 a2 = *(const float2*)&A[(size_t)node * 64 + fl * 2];
    float2 mB = make_float2(sum.x * idn, sum.y * idn);
    st[0] = make_float2(a2.x + mB.x, a2.y + mB.y);
    st[1] = make_float2(a2.x + mn.x, a2.y + mn.y);
    st[2] = make_float2(a2.x + mx.x, a2.y + mx.y);
    float vx = fmaf(-mB.x, mB.x, sq.x * idn);
    float vy = fmaf(-mB.y, mB.y, sq.y * idn);
    st[3] = make_float2(sqrtf(fmaxf(vx, 0.f) + 1e-5f), sqrtf(fmaxf(vy, 0.f) + 1e-5f));
  } else {
    st[0] = make_float2(0.f, 0.f); st[1] = st[0]; st[2] = st[0];
    float s = sqrtf(1e-5f);
    st[3] = make_float2(s, s);
  }
  float av = ok ? amp[node] : 1.f, iv = ok ? inv[node] : 1.f;
  float2 xv = ok ? *(const float2*)&h1[(size_t)node * 64 + fl * 2] : make_float2(0.f, 0.f);
  float2 w0 = *(const float2*)&W2eff[fl * 2];
  float2 w1 = *(const float2*)&W2eff[832 + fl * 2];
  float p0 = w0.x * xv.x + w0.y * xv.y;
  float p1 = w1.x * xv.x + w1.y * xv.y;
#pragma unroll
  for (int m = 0; m < 4; ++m) {
    int j = m * 64 + fl * 2;
    float2 wA0 = *(const float2*)&W2eff[64 + j];
    float2 wB0 = *(const float2*)&W2eff[320 + j];
    float2 wC0 = *(const float2*)&W2eff[576 + j];
    float2 wA1 = *(const float2*)&W2eff[832 + 64 + j];
    float2 wB1 = *(const float2*)&W2eff[832 + 320 + j];
    float2 wC1 = *(const float2*)&W2eff[832 + 576 + j];
    p0 += st[m].x * fmaf(av, wB0.x, fmaf(iv, wC0.x, wA0.x));
    p0 += st[m].y * fmaf(av, wB0.y, fmaf(iv, wC0.y, wA0.y));
    p1 += st[m].x * fmaf(av, wB1.x, fmaf(iv, wC1.x, wA1.x));
    p1 += st[m].y * fmaf(av, wB1.y, fmaf(iv, wC1.y, wA1.y));
  }
#pragma unroll
  for (int m = 16; m; m >>= 1) {
    p0 += __shfl_xor(p0, m);
    p1 += __shfl_xor(p1, m);
  }
  if (ok && fl == 0) {
    out[(size_t)node * 2 + 0] = p0 + b2eff[0];
    out[(size_t)node * 2 + 1] = p1 + b2eff[1];
  }
}

extern "C" void kernel_launch(void* const* d_in, const int* in_sizes, int n_in,
                              void* d_out, int out_size, void* d_ws, size_t ws_size,
                              hipStream_t stream) {
  const float* x = (const float*)d_in[0];
  const int* ei = (const int*)d_in[1];
  const float* W1_pre = (const float*)d_in[2];
  const float* b1_pre = (const float*)d_in[3];
  const float* W1_post = (const float*)d_in[4];
  const float* b1_post = (const float*)d_in[5];
  const float* W1_lin = (const float*)d_in[6];
  const float* b1_lin = (const float*)d_in[7];
  const float* W2_pre = (const float*)d_in[8];
  const float* b2_pre = (const float*)d_in[9];
  const float* W2_post = (const float*)d_in[10];
  const float* b2_post = (const float*)d_in[11];
  const float* W2_lin = (const float*)d_in[12];
  const float* b2_lin = (const float*)d_in[13];

  const int N = in_sizes[0] / 64;
  const int E = in_sizes[1] / 2;
  const int* srcp = ei;
  const int* dstp = ei + E;
  const int nb = (N + 255) / 256;
  const int nbuk = (N + 1023) >> 10;

  char* ws = (char*)d_ws;
  size_t off = 0;
  auto take = [&](size_t bytes) -> void* {
    void* p = ws + off;
    off = (off + bytes + 255) & ~(size_t)255;
    return p;
  };
  int* deg = (int*)take((size_t)N * 4);
  int* rowptr = (int*)take((size_t)(N + 1) * 4);
  int* cursor = (int*)take((size_t)N * 4);
  int* tmp = (int*)take((size_t)N * 4);
  int* partial = (int*)take(4096);
  int* bcur = (int*)take(4096);
  float* amp = (float*)take((size_t)N * 4);
  float* inv = (float*)take((size_t)N * 4);
  float* avgsum = (float*)take(4);
  unsigned short* W1h = (unsigned short*)take((size_t)64 * 832 * 2);
  unsigned short* W1l = (unsigned short*)take((size_t)64 * 832 * 2);
  float* b1eff = (float*)take(64 * 4);
  float* W2eff = (float*)take((size_t)2 * 832 * 4);
  float* b2eff = (float*)take(2 * 4);
  unsigned short* Wp1h = (unsigned short*)take((size_t)128 * 64 * 2);
  unsigned short* Wp1l = (unsigned short*)take((size_t)128 * 64 * 2);
  unsigned short* Wp2h = (unsigned short*)take((size_t)128 * 64 * 2);
  unsigned short* Wp2l = (unsigned short*)take((size_t)128 * 64 * 2);
  int* col = (int*)take((size_t)E * 4);
  int2* bmaj = (int2*)take((size_t)E * 8);
  float* Abuf = (float*)take((size_t)N * 64 * 4);
  __half* Bbuf = (__half*)take((size_t)N * 64 * 2);
  unsigned short* AggH = (unsigned short*)take((size_t)N * 256 * 2);
  unsigned short* AggL = (unsigned short*)take((size_t)N * 256 * 2);
  float* h1 = (float*)take((size_t)N * 64 * 4);
  (void)ws_size; (void)n_in; (void)out_size;

  hipMemsetAsync(deg, 0, (size_t)N * 4, stream);
  hipMemsetAsync(avgsum, 0, 4, stream);

  make_eff_kernel<<<(ME_S5 + 255) / 256, 256, 0, stream>>>(
      W1_post, b1_post, W1_lin, b1_lin, W2_post, b2_post, W2_lin, b2_lin,
      W1_pre, W2_pre, W1h, W1l, b1eff, W2eff, b2eff, Wp1h, Wp1l, Wp2h, Wp2l);
  hist_kernel<<<(E + 255) / 256, 256, 0, stream>>>(dstp, deg, E);
  avglog_kernel<<<(N + 255) / 256, 256, 0, stream>>>(deg, avgsum, N);
  scan1_kernel<<<nb, 256, 0, stream>>>(deg, tmp, partial, N);
  scan2_kernel<<<1, 1024, 0, stream>>>(partial, nb);
  scan3_kernel<<<nb, 256, 0, stream>>>(deg, tmp, partial, rowptr, cursor, amp, inv,
                                       avgsum, N, E);
  bucket_init<<<1, 128, 0, stream>>>(rowptr, bcur, N, nbuk);
  bucket_scatter<<<(E + ACHUNK - 1) / ACHUNK, 256, 0, stream>>>(srcp, dstp, bcur, bmaj, E, nbuk);
  bucket_fill<<<nbuk, 1024, 0, stream>>>(bmaj, rowptr, cursor, col, N, E);

  // conv1
  pre_mfma<<<(N + 127) / 128, 256, 0, stream>>>(x, Wp1h, Wp1l, b1_pre, Abuf, Bbuf, N);
  aggr_pack<<<(N + 7) / 8, 256, 0, stream>>>(Abuf, Bbuf, rowptr, col, AggH, AggL, N);
  post1_kernel<<<(N + 127) / 128, 256, 0, stream>>>(x, AggH, AggL, amp, inv,
                                                    W1h, W1l, b1eff, h1, N);
  // conv2
  pre_mfma<<<(N + 127) / 128, 256, 0, stream>>>(h1, Wp2h, Wp2l, b2_pre, Abuf, Bbuf, N);
  fused_conv2<<<(N + 7) / 8, 256, 0, stream>>>(h1, Abuf, Bbuf, rowptr, col, amp, inv,
                                               W2eff, b2eff, (float*)d_out, N);
}

// Round 8
// 433.483 us; speedup vs baseline: 2.2283x; 1.0305x over previous
//
#include <hip/hip_runtime.h>
#include <hip/hip_fp16.h>
#include <math.h>

// ---------------------------------------------------------------------------
// PNA (2 conv layers) on MI355X.
//   pre:  [A|B] = x @ [Wl|Wr]^T (+b on B)   (bf16-split MFMA GEMM; B -> fp16)
//   CSR build: hist -> scan -> 2-level bucket sort (no write amplification)
//   aggr_pack: 1 node/wave, lane=feat, fp16 gather, 16-deep pipeline
//   post1: no-LDS bf16-split MFMA GEMM, fragment-major weights
//   fused_conv2: same gather structure + 2-col dot (no aggr materialization)
// ---------------------------------------------------------------------------

typedef __attribute__((ext_vector_type(4))) float f32x4;
typedef __attribute__((ext_vector_type(8))) short s16x8;

__device__ inline unsigned short f2bf(float f) {
  unsigned int u = __float_as_uint(f);
  unsigned int r = u + 0x7fff + ((u >> 16) & 1);  // RNE
  return (unsigned short)(r >> 16);
}
__device__ inline float bf2f(unsigned short s) {
  return __uint_as_float(((unsigned int)s) << 16);
}
// truncation split: v = hi + rest, lo = bf16(rest)
__device__ inline void tsplit(float v, unsigned short& h, unsigned short& l) {
  unsigned int u = __float_as_uint(v);
  unsigned int hu = u & 0xffff0000u;
  h = (unsigned short)(hu >> 16);
  float lf = v - __uint_as_float(hu);
  l = (unsigned short)(__float_as_uint(lf) >> 16);
}

#define ME_S0 (64 * 832)
#define ME_S1 (ME_S0 + 64)
#define ME_S2 (ME_S1 + 2 * 832)
#define ME_S3 (ME_S2 + 2)
#define ME_S4 (ME_S3 + 128 * 64)
#define ME_S5 (ME_S4 + 128 * 64)

__global__ void make_eff_kernel(const float* __restrict__ W1_post, const float* __restrict__ b1_post,
                                const float* __restrict__ W1_lin, const float* __restrict__ b1_lin,
                                const float* __restrict__ W2_post, const float* __restrict__ b2_post,
                                const float* __restrict__ W2_lin, const float* __restrict__ b2_lin,
                                const float* __restrict__ W1_pre, const float* __restrict__ W2_pre,
                                unsigned short* __restrict__ W1h, unsigned short* __restrict__ W1l,
                                float* __restrict__ b1eff,
                                float* __restrict__ W2eff, float* __restrict__ b2eff,
                                unsigned short* __restrict__ Wp1h, unsigned short* __restrict__ Wp1l,
                                unsigned short* __restrict__ Wp2h, unsigned short* __restrict__ Wp2l) {
  int id = blockIdx.x * blockDim.x + threadIdx.x;
  if (id < ME_S0) {
    int o = id / 832, k = id - o * 832;
    float s = 0.f;
#pragma unroll 8
    for (int j = 0; j < 64; ++j) s = fmaf(W1_lin[o * 64 + j], W1_post[j * 832 + k], s);
    unsigned short h = f2bf(s);
    unsigned short l = f2bf(s - bf2f(h));
    // fragment-major layout: lane = klg*16 + ar holds elems j for (col, k)
    int q = k >> 5, klg = (k >> 3) & 3, jj = k & 7;
    int ct = o >> 4, ar = o & 15;
    int idx = ((q * 4 + ct) * 64 + (klg * 16 + ar)) * 8 + jj;
    W1h[idx] = h;
    W1l[idx] = l;
  } else if (id < ME_S1) {
    int o = id - ME_S0;
    float s = b1_lin[o];
    for (int j = 0; j < 64; ++j) s = fmaf(W1_lin[o * 64 + j], b1_post[j], s);
    b1eff[o] = s;
  } else if (id < ME_S2) {
    int t = id - ME_S1;
    int o = t / 832, k = t - o * 832;
    W2eff[t] = fmaf(W2_lin[o * 2 + 0], W2_post[k], W2_lin[o * 2 + 1] * W2_post[832 + k]);
  } else if (id < ME_S3) {
    int o = id - ME_S2;
    b2eff[o] = b2_lin[o] + W2_lin[o * 2 + 0] * b2_post[0] + W2_lin[o * 2 + 1] * b2_post[1];
  } else if (id < ME_S4) {
    int t = id - ME_S3;
    int c = t >> 6, k = t & 63;
    float v = (c < 64) ? W1_pre[c * 128 + k] : W1_pre[(c - 64) * 128 + 64 + k];
    unsigned short h = f2bf(v);
    Wp1h[t] = h;
    Wp1l[t] = f2bf(v - bf2f(h));
  } else if (id < ME_S5) {
    int t = id - ME_S4;
    int c = t >> 6, k = t & 63;
    float v = (c < 64) ? W2_pre[c * 128 + k] : W2_pre[(c - 64) * 128 + 64 + k];
    unsigned short h = f2bf(v);
    Wp2h[t] = h;
    Wp2l[t] = f2bf(v - bf2f(h));
  }
}

__global__ void hist_kernel(const int* __restrict__ dst, int* __restrict__ deg, int E) {
  int i = blockIdx.x * blockDim.x + threadIdx.x;
  if (i < E) atomicAdd(&deg[dst[i]], 1);
}

__global__ void avglog_kernel(const int* __restrict__ deg, float* __restrict__ out_sum, int n) {
  int i = blockIdx.x * blockDim.x + threadIdx.x;
  float v = (i < n) ? logf((float)deg[i] + 1.0f) : 0.0f;
  __shared__ float red[4];
  int lane = threadIdx.x & 63, wid = threadIdx.x >> 6;
  for (int off = 32; off; off >>= 1) v += __shfl_down(v, off);
  if (lane == 0) red[wid] = v;
  __syncthreads();
  if (threadIdx.x == 0) atomicAdd(out_sum, red[0] + red[1] + red[2] + red[3]);
}

__global__ void scan1_kernel(const int* __restrict__ deg, int* __restrict__ excl,
                             int* __restrict__ partial, int n) {
  __shared__ int wsums[4];
  int tid = threadIdx.x, b = blockIdx.x;
  int i = b * 256 + tid;
  int lane = tid & 63, wid = tid >> 6;
  int v = (i < n) ? deg[i] : 0;
  int x = v;
  for (int off = 1; off < 64; off <<= 1) {
    int t = __shfl_up(x, off);
    if (lane >= off) x += t;
  }
  if (lane == 63) wsums[wid] = x;
  __syncthreads();
  int wo = 0;
#pragma unroll
  for (int j = 0; j < 4; ++j) wo += (j < wid) ? wsums[j] : 0;
  if (i < n) excl[i] = wo + x - v;
  if (tid == 255) partial[b] = wo + x;
}

__global__ void scan2_kernel(int* __restrict__ partial, int nb) {
  __shared__ int wsums[16];
  int tid = threadIdx.x;
  int lane = tid & 63, wid = tid >> 6;
  int v = (tid < nb) ? partial[tid] : 0;
  int x = v;
  for (int off = 1; off < 64; off <<= 1) {
    int t = __shfl_up(x, off);
    if (lane >= off) x += t;
  }
  if (lane == 63) wsums[wid] = x;
  __syncthreads();
  if (wid == 0) {
    int w2 = (lane < 16) ? wsums[lane] : 0;
    for (int off = 1; off < 16; off <<= 1) {
      int t = __shfl_up(w2, off);
      if (lane >= off) w2 += t;
    }
    if (lane < 16) wsums[lane] = w2;
  }
  __syncthreads();
  int wo = (wid > 0) ? wsums[wid - 1] : 0;
  if (tid < nb) partial[tid] = wo + x - v;
}

__global__ void scan3_kernel(const int* __restrict__ deg, const int* __restrict__ excl,
                             const int* __restrict__ partial, int* __restrict__ rowptr,
                             int* __restrict__ cursor, float* __restrict__ amp,
                             float* __restrict__ inv, const float* __restrict__ avgsum,
                             int n, int E) {
  int i = blockIdx.x * 256 + threadIdx.x;
  if (i < n) {
    int r = excl[i] + partial[blockIdx.x];
    rowptr[i] = r;
    cursor[i] = r;
    int v = deg[i];
    float dnm = (float)(v > 0 ? v : 1);
    float a = logf(dnm + 1.0f) * ((float)n / avgsum[0]);
    amp[i] = a;
    inv[i] = 1.0f / a;
  }
  if (i == 0) rowptr[n] = E;
}

// ---- 2-level bucket sort CSR build (bucket = 1024 dst nodes) ----
#define BMAX 104
#define BINCAP 72
#define ACHUNK 4096

__global__ void bucket_init(const int* __restrict__ rowptr, int* __restrict__ bcur,
                            int n, int nbuk) {
  int b = blockIdx.x * blockDim.x + threadIdx.x;
  if (b < nbuk) {
    int idx = b << 10;
    if (idx > n) idx = n;
    bcur[b] = rowptr[idx];
  }
}

__global__ __launch_bounds__(256) void bucket_scatter(
    const int* __restrict__ src, const int* __restrict__ dst,
    int* __restrict__ bcur, int2* __restrict__ bmaj, int E, int nbuk) {
  __shared__ int bin_cnt[BMAX];
  __shared__ int bin_len[BMAX];
  __shared__ int bin_base[BMAX];
  __shared__ int bin_pref[BMAX + 1];
  __shared__ int2 bin_buf[BMAX * BINCAP];
  int tid = threadIdx.x;
  for (int b = tid; b < BMAX; b += 256) bin_cnt[b] = 0;
  __syncthreads();
  int start = blockIdx.x * ACHUNK;
  int end = start + ACHUNK;
  if (end > E) end = E;
  for (int i = start + tid; i < end; i += 256) {
    int s = src[i], d = dst[i];
    int b = d >> 10;
    int slot = atomicAdd(&bin_cnt[b], 1);
    if (slot < BINCAP) {
      bin_buf[b * BINCAP + slot] = make_int2(s, d);
    } else {
      int pos = atomicAdd(&bcur[b], 1);
      bmaj[pos] = make_int2(s, d);
    }
  }
  __syncthreads();
  if (tid < nbuk) {
    int c = bin_cnt[tid];
    bin_len[tid] = (c < BINCAP) ? c : BINCAP;
  }
  __syncthreads();
  if (tid == 0) {
    int acc = 0;
    for (int b = 0; b < nbuk; ++b) {
      bin_pref[b] = acc;
      acc += bin_len[b];
    }
    bin_pref[nbuk] = acc;
  }
  __syncthreads();
  if (tid < nbuk && bin_len[tid] > 0) bin_base[tid] = atomicAdd(&bcur[tid], bin_len[tid]);
  __syncthreads();
  int T = bin_pref[nbuk];
  for (int t = tid; t < T; t += 256) {
    int lo = 0, hi = nbuk - 1;
    while (lo < hi) {
      int mid = (lo + hi + 1) >> 1;
      if (bin_pref[mid] <= t) lo = mid; else hi = mid - 1;
    }
    int j = t - bin_pref[lo];
    bmaj[bin_base[lo] + j] = bin_buf[lo * BINCAP + j];
  }
}

__global__ __launch_bounds__(1024) void bucket_fill(
    const int2* __restrict__ bmaj, const int* __restrict__ rowptr,
    int* __restrict__ cursor, int* __restrict__ col, int n, int E) {
  int b = blockIdx.x;
  int i0 = b << 10;
  int i1 = i0 + 1024;
  if (i0 > n) i0 = n;
  if (i1 > n) i1 = n;
  int start = rowptr[i0];
  int end = rowptr[i1];
  for (int e = start + (int)threadIdx.x; e < end; e += 1024) {
    int2 p = bmaj[e];
    int pos = atomicAdd(&cursor[p.y], 1);
    col[pos] = p.x;
  }
}

// [A|B] = x @ [Wl|Wr]^T, bias folded into B (B stored fp16). 128-row blocks.
__global__ __launch_bounds__(256, 2) void pre_mfma(
    const float* __restrict__ xin, const unsigned short* __restrict__ Wh,
    const unsigned short* __restrict__ Wl, const float* __restrict__ bias,
    float* __restrict__ A, __half* __restrict__ Bo, int n) {
  __shared__ __attribute__((aligned(16))) unsigned short XH[128 * 64];
  __shared__ __attribute__((aligned(16))) unsigned short XL[128 * 64];
  int tid = threadIdx.x;
  int lane = tid & 63, w = tid >> 6;
  int row0 = blockIdx.x * 128;
  int sr = tid >> 1, hf = tid & 1;
  int grow = row0 + sr;
  {
    float v[32];
    if (grow < n) {
      const float4* p = (const float4*)(xin + (size_t)grow * 64 + hf * 32);
#pragma unroll
      for (int q = 0; q < 8; ++q) {
        float4 t = p[q];
        v[q * 4 + 0] = t.x; v[q * 4 + 1] = t.y; v[q * 4 + 2] = t.z; v[q * 4 + 3] = t.w;
      }
    } else {
#pragma unroll
      for (int j = 0; j < 32; ++j) v[j] = 0.f;
    }
    unsigned short hs[32], ls[32];
#pragma unroll
    for (int j = 0; j < 32; ++j) tsplit(v[j], hs[j], ls[j]);
    int rsw = sr & 7;
#pragma unroll
    for (int q = 0; q < 4; ++q) {
      int g = hf * 4 + q;
      int off = sr * 64 + ((g ^ rsw) << 3);
      *(s16x8*)&XH[off] = *(const s16x8*)&hs[q * 8];
      *(s16x8*)&XL[off] = *(const s16x8*)&ls[q * 8];
    }
  }
  __syncthreads();
  int ar = lane & 15, klg = lane >> 4;
  f32x4 acc[2][8];
#pragma unroll
  for (int rf = 0; rf < 2; ++rf)
#pragma unroll
    for (int ct = 0; ct < 8; ++ct) acc[rf][ct] = (f32x4){0.f, 0.f, 0.f, 0.f};
#pragma unroll
  for (int kk = 0; kk < 64; kk += 32) {
    s16x8 ah[2], al[2];
#pragma unroll
    for (int rf = 0; rf < 2; ++rf) {
      int lrow = w * 32 + rf * 16 + ar;
      int g = (kk >> 3) + klg;
      int off = lrow * 64 + ((g ^ (lrow & 7)) << 3);
      ah[rf] = *(const s16x8*)&XH[off];
      al[rf] = *(const s16x8*)&XL[off];
    }
    int ko = kk + klg * 8;
#pragma unroll
    for (int ct = 0; ct < 8; ++ct) {
      size_t br = (size_t)(ct * 16 + ar) * 64 + ko;
      s16x8 bh = *(const s16x8*)&Wh[br];
      s16x8 bl = *(const s16x8*)&Wl[br];
#pragma unroll
      for (int rf = 0; rf < 2; ++rf) {
        acc[rf][ct] = __builtin_amdgcn_mfma_f32_16x16x32_bf16(ah[rf], bh, acc[rf][ct], 0, 0, 0);
        acc[rf][ct] = __builtin_amdgcn_mfma_f32_16x16x32_bf16(ah[rf], bl, acc[rf][ct], 0, 0, 0);
        acc[rf][ct] = __builtin_amdgcn_mfma_f32_16x16x32_bf16(al[rf], bh, acc[rf][ct], 0, 0, 0);
      }
    }
  }
#pragma unroll
  for (int rf = 0; rf < 2; ++rf)
#pragma unroll
    for (int i = 0; i < 4; ++i) {
      int r = row0 + w * 32 + rf * 16 + klg * 4 + i;
      if (r < n) {
#pragma unroll
        for (int ct = 0; ct < 8; ++ct) {
          int c = ct * 16 + ar;
          float vv = acc[rf][ct][i];
          if (ct < 4) A[(size_t)r * 64 + c] = vv;
          else Bo[(size_t)r * 64 + (c - 64)] = __float2half(vv + bias[c - 64]);
        }
      }
    }
}

// ---- shared gather macro body: 1 node/wave, lane=feat, fp16 B, 16-deep ----
#define GATHER_STATS                                                        \
  float sum = 0.f, sq = 0.f, mx = -3.4e38f, mn = 3.4e38f;                   \
  int e = s0;                                                               \
  for (; e + 16 <= s1; e += 16) {                                           \
    int idx[16];                                                            \
    _Pragma("unroll") for (int j = 0; j < 16; ++j) idx[j] = col[e + j];     \
    __half hv[16];                                                          \
    _Pragma("unroll") for (int j = 0; j < 16; ++j)                          \
        hv[j] = B[(size_t)idx[j] * 64 + lane];                              \
    _Pragma("unroll") for (int j = 0; j < 16; ++j) {                        \
      float b = __half2float(hv[j]);                                        \
      sum += b; sq = fmaf(b, b, sq);                                        \
      mx = fmaxf(mx, b); mn = fminf(mn, b);                                 \
    }                                                                       \
  }                                                                         \
  for (; e + 4 <= s1; e += 4) {                                             \
    int idx[4];                                                             \
    _Pragma("unroll") for (int j = 0; j < 4; ++j) idx[j] = col[e + j];      \
    __half hv[4];                                                           \
    _Pragma("unroll") for (int j = 0; j < 4; ++j)                           \
        hv[j] = B[(size_t)idx[j] * 64 + lane];                              \
    _Pragma("unroll") for (int j = 0; j < 4; ++j) {                         \
      float b = __half2float(hv[j]);                                        \
      sum += b; sq = fmaf(b, b, sq);                                        \
      mx = fmaxf(mx, b); mn = fminf(mn, b);                                 \
    }                                                                       \
  }                                                                         \
  for (; e < s1; ++e) {                                                     \
    float b = __half2float(B[(size_t)col[e] * 64 + lane]);                  \
    sum += b; sq = fmaf(b, b, sq);                                          \
    mx = fmaxf(mx, b); mn = fminf(mn, b);                                   \
  }

// wave per node: CSR gather stats of fp16 B -> packed bf16 hi/lo Agg
__global__ __launch_bounds__(256) void aggr_pack(
    const float* __restrict__ A, const __half* __restrict__ B,
    const int* __restrict__ rowptr, const int* __restrict__ col,
    unsigned short* __restrict__ AggH, unsigned short* __restrict__ AggL, int n) {
  int tid = threadIdx.x;
  int lane = tid & 63, wv = tid >> 6;
  int node = blockIdx.x * 4 + wv;
  if (node >= n) return;
  int s0 = rowptr[node], s1 = rowptr[node + 1];
  GATHER_STATS
  int d = s1 - s0;
  float st[4];
  if (d > 0) {
    float idn = 1.0f / (float)d;
    float mB = sum * idn;
    float a = A[(size_t)node * 64 + lane];
    st[0] = a + mB;
    st[1] = a + mn;
    st[2] = a + mx;
    float var = fmaf(-mB, mB, sq * idn);
    st[3] = sqrtf(fmaxf(var, 0.0f) + 1e-5f);
  } else {
    st[0] = 0.f; st[1] = 0.f; st[2] = 0.f; st[3] = sqrtf(1e-5f);
  }
  size_t o = (size_t)node * 256 + lane;
#pragma unroll
  for (int c = 0; c < 4; ++c) {
    unsigned short h, l;
    tsplit(st[c], h, l);
    AggH[o + c * 64] = h;
    AggL[o + c * 64] = l;
  }
}

// post1: no-LDS bf16-split MFMA GEMM. 128-row blocks, 4 waves x 32 rows.
// Weights fragment-major: frag base = ((q*4+ct)*64 + lane)*8.
__global__ __launch_bounds__(256) void post1_kernel(
    const float* __restrict__ x,
    const unsigned short* __restrict__ AggH, const unsigned short* __restrict__ AggL,
    const float* __restrict__ amp, const float* __restrict__ inv,
    const unsigned short* __restrict__ Wh, const unsigned short* __restrict__ Wl,
    const float* __restrict__ beff, float* __restrict__ h1, int n) {
  int tid = threadIdx.x;
  int lane = tid & 63, w = tid >> 6;
  int row0 = blockIdx.x * 128;
  int ar = lane & 15, klg = lane >> 4;
  int grow[2];
  bool rok[2];
#pragma unroll
  for (int rf = 0; rf < 2; ++rf) {
    grow[rf] = row0 + w * 32 + rf * 16 + ar;
    rok[rf] = grow[rf] < n;
  }
  f32x4 accP[2][4], accQ[2][4], accR[2][4];
#pragma unroll
  for (int rf = 0; rf < 2; ++rf)
#pragma unroll
    for (int ct = 0; ct < 4; ++ct) {
      accP[rf][ct] = (f32x4){0.f, 0.f, 0.f, 0.f};
      accQ[rf][ct] = (f32x4){0.f, 0.f, 0.f, 0.f};
      accR[rf][ct] = (f32x4){0.f, 0.f, 0.f, 0.f};
    }
#pragma unroll
  for (int kk = 0; kk < 64; kk += 32) {
    s16x8 ah[2], al[2];
#pragma unroll
    for (int rf = 0; rf < 2; ++rf) {
      unsigned short hs[8], ls[8];
      if (rok[rf]) {
        const float* p = x + (size_t)grow[rf] * 64 + kk + klg * 8;
        float4 v0 = *(const float4*)p;
        float4 v1 = *(const float4*)(p + 4);
        float vv[8] = {v0.x, v0.y, v0.z, v0.w, v1.x, v1.y, v1.z, v1.w};
#pragma unroll
        for (int j = 0; j < 8; ++j) tsplit(vv[j], hs[j], ls[j]);
      } else {
#pragma unroll
        for (int j = 0; j < 8; ++j) { hs[j] = 0; ls[j] = 0; }
      }
      ah[rf] = *(const s16x8*)hs;
      al[rf] = *(const s16x8*)ls;
    }
    int q = kk >> 5;
#pragma unroll
    for (int ct = 0; ct < 4; ++ct) {
      size_t wb = (size_t)(((q * 4 + ct) * 64 + lane)) * 8;
      s16x8 bh = *(const s16x8*)&Wh[wb];
      s16x8 bl = *(const s16x8*)&Wl[wb];
#pragma unroll
      for (int rf = 0; rf < 2; ++rf) {
        accP[rf][ct] = __builtin_amdgcn_mfma_f32_16x16x32_bf16(ah[rf], bh, accP[rf][ct], 0, 0, 0);
        accP[rf][ct] = __builtin_amdgcn_mfma_f32_16x16x32_bf16(ah[rf], bl, accP[rf][ct], 0, 0, 0);
        accP[rf][ct] = __builtin_amdgcn_mfma_f32_16x16x32_bf16(al[rf], bh, accP[rf][ct], 0, 0, 0);
      }
    }
  }
#pragma unroll
  for (int c = 0; c < 4; ++c) {
#pragma unroll
    for (int kk = 0; kk < 64; kk += 32) {
      s16x8 ah[2], al[2];
#pragma unroll
      for (int rf = 0; rf < 2; ++rf) {
        if (rok[rf]) {
          size_t ao = (size_t)grow[rf] * 256 + c * 64 + kk + klg * 8;
          ah[rf] = *(const s16x8*)&AggH[ao];
          al[rf] = *(const s16x8*)&AggL[ao];
        } else {
          ah[rf] = (s16x8){0, 0, 0, 0, 0, 0, 0, 0};
          al[rf] = (s16x8){0, 0, 0, 0, 0, 0, 0, 0};
        }
      }
      int qP = 2 + c * 2 + (kk >> 5);
#pragma unroll
      for (int ct = 0; ct < 4; ++ct) {
        size_t wbP = (size_t)(((qP * 4 + ct) * 64 + lane)) * 8;
        s16x8 bh = *(const s16x8*)&Wh[wbP];
        s16x8 bl = *(const s16x8*)&Wl[wbP];
#pragma unroll
        for (int rf = 0; rf < 2; ++rf) {
          accP[rf][ct] = __builtin_amdgcn_mfma_f32_16x16x32_bf16(ah[rf], bh, accP[rf][ct], 0, 0, 0);
          accP[rf][ct] = __builtin_amdgcn_mfma_f32_16x16x32_bf16(ah[rf], bl, accP[rf][ct], 0, 0, 0);
          accP[rf][ct] = __builtin_amdgcn_mfma_f32_16x16x32_bf16(al[rf], bh, accP[rf][ct], 0, 0, 0);
        }
        size_t wbQ = wbP + (size_t)8 * 4 * 64 * 8;
        bh = *(const s16x8*)&Wh[wbQ];
        bl = *(const s16x8*)&Wl[wbQ];
#pragma unroll
        for (int rf = 0; rf < 2; ++rf) {
          accQ[rf][ct] = __builtin_amdgcn_mfma_f32_16x16x32_bf16(ah[rf], bh, accQ[rf][ct], 0, 0, 0);
          accQ[rf][ct] = __builtin_amdgcn_mfma_f32_16x16x32_bf16(ah[rf], bl, accQ[rf][ct], 0, 0, 0);
          accQ[rf][ct] = __builtin_amdgcn_mfma_f32_16x16x32_bf16(al[rf], bh, accQ[rf][ct], 0, 0, 0);
        }
        size_t wbR = wbP + (size_t)16 * 4 * 64 * 8;
        bh = *(const s16x8*)&Wh[wbR];
        bl = *(const s16x8*)&Wl[wbR];
#pragma unroll
        for (int rf = 0; rf < 2; ++rf) {
          accR[rf][ct] = __builtin_amdgcn_mfma_f32_16x16x32_bf16(ah[rf], bh, accR[rf][ct], 0, 0, 0);
          accR[rf][ct] = __builtin_amdgcn_mfma_f32_16x16x32_bf16(ah[rf], bl, accR[rf][ct], 0, 0, 0);
          accR[rf][ct] = __builtin_amdgcn_mfma_f32_16x16x32_bf16(al[rf], bh, accR[rf][ct], 0, 0, 0);
        }
      }
    }
  }
#pragma unroll
  for (int rf = 0; rf < 2; ++rf)
#pragma unroll
    for (int i = 0; i < 4; ++i) {
      int r = row0 + w * 32 + rf * 16 + klg * 4 + i;
      if (r < n) {
        float av = amp[r], iv = inv[r];
#pragma unroll
        for (int ct = 0; ct < 4; ++ct) {
          int colo = ct * 16 + ar;
          float vv = accP[rf][ct][i] + av * accQ[rf][ct][i] + iv * accR[rf][ct][i] + beff[colo];
          h1[(size_t)r * 64 + colo] = fmaxf(vv, 0.f);
        }
      }
    }
}

// fused conv2: wave/node stats (16-deep fp16 gather) + 2-col dot, wave reduce
__global__ __launch_bounds__(256) void fused_conv2(
    const float* __restrict__ h1, const float* __restrict__ A,
    const __half* __restrict__ B, const int* __restrict__ rowptr,
    const int* __restrict__ col, const float* __restrict__ amp,
    const float* __restrict__ inv, const float* __restrict__ W2eff,
    const float* __restrict__ b2eff, float* __restrict__ out, int n) {
  int tid = threadIdx.x;
  int lane = tid & 63, wv = tid >> 6;
  int node = blockIdx.x * 4 + wv;
  if (node >= n) return;
  int s0 = rowptr[node], s1 = rowptr[node + 1];
  GATHER_STATS
  int d = s1 - s0;
  float st[4];
  if (d > 0) {
    float idn = 1.0f / (float)d;
    float mB = sum * idn;
    float a = A[(size_t)node * 64 + lane];
    st[0] = a + mB;
    st[1] = a + mn;
    st[2] = a + mx;
    float var = fmaf(-mB, mB, sq * idn);
    st[3] = sqrtf(fmaxf(var, 0.0f) + 1e-5f);
  } else {
    st[0] = 0.f; st[1] = 0.f; st[2] = 0.f; st[3] = sqrtf(1e-5f);
  }
  float av = amp[node], iv = inv[node];
  float xv = h1[(size_t)node * 64 + lane];
  float p0 = W2eff[lane] * xv;
  float p1 = W2eff[832 + lane] * xv;
#pragma unroll
  for (int m = 0; m < 4; ++m) {
    int j = m * 64 + lane;
    p0 = fmaf(st[m], fmaf(av, W2eff[320 + j], fmaf(iv, W2eff[576 + j], W2eff[64 + j])), p0);
    p1 = fmaf(st[m], fmaf(av, W2eff[832 + 320 + j], fmaf(iv, W2eff[832 + 576 + j], W2eff[832 + 64 + j])), p1);
  }
#pragma unroll
  for (int m = 32; m; m >>= 1) {
    p0 += __shfl_xor(p0, m);
    p1 += __shfl_xor(p1, m);
  }
  if (lane == 0) {
    out[(size_t)node * 2 + 0] = p0 + b2eff[0];
    out[(size_t)node * 2 + 1] = p1 + b2eff[1];
  }
}

extern "C" void kernel_launch(void* const* d_in, const int* in_sizes, int n_in,
                              void* d_out, int out_size, void* d_ws, size_t ws_size,
                              hipStream_t stream) {
  const float* x = (const float*)d_in[0];
  const int* ei = (const int*)d_in[1];
  const float* W1_pre = (const float*)d_in[2];
  const float* b1_pre = (const float*)d_in[3];
  const float* W1_post = (const float*)d_in[4];
  const float* b1_post = (const float*)d_in[5];
  const float* W1_lin = (const float*)d_in[6];
  const float* b1_lin = (const float*)d_in[7];
  const float* W2_pre = (const float*)d_in[8];
  const float* b2_pre = (const float*)d_in[9];
  const float* W2_post = (const float*)d_in[10];
  const float* b2_post = (const float*)d_in[11];
  const float* W2_lin = (const float*)d_in[12];
  const float* b2_lin = (const float*)d_in[13];

  const int N = in_sizes[0] / 64;
  const int E = in_sizes[1] / 2;
  const int* srcp = ei;
  const int* dstp = ei + E;
  const int nb = (N + 255) / 256;
  const int nbuk = (N + 1023) >> 10;

  char* ws = (char*)d_ws;
  size_t off = 0;
  auto take = [&](size_t bytes) -> void* {
    void* p = ws + off;
    off = (off + bytes + 255) & ~(size_t)255;
    return p;
  };
  int* deg = (int*)take((size_t)N * 4);
  int* rowptr = (int*)take((size_t)(N + 1) * 4);
  int* cursor = (int*)take((size_t)N * 4);
  int* tmp = (int*)take((size_t)N * 4);
  int* partial = (int*)take(4096);
  int* bcur = (int*)take(4096);
  float* amp = (float*)take((size_t)N * 4);
  float* inv = (float*)take((size_t)N * 4);
  float* avgsum = (float*)take(4);
  unsigned short* W1h = (unsigned short*)take((size_t)64 * 832 * 2);
  unsigned short* W1l = (unsigned short*)take((size_t)64 * 832 * 2);
  float* b1eff = (float*)take(64 * 4);
  float* W2eff = (float*)take((size_t)2 * 832 * 4);
  float* b2eff = (float*)take(2 * 4);
  unsigned short* Wp1h = (unsigned short*)take((size_t)128 * 64 * 2);
  unsigned short* Wp1l = (unsigned short*)take((size_t)128 * 64 * 2);
  unsigned short* Wp2h = (unsigned short*)take((size_t)128 * 64 * 2);
  unsigned short* Wp2l = (unsigned short*)take((size_t)128 * 64 * 2);
  int* col = (int*)take((size_t)E * 4);
  int2* bmaj = (int2*)take((size_t)E * 8);
  float* Abuf = (float*)take((size_t)N * 64 * 4);
  __half* Bbuf = (__half*)take((size_t)N * 64 * 2);
  unsigned short* AggH = (unsigned short*)take((size_t)N * 256 * 2);
  unsigned short* AggL = (unsigned short*)take((size_t)N * 256 * 2);
  float* h1 = (float*)take((size_t)N * 64 * 4);
  (void)ws_size; (void)n_in; (void)out_size;

  hipMemsetAsync(deg, 0, (size_t)N * 4, stream);
  hipMemsetAsync(avgsum, 0, 4, stream);

  make_eff_kernel<<<(ME_S5 + 255) / 256, 256, 0, stream>>>(
      W1_post, b1_post, W1_lin, b1_lin, W2_post, b2_post, W2_lin, b2_lin,
      W1_pre, W2_pre, W1h, W1l, b1eff, W2eff, b2eff, Wp1h, Wp1l, Wp2h, Wp2l);
  hist_kernel<<<(E + 255) / 256, 256, 0, stream>>>(dstp, deg, E);
  avglog_kernel<<<(N + 255) / 256, 256, 0, stream>>>(deg, avgsum, N);
  scan1_kernel<<<nb, 256, 0, stream>>>(deg, tmp, partial, N);
  scan2_kernel<<<1, 1024, 0, stream>>>(partial, nb);
  scan3_kernel<<<nb, 256, 0, stream>>>(deg, tmp, partial, rowptr, cursor, amp, inv,
                                       avgsum, N, E);
  bucket_init<<<1, 128, 0, stream>>>(rowptr, bcur, N, nbuk);
  bucket_scatter<<<(E + ACHUNK - 1) / ACHUNK, 256, 0, stream>>>(srcp, dstp, bcur, bmaj, E, nbuk);
  bucket_fill<<<nbuk, 1024, 0, stream>>>(bmaj, rowptr, cursor, col, N, E);

  // conv1
  pre_mfma<<<(N + 127) / 128, 256, 0, stream>>>(x, Wp1h, Wp1l, b1_pre, Abuf, Bbuf, N);
  aggr_pack<<<(N + 3) / 4, 256, 0, stream>>>(Abuf, Bbuf, rowptr, col, AggH, AggL, N);
  post1_kernel<<<(N + 127) / 128, 256, 0, stream>>>(x, AggH, AggL, amp, inv,
                                                    W1h, W1l, b1eff, h1, N);
  // conv2
  pre_mfma<<<(N + 127) / 128, 256, 0, stream>>>(h1, Wp2h, Wp2l, b2_pre, Abuf, Bbuf, N);
  fused_conv2<<<(N + 3) / 4, 256, 0, stream>>>(h1, Abuf, Bbuf, rowptr, col, amp, inv,
                                               W2eff, b2eff, (float*)d_out, N);
}